// Round 1
// baseline (806.326 us; speedup 1.0000x reference)
//
#include <hip/hip_runtime.h>
#include <math.h>

#define LL 4096
#define NBATCH 4
#define CM 192
#define DI 384
#define NST 16
#define RK 12
#define NCH 44
#define SGH 96

// workspace offsets (floats)
#define O_WT_IN   0
#define O_WT_LOW  147456
#define O_WT_XP   221184
#define O_WT_XPL  245760
#define O_WT_OUT  270336
#define O_XN      344064
#define O_LOWT    3489792
#define O_XH      6635520
#define O_Z       12926976
#define O_LOWP    19218432
#define O_XS      25509888
#define O_DBCH    31801344
#define O_DBCL    32522240
#define O_DBC     33243136
#define O_BS      33964032
#define O_CS      34226176
#define O_DELTA   O_LOWP   // lowp dead after x_proj_low GEMM
#define O_Y       O_XH     // xh dead after conv2d
#define O_YG      O_XN     // xn+lowT dead after in_proj GEMMs (spans both)

#define LD16(dst, ptr) { const float4* _p = (const float4*)(ptr); \
  float4 _a=_p[0], _b=_p[1], _c=_p[2], _d=_p[3]; \
  dst[0]=_a.x; dst[1]=_a.y; dst[2]=_a.z; dst[3]=_a.w; \
  dst[4]=_b.x; dst[5]=_b.y; dst[6]=_b.z; dst[7]=_b.w; \
  dst[8]=_c.x; dst[9]=_c.y; dst[10]=_c.z; dst[11]=_c.w; \
  dst[12]=_d.x; dst[13]=_d.y; dst[14]=_d.z; dst[15]=_d.w; }
#define ST16(ptr, src) { float4* _p = (float4*)(ptr); \
  _p[0] = make_float4(src[0],src[1],src[2],src[3]); \
  _p[1] = make_float4(src[4],src[5],src[6],src[7]); \
  _p[2] = make_float4(src[8],src[9],src[10],src[11]); \
  _p[3] = make_float4(src[12],src[13],src[14],src[15]); }

// -------- weight transpose + pad:  in [N][K] -> out [K][N64] (zero padded) ----
__global__ void transpose_pad_kernel(const float* __restrict__ in, float* __restrict__ out,
                                     int N, int K, int N64)
{
    int idx = blockIdx.x * 256 + threadIdx.x;
    if (idx >= K * N64) return;
    int k = idx / N64, n = idx % N64;
    out[idx] = (n < N) ? in[n * K + k] : 0.f;
}

// -------- LayerNorm (optional) + transpose [T,192] -> [B][192][L] ------------
__global__ __launch_bounds__(256) void ln_tr_kernel(const float* __restrict__ X,
    const float* __restrict__ gw, const float* __restrict__ bw,
    float* __restrict__ out, int apply)
{
    __shared__ float xt[64][193];
    __shared__ float reds[64][4], redq[64][4];
    __shared__ float mu_s[64], rs_s[64];
    int tid = threadIdx.x;
    int t0 = blockIdx.x * 64;
    const float* Xb = X + (size_t)t0 * CM;
#pragma unroll
    for (int i = 0; i < 12; i++) {
        int f4 = tid + 256 * i;
        float4 v = *(const float4*)&Xb[f4 * 4];
        int row = f4 / 48, c = (f4 % 48) * 4;
        xt[row][c] = v.x; xt[row][c+1] = v.y; xt[row][c+2] = v.z; xt[row][c+3] = v.w;
    }
    __syncthreads();
    int tok = tid & 63, p = tid >> 6;
    if (apply) {
        float s = 0.f, q = 0.f;
#pragma unroll 8
        for (int i = 0; i < 48; i++) { float v = xt[tok][p*48+i]; s += v; q = fmaf(v, v, q); }
        reds[tok][p] = s; redq[tok][p] = q;
        __syncthreads();
        if (tid < 64) {
            float ss = reds[tid][0]+reds[tid][1]+reds[tid][2]+reds[tid][3];
            float qq = redq[tid][0]+redq[tid][1]+redq[tid][2]+redq[tid][3];
            float mu = ss * (1.f/CM);
            float var = qq * (1.f/CM) - mu*mu;
            mu_s[tid] = mu; rs_s[tid] = rsqrtf(var + 1e-5f);
        }
        __syncthreads();
    }
    int bb = t0 / LL, l0 = t0 % LL;
    float mu = apply ? mu_s[tok] : 0.f;
    float rs = apply ? rs_s[tok] : 1.f;
    for (int i = 0; i < 48; i++) {
        int c = p*48 + i;
        float v = xt[tok][c];
        if (apply) v = (v - mu) * rs * gw[c] + bw[c];
        out[((size_t)bb*CM + c)*LL + l0 + tok] = v;
    }
}

// -------- tiled GEMM: A channel-major [B][K][L], Wt [K][N64] ------------------
// MODE 0: in_proj  -> out0=xh [B][DI][L] (n<DI), out1=z [B][DI][L] (n>=DI)
// MODE 1: generic  -> out0 [B][Nreal][L] (n<Nreal)
// MODE 2: out_proj -> out0[t*Nreal+n] = resid + acc   (token-major + residual)
template<int MODE>
__global__ __launch_bounds__(256) void gemm_ta(
    const float* __restrict__ A, const float* __restrict__ Wt,
    const float* __restrict__ resid, float* __restrict__ out0,
    float* __restrict__ out1, int K, int N64, int Nreal)
{
    __shared__ __align__(16) float At[64][64];
    __shared__ __align__(16) float Wl[64][64];
    int tid = threadIdx.x;
    int t0 = blockIdx.x * 64;
    int b = t0 / LL, l0 = t0 % LL;
    int n0 = blockIdx.y * 64;
    const float* Ab = A + (size_t)b * K * LL;
    float acc[4][4] = {};
    int kr = tid >> 4;
    int m4 = (tid & 15) * 4;
    int r0 = m4;
    int c0 = kr * 4;
    for (int k0 = 0; k0 < K; k0 += 64) {
        __syncthreads();
#pragma unroll
        for (int i = 0; i < 4; i++) {
            int k = kr + i * 16;
            *(float4*)&At[k][m4] = *(const float4*)&Ab[(size_t)(k0+k)*LL + l0 + m4];
            *(float4*)&Wl[k][m4] = *(const float4*)&Wt[(size_t)(k0+k)*N64 + n0 + m4];
        }
        __syncthreads();
#pragma unroll
        for (int k = 0; k < 64; k++) {
            float4 a4 = *(const float4*)&At[k][r0];
            float4 w4 = *(const float4*)&Wl[k][c0];
            float av[4] = {a4.x, a4.y, a4.z, a4.w};
            float wv[4] = {w4.x, w4.y, w4.z, w4.w};
#pragma unroll
            for (int i = 0; i < 4; i++)
#pragma unroll
                for (int j = 0; j < 4; j++)
                    acc[i][j] = fmaf(av[i], wv[j], acc[i][j]);
        }
    }
#pragma unroll
    for (int i = 0; i < 4; i++) {
        int l = l0 + r0 + i;
        int t = t0 + r0 + i;
#pragma unroll
        for (int j = 0; j < 4; j++) {
            int n = n0 + c0 + j;
            float v = acc[i][j];
            if (MODE == 0) {
                if (n < DI) out0[((size_t)b*DI + n)*LL + l] = v;
                else        out1[((size_t)b*DI + (n-DI))*LL + l] = v;
            } else if (MODE == 1) {
                if (n < Nreal) out0[((size_t)b*Nreal + n)*LL + l] = v;
            } else {
                out0[(size_t)t*Nreal + n] = resid[(size_t)t*Nreal + n] + v;
            }
        }
    }
}

// -------- depthwise 3x3 conv + bias + SiLU ------------------------------------
__global__ __launch_bounds__(256) void conv2d_silu_kernel(const float* __restrict__ xh,
    const float* __restrict__ w, const float* __restrict__ bias, float* __restrict__ xs)
{
    int tid = threadIdx.x;
    int l = blockIdx.x * 256 + tid;
    int c = blockIdx.y, b = blockIdx.z;
    const float* P = xh + ((size_t)b*DI + c)*LL;
    int h = l >> 6, ww = l & 63;
    float acc = bias[c];
#pragma unroll
    for (int kh = 0; kh < 3; kh++) {
        int hh = h + kh - 1;
        if ((unsigned)hh < 64u) {
#pragma unroll
            for (int kw = 0; kw < 3; kw++) {
                int wv = ww + kw - 1;
                if ((unsigned)wv < 64u) acc = fmaf(w[c*9 + kh*3 + kw], P[hh*64 + wv], acc);
            }
        }
    }
    float sg = 1.f / (1.f + expf(-acc));
    xs[((size_t)b*DI + c)*LL + l] = acc * sg;
}

// -------- SimpleGates on low B/C + sum high+low -> dbc [B][44][L] -------------
__global__ __launch_bounds__(256) void gates_kernel(const float* __restrict__ dbcH,
    const float* __restrict__ dbcL,
    const float* __restrict__ sgb1, const float* __restrict__ sgb2,
    const float* __restrict__ sgc1, const float* __restrict__ sgc2,
    float* __restrict__ dbc)
{
    __shared__ float w1b[192*16], w2b[16*96], w1c[192*16], w2c[16*96];
    int tid = threadIdx.x;
    for (int i = tid; i < 192*16; i += 256) { w1b[i] = sgb1[i]; w1c[i] = sgc1[i]; }
    for (int i = tid; i < 16*96;  i += 256) { w2b[i] = sgb2[i]; w2c[i] = sgc2[i]; }
    __syncthreads();
    int l = blockIdx.x * 256 + tid;
    int b = blockIdx.y;
    size_t pb_ = (size_t)b*NCH*LL + l;
#pragma unroll
    for (int c = 0; c < RK; c++)
        dbc[pb_ + (size_t)c*LL] = dbcH[pb_ + (size_t)c*LL] + dbcL[pb_ + (size_t)c*LL];
    // B gate
    {
        float xin[16], og[16];
#pragma unroll
        for (int n = 0; n < 16; n++) { xin[n] = dbcL[pb_ + (size_t)(RK+n)*LL]; og[n] = 0.f; }
        for (int h = 0; h < SGH; h++) {
            float ya = 0.f, yb = 0.f;
#pragma unroll
            for (int n = 0; n < 16; n++) {
                ya = fmaf(w1b[h*16+n], xin[n], ya);
                yb = fmaf(w1b[(h+SGH)*16+n], xin[n], yb);
            }
            float gg = 0.5f * ya * (1.f + erff(ya * 0.70710678f)) * yb;
#pragma unroll
            for (int n = 0; n < 16; n++) og[n] = fmaf(w2b[n*SGH+h], gg, og[n]);
        }
#pragma unroll
        for (int n = 0; n < 16; n++)
            dbc[pb_ + (size_t)(RK+n)*LL] = dbcH[pb_ + (size_t)(RK+n)*LL] + og[n];
    }
    // C gate
    {
        float xin[16], og[16];
#pragma unroll
        for (int n = 0; n < 16; n++) { xin[n] = dbcL[pb_ + (size_t)(RK+16+n)*LL]; og[n] = 0.f; }
        for (int h = 0; h < SGH; h++) {
            float ya = 0.f, yb = 0.f;
#pragma unroll
            for (int n = 0; n < 16; n++) {
                ya = fmaf(w1c[h*16+n], xin[n], ya);
                yb = fmaf(w1c[(h+SGH)*16+n], xin[n], yb);
            }
            float gg = 0.5f * ya * (1.f + erff(ya * 0.70710678f)) * yb;
#pragma unroll
            for (int n = 0; n < 16; n++) og[n] = fmaf(w2c[n*SGH+h], gg, og[n]);
        }
#pragma unroll
        for (int n = 0; n < 16; n++)
            dbc[pb_ + (size_t)(RK+16+n)*LL] = dbcH[pb_ + (size_t)(RK+16+n)*LL] + og[n];
    }
}

// -------- residual dilated dwconv1d + delta projection + softplus -------------
__global__ __launch_bounds__(256) void convd_delta_kernel(const float* __restrict__ dbc,
    const float* __restrict__ wdt, const float* __restrict__ wB, const float* __restrict__ wC,
    const float* __restrict__ dtw, const float* __restrict__ dtb,
    float* __restrict__ Bs, float* __restrict__ Cs, float* __restrict__ delta)
{
    __shared__ float wch[NCH*15];
    __shared__ float dwl[DI*RK];
    int tid = threadIdx.x;
    for (int i = tid; i < RK*15;  i += 256) wch[i] = wdt[i];
    for (int i = tid; i < NST*15; i += 256) wch[RK*15 + i] = wB[i];
    for (int i = tid; i < NST*15; i += 256) wch[(RK+NST)*15 + i] = wC[i];
    for (int i = tid; i < DI*RK;  i += 256) dwl[i] = dtw[i];
    __syncthreads();
    int l = blockIdx.x * 256 + tid;
    int b = blockIdx.y;
    float val[NCH];
#pragma unroll
    for (int c = 0; c < NCH; c++) {
        const float* P = dbc + ((size_t)b*NCH + c)*LL;
        float a = P[l];
#pragma unroll
        for (int k = 0; k < 15; k++) {
            int lt = l + 2*k - 14;
            if ((unsigned)lt < (unsigned)LL) a = fmaf(wch[c*15+k], P[lt], a);
        }
        val[c] = a;
    }
#pragma unroll
    for (int n = 0; n < NST; n++) {
        Bs[((size_t)b*NST + n)*LL + l] = val[RK + n];
        Cs[((size_t)b*NST + n)*LL + l] = val[RK + NST + n];
    }
    for (int d = 0; d < DI; d++) {
        float s = dtb[d];
#pragma unroll
        for (int r = 0; r < RK; r++) s = fmaf(dwl[d*RK + r], val[r], s);
        float sp = fmaxf(s, 0.f) + log1pf(expf(-fabsf(s)));
        delta[((size_t)b*DI + d)*LL + l] = sp;
    }
}

// -------- selective scan: chunked parallel scan, one block per (b,d) ----------
__global__ __launch_bounds__(256) void scan_kernel(
    const float* __restrict__ u_, const float* __restrict__ delta_,
    const float* __restrict__ Bs_, const float* __restrict__ Cs_,
    const float* __restrict__ Alogs, const float* __restrict__ Ds,
    float* __restrict__ y_)
{
    __shared__ float sA[256][NST+1];
    __shared__ float sB[256][NST+1];
    int tid = threadIdx.x;
    int bd = blockIdx.x;
    int b = bd / DI, d = bd % DI;
    size_t base = ((size_t)b*DI + d)*LL + tid*16;
    float dl[16], du[16], yac[16];
    LD16(du, u_ + base);
    LD16(dl, delta_ + base);
    float Dd = Ds[d];
#pragma unroll
    for (int s = 0; s < 16; s++) { yac[s] = du[s]*Dd; du[s] = dl[s]*du[s]; }
    float Av[16];
#pragma unroll
    for (int n = 0; n < 16; n++) Av[n] = -expf(Alogs[d*NST + n]);
    float ap[16], hv[16];
    // phase 1: local scan over 16 steps for each of 16 states
#pragma unroll
    for (int n = 0; n < 16; n++) {
        float Bn[16];
        LD16(Bn, Bs_ + ((size_t)b*NST + n)*LL + tid*16);
        float a = 1.f, h = 0.f, An = Av[n];
#pragma unroll
        for (int s = 0; s < 16; s++) {
            float e = expf(dl[s]*An);
            h = fmaf(e, h, du[s]*Bn[s]);
            a *= e;
        }
        ap[n] = a; hv[n] = h;
    }
    // phase 2: Hillis-Steele inclusive scan of affine transforms (a,b)
#pragma unroll
    for (int n = 0; n < 16; n++) { sA[tid][n] = ap[n]; sB[tid][n] = hv[n]; }
    for (int off = 1; off < 256; off <<= 1) {
        __syncthreads();
        float pa[16], pb[16];
        int src = tid - off;
        if (src >= 0) {
#pragma unroll
            for (int n = 0; n < 16; n++) { pa[n] = sA[src][n]; pb[n] = sB[src][n]; }
        }
        __syncthreads();
        if (src >= 0) {
#pragma unroll
            for (int n = 0; n < 16; n++) {
                hv[n] = fmaf(ap[n], pb[n], hv[n]);
                ap[n] = ap[n]*pa[n];
                sA[tid][n] = ap[n]; sB[tid][n] = hv[n];
            }
        }
    }
    __syncthreads();
    float hin[16];
#pragma unroll
    for (int n = 0; n < 16; n++) hin[n] = (tid > 0) ? sB[tid-1][n] : 0.f;
    // phase 3: recompute with incoming state, accumulate y = C . h
#pragma unroll
    for (int n = 0; n < 16; n++) {
        float Bn[16], Cn[16];
        LD16(Bn, Bs_ + ((size_t)b*NST + n)*LL + tid*16);
        LD16(Cn, Cs_ + ((size_t)b*NST + n)*LL + tid*16);
        float h = hin[n], An = Av[n];
#pragma unroll
        for (int s = 0; s < 16; s++) {
            float e = expf(dl[s]*An);
            h = fmaf(e, h, du[s]*Bn[s]);
            yac[s] = fmaf(Cn[s], h, yac[s]);
        }
    }
    ST16(y_ + base, yac);
}

// -------- out-norm LN(384) + z-SiLU gating -> yg [B][DI][L] -------------------
__global__ __launch_bounds__(256) void outnorm_gate_kernel(const float* __restrict__ y,
    const float* __restrict__ z, const float* __restrict__ g, const float* __restrict__ bt,
    float* __restrict__ yg)
{
    int tid = threadIdx.x;
    int l = blockIdx.x * 256 + tid;
    int b = blockIdx.y;
    const float* yp = y + (size_t)b*DI*LL + l;
    float s = 0.f, q = 0.f;
#pragma unroll 4
    for (int d = 0; d < DI; d++) { float v = yp[(size_t)d*LL]; s += v; q = fmaf(v, v, q); }
    float mu = s * (1.f/DI);
    float var = q * (1.f/DI) - mu*mu;
    float rs = rsqrtf(var + 1e-5f);
    const float* zp = z + (size_t)b*DI*LL + l;
    float* op = yg + (size_t)b*DI*LL + l;
#pragma unroll 4
    for (int d = 0; d < DI; d++) {
        float v = (yp[(size_t)d*LL] - mu)*rs*g[d] + bt[d];
        float zv = zp[(size_t)d*LL];
        float sg = 1.f / (1.f + expf(-zv));
        op[(size_t)d*LL] = v * (zv * sg);
    }
}

extern "C" void kernel_launch(void* const* d_in, const int* in_sizes, int n_in,
                              void* d_out, int out_size, void* d_ws, size_t ws_size,
                              hipStream_t stream)
{
    (void)in_sizes; (void)n_in; (void)out_size; (void)ws_size;
    const float* x     = (const float*)d_in[0];
    const float* low   = (const float*)d_in[1];
    const float* ln_g  = (const float*)d_in[2];
    const float* ln_b  = (const float*)d_in[3];
    const float* w_in  = (const float*)d_in[4];
    const float* w_low = (const float*)d_in[5];
    const float* w_c2d = (const float*)d_in[6];
    const float* b_c2d = (const float*)d_in[7];
    const float* w_xp  = (const float*)d_in[8];
    const float* w_xpl = (const float*)d_in[9];
    const float* w_cdt = (const float*)d_in[10];
    const float* w_cB  = (const float*)d_in[11];
    const float* w_cC  = (const float*)d_in[12];
    const float* sgb1  = (const float*)d_in[13];
    const float* sgb2  = (const float*)d_in[14];
    const float* sgc1  = (const float*)d_in[15];
    const float* sgc2  = (const float*)d_in[16];
    const float* dtw   = (const float*)d_in[17];
    const float* dtb   = (const float*)d_in[18];
    const float* Alogs = (const float*)d_in[19];
    const float* Ds    = (const float*)d_in[20];
    const float* ong   = (const float*)d_in[21];
    const float* onb   = (const float*)d_in[22];
    const float* w_out = (const float*)d_in[23];
    float* ws  = (float*)d_ws;
    float* out = (float*)d_out;
    dim3 blk(256);

    transpose_pad_kernel<<<576, blk, 0, stream>>>(w_in,  ws + O_WT_IN,  768, 192, 768);
    transpose_pad_kernel<<<288, blk, 0, stream>>>(w_low, ws + O_WT_LOW, 384, 192, 384);
    transpose_pad_kernel<<<96,  blk, 0, stream>>>(w_xp,  ws + O_WT_XP,  44,  384, 64);
    transpose_pad_kernel<<<96,  blk, 0, stream>>>(w_xpl, ws + O_WT_XPL, 44,  384, 64);
    transpose_pad_kernel<<<288, blk, 0, stream>>>(w_out, ws + O_WT_OUT, 192, 384, 192);

    ln_tr_kernel<<<256, blk, 0, stream>>>(x,   ln_g, ln_b, ws + O_XN,   1);
    ln_tr_kernel<<<256, blk, 0, stream>>>(low, ln_g, ln_b, ws + O_LOWT, 0);

    gemm_ta<0><<<dim3(256,12), blk, 0, stream>>>(ws+O_XN,   ws+O_WT_IN,  nullptr, ws+O_XH,   ws+O_Z, 192, 768, 768);
    gemm_ta<1><<<dim3(256,6),  blk, 0, stream>>>(ws+O_LOWT, ws+O_WT_LOW, nullptr, ws+O_LOWP, nullptr, 192, 384, 384);

    conv2d_silu_kernel<<<dim3(16,384,4), blk, 0, stream>>>(ws+O_XH, w_c2d, b_c2d, ws+O_XS);

    gemm_ta<1><<<dim3(256,1), blk, 0, stream>>>(ws+O_XS,   ws+O_WT_XP,  nullptr, ws+O_DBCH, nullptr, 384, 64, 44);
    gemm_ta<1><<<dim3(256,1), blk, 0, stream>>>(ws+O_LOWP, ws+O_WT_XPL, nullptr, ws+O_DBCL, nullptr, 384, 64, 44);

    gates_kernel<<<dim3(16,4), blk, 0, stream>>>(ws+O_DBCH, ws+O_DBCL, sgb1, sgb2, sgc1, sgc2, ws+O_DBC);

    convd_delta_kernel<<<dim3(16,4), blk, 0, stream>>>(ws+O_DBC, w_cdt, w_cB, w_cC, dtw, dtb,
                                                       ws+O_BS, ws+O_CS, ws+O_DELTA);

    scan_kernel<<<1536, blk, 0, stream>>>(ws+O_XS, ws+O_DELTA, ws+O_BS, ws+O_CS, Alogs, Ds, ws+O_Y);

    outnorm_gate_kernel<<<dim3(16,4), blk, 0, stream>>>(ws+O_Y, ws+O_Z, ong, onb, ws+O_YG);

    gemm_ta<2><<<dim3(256,3), blk, 0, stream>>>(ws+O_YG, ws+O_WT_OUT, x, out, nullptr, 384, 192, 192);
}

// Round 2
// 482.972 us; speedup vs baseline: 1.6695x; 1.6695x over previous
//
#include <hip/hip_runtime.h>
#include <math.h>

#define LL 4096
#define NBATCH 4
#define CM 192
#define DI 384
#define NST 16
#define RK 12
#define NCH 44
#define SGH 96

// workspace offsets (floats)
#define O_WT_IN   0
#define O_WT_LOW  147456
#define O_WT_XP   221184
#define O_WT_XPL  245760
#define O_WT_OUT  270336
#define O_XN      344064
#define O_LOWT    3489792
#define O_XH      6635520
#define O_Z       12926976
#define O_LOWP    19218432
#define O_XS      25509888
#define O_DBCH    31801344
#define O_DBCL    32522240
#define O_DBC     33243136
#define O_BS      33964032
#define O_CS      34226176
#define O_DELTA   O_LOWP   // lowp dead after x_proj_low GEMM
#define O_Y       O_XH     // xh dead after conv2d
#define O_YG      O_XN     // xn+lowT dead after in_proj GEMMs (spans both)
#define O_DTS     O_DBCH   // dbcH dead after gates_kernel

#define LD16(dst, ptr) { const float4* _p = (const float4*)(ptr); \
  float4 _a=_p[0], _b=_p[1], _c=_p[2], _d=_p[3]; \
  dst[0]=_a.x; dst[1]=_a.y; dst[2]=_a.z; dst[3]=_a.w; \
  dst[4]=_b.x; dst[5]=_b.y; dst[6]=_b.z; dst[7]=_b.w; \
  dst[8]=_c.x; dst[9]=_c.y; dst[10]=_c.z; dst[11]=_c.w; \
  dst[12]=_d.x; dst[13]=_d.y; dst[14]=_d.z; dst[15]=_d.w; }
#define ST16(ptr, src) { float4* _p = (float4*)(ptr); \
  _p[0] = make_float4(src[0],src[1],src[2],src[3]); \
  _p[1] = make_float4(src[4],src[5],src[6],src[7]); \
  _p[2] = make_float4(src[8],src[9],src[10],src[11]); \
  _p[3] = make_float4(src[12],src[13],src[14],src[15]); }

// -------- weight transpose + pad:  in [N][K] -> out [K][N64] (zero padded) ----
__global__ void transpose_pad_kernel(const float* __restrict__ in, float* __restrict__ out,
                                     int N, int K, int N64)
{
    int idx = blockIdx.x * 256 + threadIdx.x;
    if (idx >= K * N64) return;
    int k = idx / N64, n = idx % N64;
    out[idx] = (n < N) ? in[n * K + k] : 0.f;
}

// -------- LayerNorm (optional) + transpose [T,192] -> [B][192][L] ------------
__global__ __launch_bounds__(256) void ln_tr_kernel(const float* __restrict__ X,
    const float* __restrict__ gw, const float* __restrict__ bw,
    float* __restrict__ out, int apply)
{
    __shared__ float xt[64][193];
    __shared__ float reds[64][4], redq[64][4];
    __shared__ float mu_s[64], rs_s[64];
    int tid = threadIdx.x;
    int t0 = blockIdx.x * 64;
    const float* Xb = X + (size_t)t0 * CM;
#pragma unroll
    for (int i = 0; i < 12; i++) {
        int f4 = tid + 256 * i;
        float4 v = *(const float4*)&Xb[f4 * 4];
        int row = f4 / 48, c = (f4 % 48) * 4;
        xt[row][c] = v.x; xt[row][c+1] = v.y; xt[row][c+2] = v.z; xt[row][c+3] = v.w;
    }
    __syncthreads();
    int tok = tid & 63, p = tid >> 6;
    if (apply) {
        float s = 0.f, q = 0.f;
#pragma unroll 8
        for (int i = 0; i < 48; i++) { float v = xt[tok][p*48+i]; s += v; q = fmaf(v, v, q); }
        reds[tok][p] = s; redq[tok][p] = q;
        __syncthreads();
        if (tid < 64) {
            float ss = reds[tid][0]+reds[tid][1]+reds[tid][2]+reds[tid][3];
            float qq = redq[tid][0]+redq[tid][1]+redq[tid][2]+redq[tid][3];
            float mu = ss * (1.f/CM);
            float var = qq * (1.f/CM) - mu*mu;
            mu_s[tid] = mu; rs_s[tid] = rsqrtf(var + 1e-5f);
        }
        __syncthreads();
    }
    int bb = t0 / LL, l0 = t0 % LL;
    float mu = apply ? mu_s[tok] : 0.f;
    float rs = apply ? rs_s[tok] : 1.f;
    for (int i = 0; i < 48; i++) {
        int c = p*48 + i;
        float v = xt[tok][c];
        if (apply) v = (v - mu) * rs * gw[c] + bw[c];
        out[((size_t)bb*CM + c)*LL + l0 + tok] = v;
    }
}

// -------- tiled GEMM: A channel-major [B][K][L], Wt [K][N64] ------------------
template<int MODE>
__global__ __launch_bounds__(256) void gemm_ta(
    const float* __restrict__ A, const float* __restrict__ Wt,
    const float* __restrict__ resid, float* __restrict__ out0,
    float* __restrict__ out1, int K, int N64, int Nreal)
{
    __shared__ __align__(16) float At[64][64];
    __shared__ __align__(16) float Wl[64][64];
    int tid = threadIdx.x;
    int t0 = blockIdx.x * 64;
    int b = t0 / LL, l0 = t0 % LL;
    int n0 = blockIdx.y * 64;
    const float* Ab = A + (size_t)b * K * LL;
    float acc[4][4] = {};
    int kr = tid >> 4;
    int m4 = (tid & 15) * 4;
    int r0 = m4;
    int c0 = kr * 4;
    for (int k0 = 0; k0 < K; k0 += 64) {
        __syncthreads();
#pragma unroll
        for (int i = 0; i < 4; i++) {
            int k = kr + i * 16;
            *(float4*)&At[k][m4] = *(const float4*)&Ab[(size_t)(k0+k)*LL + l0 + m4];
            *(float4*)&Wl[k][m4] = *(const float4*)&Wt[(size_t)(k0+k)*N64 + n0 + m4];
        }
        __syncthreads();
#pragma unroll
        for (int k = 0; k < 64; k++) {
            float4 a4 = *(const float4*)&At[k][r0];
            float4 w4 = *(const float4*)&Wl[k][c0];
            float av[4] = {a4.x, a4.y, a4.z, a4.w};
            float wv[4] = {w4.x, w4.y, w4.z, w4.w};
#pragma unroll
            for (int i = 0; i < 4; i++)
#pragma unroll
                for (int j = 0; j < 4; j++)
                    acc[i][j] = fmaf(av[i], wv[j], acc[i][j]);
        }
    }
#pragma unroll
    for (int i = 0; i < 4; i++) {
        int l = l0 + r0 + i;
        int t = t0 + r0 + i;
#pragma unroll
        for (int j = 0; j < 4; j++) {
            int n = n0 + c0 + j;
            float v = acc[i][j];
            if (MODE == 0) {
                if (n < DI) out0[((size_t)b*DI + n)*LL + l] = v;
                else        out1[((size_t)b*DI + (n-DI))*LL + l] = v;
            } else if (MODE == 1) {
                if (n < Nreal) out0[((size_t)b*Nreal + n)*LL + l] = v;
            } else {
                out0[(size_t)t*Nreal + n] = resid[(size_t)t*Nreal + n] + v;
            }
        }
    }
}

// -------- depthwise 3x3 conv + bias + SiLU ------------------------------------
__global__ __launch_bounds__(256) void conv2d_silu_kernel(const float* __restrict__ xh,
    const float* __restrict__ w, const float* __restrict__ bias, float* __restrict__ xs)
{
    int tid = threadIdx.x;
    int l = blockIdx.x * 256 + tid;
    int c = blockIdx.y, b = blockIdx.z;
    const float* P = xh + ((size_t)b*DI + c)*LL;
    int h = l >> 6, ww = l & 63;
    float acc = bias[c];
#pragma unroll
    for (int kh = 0; kh < 3; kh++) {
        int hh = h + kh - 1;
        if ((unsigned)hh < 64u) {
#pragma unroll
            for (int kw = 0; kw < 3; kw++) {
                int wv = ww + kw - 1;
                if ((unsigned)wv < 64u) acc = fmaf(w[c*9 + kh*3 + kw], P[hh*64 + wv], acc);
            }
        }
    }
    float sg = 1.f / (1.f + __expf(-acc));
    xs[((size_t)b*DI + c)*LL + l] = acc * sg;
}

// -------- SimpleGates on low B/C + sum high+low -> dbc [B][44][L] -------------
// 256 blocks: each block 64 tokens, 4-way h-split, LDS reduce (lane-major, no conflicts)
__global__ __launch_bounds__(256) void gates_kernel(const float* __restrict__ dbcH,
    const float* __restrict__ dbcL,
    const float* __restrict__ sgb1, const float* __restrict__ sgb2,
    const float* __restrict__ sgc1, const float* __restrict__ sgc2,
    float* __restrict__ dbc)
{
    __shared__ float w1[2][192*16];
    __shared__ float w2[2][16*96];
    __shared__ float red[4][16][64];
    int tid = threadIdx.x;
    for (int i = tid; i < 192*16; i += 256) { w1[0][i] = sgb1[i]; w1[1][i] = sgc1[i]; }
    for (int i = tid; i < 16*96;  i += 256) { w2[0][i] = sgb2[i]; w2[1][i] = sgc2[i]; }
    int lq = tid & 63, p = tid >> 6;
    int l = blockIdx.x * 64 + lq;
    int b = blockIdx.y;
    size_t pb_ = (size_t)b*NCH*LL + l;
    __syncthreads();
    // dt channels passthrough sum (12 channels split 3 per p-group)
#pragma unroll
    for (int i = 0; i < 3; i++) {
        int c = p*3 + i;
        dbc[pb_ + (size_t)c*LL] = dbcH[pb_ + (size_t)c*LL] + dbcL[pb_ + (size_t)c*LL];
    }
    for (int gate = 0; gate < 2; gate++) {
        int coff = RK + gate*NST;
        float xin[16], og[16];
#pragma unroll
        for (int n = 0; n < 16; n++) { xin[n] = dbcL[pb_ + (size_t)(coff+n)*LL]; og[n] = 0.f; }
        int h0 = p * 24;
        for (int h = h0; h < h0 + 24; h++) {
            float ya = 0.f, yb = 0.f;
#pragma unroll
            for (int n = 0; n < 16; n++) {
                ya = fmaf(w1[gate][h*16+n], xin[n], ya);
                yb = fmaf(w1[gate][(h+SGH)*16+n], xin[n], yb);
            }
            float gg = 0.5f * ya * (1.f + erff(ya * 0.70710678f)) * yb;
#pragma unroll
            for (int n = 0; n < 16; n++) og[n] = fmaf(w2[gate][n*SGH+h], gg, og[n]);
        }
#pragma unroll
        for (int n = 0; n < 16; n++) red[p][n][lq] = og[n];
        __syncthreads();
#pragma unroll
        for (int i = 0; i < 4; i++) {
            int n = p*4 + i;
            float v = red[0][n][lq] + red[1][n][lq] + red[2][n][lq] + red[3][n][lq];
            dbc[pb_ + (size_t)(coff+n)*LL] = dbcH[pb_ + (size_t)(coff+n)*LL] + v;
        }
        __syncthreads();
    }
}

// -------- residual dilated dwconv1d on dbc -> dts / Bs / Cs -------------------
__global__ __launch_bounds__(256) void conv_dbc_kernel(const float* __restrict__ dbc,
    const float* __restrict__ wdt, const float* __restrict__ wB, const float* __restrict__ wC,
    float* __restrict__ dts, float* __restrict__ Bs, float* __restrict__ Cs)
{
    int l = blockIdx.x * 256 + threadIdx.x;
    int c = blockIdx.y, b = blockIdx.z;
    const float* wsrc = (c < RK) ? (wdt + c*15)
                      : (c < RK+NST ? wB + (c-RK)*15 : wC + (c-RK-NST)*15);
    float w[15];
#pragma unroll
    for (int k = 0; k < 15; k++) w[k] = wsrc[k];
    const float* P = dbc + ((size_t)b*NCH + c)*LL;
    float a = P[l];
#pragma unroll
    for (int k = 0; k < 15; k++) {
        int lt = l + 2*k - 14;
        if ((unsigned)lt < (unsigned)LL) a = fmaf(w[k], P[lt], a);
    }
    if (c < RK)            dts[((size_t)b*RK  + c)*LL + l] = a;
    else if (c < RK+NST)   Bs [((size_t)b*NST + (c-RK))*LL + l] = a;
    else                   Cs [((size_t)b*NST + (c-RK-NST))*LL + l] = a;
}

// -------- delta projection + softplus:  [B][DI][L] ----------------------------
__global__ __launch_bounds__(256) void delta_kernel(const float* __restrict__ dts,
    const float* __restrict__ dtw, const float* __restrict__ dtb, float* __restrict__ delta)
{
    __shared__ float sdt[RK][128];
    __shared__ float sw[64][RK];
    int tid = threadIdx.x;
    int l0 = blockIdx.x * 128, d0 = blockIdx.y * 64, b = blockIdx.z;
    for (int i = tid; i < RK*128; i += 256) {
        int r = i >> 7, lq = i & 127;
        sdt[r][lq] = dts[((size_t)b*RK + r)*LL + l0 + lq];
    }
    for (int i = tid; i < 64*RK; i += 256) {
        int dq = i / RK, r = i - dq*RK;
        sw[dq][r] = dtw[(size_t)(d0+dq)*RK + r];
    }
    __syncthreads();
    int lq = tid & 63, g = tid >> 6;
    for (int dd = 0; dd < 16; dd++) {
        int dqq = g*16 + dd, d = d0 + dqq;
        float wr[RK];
#pragma unroll
        for (int r = 0; r < RK; r++) wr[r] = sw[dqq][r];
        float bias = dtb[d];
#pragma unroll
        for (int li = 0; li < 2; li++) {
            int lloc = lq + li*64;
            float s = bias;
#pragma unroll
            for (int r = 0; r < RK; r++) s = fmaf(wr[r], sdt[r][lloc], s);
            float sp = fmaxf(s, 0.f) + log1pf(__expf(-fabsf(s)));
            delta[((size_t)b*DI + d)*LL + l0 + lloc] = sp;
        }
    }
}

// -------- selective scan: chunked parallel scan, one block per (b,d) ----------
__global__ __launch_bounds__(256) void scan_kernel(
    const float* __restrict__ u_, const float* __restrict__ delta_,
    const float* __restrict__ Bs_, const float* __restrict__ Cs_,
    const float* __restrict__ Alogs, const float* __restrict__ Ds,
    float* __restrict__ y_)
{
    __shared__ float sA[256][NST+1];
    __shared__ float sB[256][NST+1];
    int tid = threadIdx.x;
    int bd = blockIdx.x;
    int b = bd / DI, d = bd % DI;
    size_t base = ((size_t)b*DI + d)*LL + tid*16;
    float dl[16], du[16], yac[16];
    LD16(du, u_ + base);
    LD16(dl, delta_ + base);
    float Dd = Ds[d];
#pragma unroll
    for (int s = 0; s < 16; s++) { yac[s] = du[s]*Dd; du[s] = dl[s]*du[s]; }
    float Av[16];
#pragma unroll
    for (int n = 0; n < 16; n++) Av[n] = -__expf(Alogs[d*NST + n]);
    float ap[16], hv[16];
#pragma unroll
    for (int n = 0; n < 16; n++) {
        float Bn[16];
        LD16(Bn, Bs_ + ((size_t)b*NST + n)*LL + tid*16);
        float a = 1.f, h = 0.f, An = Av[n];
#pragma unroll
        for (int s = 0; s < 16; s++) {
            float e = __expf(dl[s]*An);
            h = fmaf(e, h, du[s]*Bn[s]);
            a *= e;
        }
        ap[n] = a; hv[n] = h;
    }
#pragma unroll
    for (int n = 0; n < 16; n++) { sA[tid][n] = ap[n]; sB[tid][n] = hv[n]; }
    for (int off = 1; off < 256; off <<= 1) {
        __syncthreads();
        float pa[16], pb[16];
        int src = tid - off;
        if (src >= 0) {
#pragma unroll
            for (int n = 0; n < 16; n++) { pa[n] = sA[src][n]; pb[n] = sB[src][n]; }
        }
        __syncthreads();
        if (src >= 0) {
#pragma unroll
            for (int n = 0; n < 16; n++) {
                hv[n] = fmaf(ap[n], pb[n], hv[n]);
                ap[n] = ap[n]*pa[n];
                sA[tid][n] = ap[n]; sB[tid][n] = hv[n];
            }
        }
    }
    __syncthreads();
    float hin[16];
#pragma unroll
    for (int n = 0; n < 16; n++) hin[n] = (tid > 0) ? sB[tid-1][n] : 0.f;
#pragma unroll
    for (int n = 0; n < 16; n++) {
        float Bn[16], Cn[16];
        LD16(Bn, Bs_ + ((size_t)b*NST + n)*LL + tid*16);
        LD16(Cn, Cs_ + ((size_t)b*NST + n)*LL + tid*16);
        float h = hin[n], An = Av[n];
#pragma unroll
        for (int s = 0; s < 16; s++) {
            float e = __expf(dl[s]*An);
            h = fmaf(e, h, du[s]*Bn[s]);
            yac[s] = fmaf(Cn[s], h, yac[s]);
        }
    }
    ST16(y_ + base, yac);
}

// -------- out-norm LN(384) + z-SiLU gating -> yg [B][DI][L] -------------------
// 256 blocks: 64 tokens/block, 4-way d-split + LDS reduce
__global__ __launch_bounds__(256) void outnorm_gate_kernel(const float* __restrict__ y,
    const float* __restrict__ z, const float* __restrict__ g, const float* __restrict__ bt,
    float* __restrict__ yg)
{
    __shared__ float rs_[4][64], rq_[4][64];
    __shared__ float mu_s[64], rstd_s[64];
    int tid = threadIdx.x;
    int lq = tid & 63, p = tid >> 6;
    int l = blockIdx.x * 64 + lq;
    int b = blockIdx.y;
    const float* yp = y + (size_t)b*DI*LL + l;
    float s = 0.f, q = 0.f;
#pragma unroll 4
    for (int i = 0; i < 96; i++) {
        int d = p*96 + i;
        float v = yp[(size_t)d*LL];
        s += v; q = fmaf(v, v, q);
    }
    rs_[p][lq] = s; rq_[p][lq] = q;
    __syncthreads();
    if (p == 0) {
        float ss = rs_[0][lq]+rs_[1][lq]+rs_[2][lq]+rs_[3][lq];
        float qq = rq_[0][lq]+rq_[1][lq]+rq_[2][lq]+rq_[3][lq];
        float mu = ss * (1.f/DI);
        float var = qq * (1.f/DI) - mu*mu;
        mu_s[lq] = mu; rstd_s[lq] = rsqrtf(var + 1e-5f);
    }
    __syncthreads();
    float mu = mu_s[lq], rs = rstd_s[lq];
    const float* zp = z + (size_t)b*DI*LL + l;
    float* op = yg + (size_t)b*DI*LL + l;
#pragma unroll 4
    for (int i = 0; i < 96; i++) {
        int d = p*96 + i;
        float v = (yp[(size_t)d*LL] - mu)*rs*g[d] + bt[d];
        float zv = zp[(size_t)d*LL];
        float sg = 1.f / (1.f + __expf(-zv));
        op[(size_t)d*LL] = v * (zv * sg);
    }
}

extern "C" void kernel_launch(void* const* d_in, const int* in_sizes, int n_in,
                              void* d_out, int out_size, void* d_ws, size_t ws_size,
                              hipStream_t stream)
{
    (void)in_sizes; (void)n_in; (void)out_size; (void)ws_size;
    const float* x     = (const float*)d_in[0];
    const float* low   = (const float*)d_in[1];
    const float* ln_g  = (const float*)d_in[2];
    const float* ln_b  = (const float*)d_in[3];
    const float* w_in  = (const float*)d_in[4];
    const float* w_low = (const float*)d_in[5];
    const float* w_c2d = (const float*)d_in[6];
    const float* b_c2d = (const float*)d_in[7];
    const float* w_xp  = (const float*)d_in[8];
    const float* w_xpl = (const float*)d_in[9];
    const float* w_cdt = (const float*)d_in[10];
    const float* w_cB  = (const float*)d_in[11];
    const float* w_cC  = (const float*)d_in[12];
    const float* sgb1  = (const float*)d_in[13];
    const float* sgb2  = (const float*)d_in[14];
    const float* sgc1  = (const float*)d_in[15];
    const float* sgc2  = (const float*)d_in[16];
    const float* dtw   = (const float*)d_in[17];
    const float* dtb   = (const float*)d_in[18];
    const float* Alogs = (const float*)d_in[19];
    const float* Ds    = (const float*)d_in[20];
    const float* ong   = (const float*)d_in[21];
    const float* onb   = (const float*)d_in[22];
    const float* w_out = (const float*)d_in[23];
    float* ws  = (float*)d_ws;
    float* out = (float*)d_out;
    dim3 blk(256);

    transpose_pad_kernel<<<576, blk, 0, stream>>>(w_in,  ws + O_WT_IN,  768, 192, 768);
    transpose_pad_kernel<<<288, blk, 0, stream>>>(w_low, ws + O_WT_LOW, 384, 192, 384);
    transpose_pad_kernel<<<96,  blk, 0, stream>>>(w_xp,  ws + O_WT_XP,  44,  384, 64);
    transpose_pad_kernel<<<96,  blk, 0, stream>>>(w_xpl, ws + O_WT_XPL, 44,  384, 64);
    transpose_pad_kernel<<<288, blk, 0, stream>>>(w_out, ws + O_WT_OUT, 192, 384, 192);

    ln_tr_kernel<<<256, blk, 0, stream>>>(x,   ln_g, ln_b, ws + O_XN,   1);
    ln_tr_kernel<<<256, blk, 0, stream>>>(low, ln_g, ln_b, ws + O_LOWT, 0);

    gemm_ta<0><<<dim3(256,12), blk, 0, stream>>>(ws+O_XN,   ws+O_WT_IN,  nullptr, ws+O_XH,   ws+O_Z, 192, 768, 768);
    gemm_ta<1><<<dim3(256,6),  blk, 0, stream>>>(ws+O_LOWT, ws+O_WT_LOW, nullptr, ws+O_LOWP, nullptr, 192, 384, 384);

    conv2d_silu_kernel<<<dim3(16,384,4), blk, 0, stream>>>(ws+O_XH, w_c2d, b_c2d, ws+O_XS);

    gemm_ta<1><<<dim3(256,1), blk, 0, stream>>>(ws+O_XS,   ws+O_WT_XP,  nullptr, ws+O_DBCH, nullptr, 384, 64, 44);
    gemm_ta<1><<<dim3(256,1), blk, 0, stream>>>(ws+O_LOWP, ws+O_WT_XPL, nullptr, ws+O_DBCL, nullptr, 384, 64, 44);

    gates_kernel<<<dim3(64,4), blk, 0, stream>>>(ws+O_DBCH, ws+O_DBCL, sgb1, sgb2, sgc1, sgc2, ws+O_DBC);

    conv_dbc_kernel<<<dim3(16,44,4), blk, 0, stream>>>(ws+O_DBC, w_cdt, w_cB, w_cC,
                                                       ws+O_DTS, ws+O_BS, ws+O_CS);
    delta_kernel<<<dim3(32,6,4), blk, 0, stream>>>(ws+O_DTS, dtw, dtb, ws+O_DELTA);

    scan_kernel<<<1536, blk, 0, stream>>>(ws+O_XS, ws+O_DELTA, ws+O_BS, ws+O_CS, Alogs, Ds, ws+O_Y);

    outnorm_gate_kernel<<<dim3(64,4), blk, 0, stream>>>(ws+O_Y, ws+O_Z, ong, onb, ws+O_YG);

    gemm_ta<2><<<dim3(256,3), blk, 0, stream>>>(ws+O_YG, ws+O_WT_OUT, x, out, nullptr, 384, 192, 192);
}

// Round 3
// 475.302 us; speedup vs baseline: 1.6965x; 1.0161x over previous
//
#include <hip/hip_runtime.h>
#include <math.h>

#define LL 4096
#define NBATCH 4
#define CM 192
#define DI 384
#define NST 16
#define RK 12
#define NCH 44
#define SGH 96

// workspace offsets (floats)
#define O_WT_IN   0
#define O_WT_LOW  147456
#define O_WT_XP   221184
#define O_WT_XPL  245760
#define O_WT_OUT  270336
#define O_XN      344064
#define O_LOWT    3489792
#define O_XH      6635520
#define O_Z       12926976
#define O_LOWP    19218432
#define O_XS      25509888
#define O_DBCH    31801344
#define O_DBCL    32522240
#define O_DBC     33243136
#define O_BS      33964032
#define O_CS      34226176
#define O_DELTA   O_LOWP   // lowp dead after x_proj GEMMs
#define O_Y       O_XH     // xh dead after conv2d
#define O_Y1      O_XN     // xn+lowT dead after in_proj GEMMs (spans DI*LL*NB exactly)
#define O_YG      O_XN     // yg overwrites y1 in-place (same-thread read-then-write)
#define O_DTS     O_DBCH   // dbcH dead after gates_kernel

#define LD16(dst, ptr) { const float4* _p = (const float4*)(ptr); \
  float4 _a=_p[0], _b=_p[1], _c=_p[2], _d=_p[3]; \
  dst[0]=_a.x; dst[1]=_a.y; dst[2]=_a.z; dst[3]=_a.w; \
  dst[4]=_b.x; dst[5]=_b.y; dst[6]=_b.z; dst[7]=_b.w; \
  dst[8]=_c.x; dst[9]=_c.y; dst[10]=_c.z; dst[11]=_c.w; \
  dst[12]=_d.x; dst[13]=_d.y; dst[14]=_d.z; dst[15]=_d.w; }
#define ST16(ptr, src) { float4* _p = (float4*)(ptr); \
  _p[0] = make_float4(src[0],src[1],src[2],src[3]); \
  _p[1] = make_float4(src[4],src[5],src[6],src[7]); \
  _p[2] = make_float4(src[8],src[9],src[10],src[11]); \
  _p[3] = make_float4(src[12],src[13],src[14],src[15]); }

// -------- weight transpose + pad:  in [N][K] -> out [K][N64] (zero padded) ----
__global__ void transpose_pad_kernel(const float* __restrict__ in, float* __restrict__ out,
                                     int N, int K, int N64)
{
    int idx = blockIdx.x * 256 + threadIdx.x;
    if (idx >= K * N64) return;
    int k = idx / N64, n = idx % N64;
    out[idx] = (n < N) ? in[n * K + k] : 0.f;
}

// -------- LayerNorm (optional) + transpose [T,192] -> [B][192][L] ------------
__global__ __launch_bounds__(256) void ln_tr_kernel(const float* __restrict__ X,
    const float* __restrict__ gw, const float* __restrict__ bw,
    float* __restrict__ out, int apply)
{
    __shared__ float xt[64][193];
    __shared__ float reds[64][4], redq[64][4];
    __shared__ float mu_s[64], rs_s[64];
    int tid = threadIdx.x;
    int t0 = blockIdx.x * 64;
    const float* Xb = X + (size_t)t0 * CM;
#pragma unroll
    for (int i = 0; i < 12; i++) {
        int f4 = tid + 256 * i;
        float4 v = *(const float4*)&Xb[f4 * 4];
        int row = f4 / 48, c = (f4 % 48) * 4;
        xt[row][c] = v.x; xt[row][c+1] = v.y; xt[row][c+2] = v.z; xt[row][c+3] = v.w;
    }
    __syncthreads();
    int tok = tid & 63, p = tid >> 6;
    if (apply) {
        float s = 0.f, q = 0.f;
#pragma unroll 8
        for (int i = 0; i < 48; i++) { float v = xt[tok][p*48+i]; s += v; q = fmaf(v, v, q); }
        reds[tok][p] = s; redq[tok][p] = q;
        __syncthreads();
        if (tid < 64) {
            float ss = reds[tid][0]+reds[tid][1]+reds[tid][2]+reds[tid][3];
            float qq = redq[tid][0]+redq[tid][1]+redq[tid][2]+redq[tid][3];
            float mu = ss * (1.f/CM);
            float var = qq * (1.f/CM) - mu*mu;
            mu_s[tid] = mu; rs_s[tid] = rsqrtf(var + 1e-5f);
        }
        __syncthreads();
    }
    int bb = t0 / LL, l0 = t0 % LL;
    float mu = apply ? mu_s[tok] : 0.f;
    float rs = apply ? rs_s[tok] : 1.f;
    for (int i = 0; i < 48; i++) {
        int c = p*48 + i;
        float v = xt[tok][c];
        if (apply) v = (v - mu) * rs * gw[c] + bw[c];
        out[((size_t)bb*CM + c)*LL + l0 + tok] = v;
    }
}

// -------- tiled GEMM: A channel-major [B][K][L], Wt [K][N64] ------------------
template<int MODE>
__global__ __launch_bounds__(256) void gemm_ta(
    const float* __restrict__ A, const float* __restrict__ Wt,
    const float* __restrict__ resid, float* __restrict__ out0,
    float* __restrict__ out1, int K, int N64, int Nreal)
{
    __shared__ __align__(16) float At[64][64];
    __shared__ __align__(16) float Wl[64][64];
    int tid = threadIdx.x;
    int t0 = blockIdx.x * 64;
    int b = t0 / LL, l0 = t0 % LL;
    int n0 = blockIdx.y * 64;
    const float* Ab = A + (size_t)b * K * LL;
    float acc[4][4] = {};
    int kr = tid >> 4;
    int m4 = (tid & 15) * 4;
    int r0 = m4;
    int c0 = kr * 4;
    for (int k0 = 0; k0 < K; k0 += 64) {
        __syncthreads();
#pragma unroll
        for (int i = 0; i < 4; i++) {
            int k = kr + i * 16;
            *(float4*)&At[k][m4] = *(const float4*)&Ab[(size_t)(k0+k)*LL + l0 + m4];
            *(float4*)&Wl[k][m4] = *(const float4*)&Wt[(size_t)(k0+k)*N64 + n0 + m4];
        }
        __syncthreads();
#pragma unroll
        for (int k = 0; k < 64; k++) {
            float4 a4 = *(const float4*)&At[k][r0];
            float4 w4 = *(const float4*)&Wl[k][c0];
            float av[4] = {a4.x, a4.y, a4.z, a4.w};
            float wv[4] = {w4.x, w4.y, w4.z, w4.w};
#pragma unroll
            for (int i = 0; i < 4; i++)
#pragma unroll
                for (int j = 0; j < 4; j++)
                    acc[i][j] = fmaf(av[i], wv[j], acc[i][j]);
        }
    }
#pragma unroll
    for (int i = 0; i < 4; i++) {
        int l = l0 + r0 + i;
        int t = t0 + r0 + i;
#pragma unroll
        for (int j = 0; j < 4; j++) {
            int n = n0 + c0 + j;
            float v = acc[i][j];
            if (MODE == 0) {
                if (n < DI) out0[((size_t)b*DI + n)*LL + l] = v;
                else        out1[((size_t)b*DI + (n-DI))*LL + l] = v;
            } else if (MODE == 1) {
                if (n < Nreal) out0[((size_t)b*Nreal + n)*LL + l] = v;
            } else {
                out0[(size_t)t*Nreal + n] = resid[(size_t)t*Nreal + n] + v;
            }
        }
    }
}

// -------- fused dual x_proj GEMM (blockIdx.z picks high/low branch) -----------
__global__ __launch_bounds__(256) void gemm_xproj(
    const float* __restrict__ A0, const float* __restrict__ W0, float* __restrict__ o0,
    const float* __restrict__ A1, const float* __restrict__ W1, float* __restrict__ o1,
    int K, int N64, int Nreal)
{
    __shared__ __align__(16) float At[64][64];
    __shared__ __align__(16) float Wl[64][64];
    const float* A  = blockIdx.z ? A1 : A0;
    const float* Wt = blockIdx.z ? W1 : W0;
    float* out0     = blockIdx.z ? o1 : o0;
    int tid = threadIdx.x;
    int t0 = blockIdx.x * 64;
    int b = t0 / LL, l0 = t0 % LL;
    int n0 = blockIdx.y * 64;
    const float* Ab = A + (size_t)b * K * LL;
    float acc[4][4] = {};
    int kr = tid >> 4;
    int m4 = (tid & 15) * 4;
    int r0 = m4;
    int c0 = kr * 4;
    for (int k0 = 0; k0 < K; k0 += 64) {
        __syncthreads();
#pragma unroll
        for (int i = 0; i < 4; i++) {
            int k = kr + i * 16;
            *(float4*)&At[k][m4] = *(const float4*)&Ab[(size_t)(k0+k)*LL + l0 + m4];
            *(float4*)&Wl[k][m4] = *(const float4*)&Wt[(size_t)(k0+k)*N64 + n0 + m4];
        }
        __syncthreads();
#pragma unroll
        for (int k = 0; k < 64; k++) {
            float4 a4 = *(const float4*)&At[k][r0];
            float4 w4 = *(const float4*)&Wl[k][c0];
            float av[4] = {a4.x, a4.y, a4.z, a4.w};
            float wv[4] = {w4.x, w4.y, w4.z, w4.w};
#pragma unroll
            for (int i = 0; i < 4; i++)
#pragma unroll
                for (int j = 0; j < 4; j++)
                    acc[i][j] = fmaf(av[i], wv[j], acc[i][j]);
        }
    }
#pragma unroll
    for (int i = 0; i < 4; i++) {
        int l = l0 + r0 + i;
#pragma unroll
        for (int j = 0; j < 4; j++) {
            int n = n0 + c0 + j;
            if (n < Nreal) out0[((size_t)b*Nreal + n)*LL + l] = acc[i][j];
        }
    }
}

// -------- depthwise 3x3 conv + bias + SiLU ------------------------------------
__global__ __launch_bounds__(256) void conv2d_silu_kernel(const float* __restrict__ xh,
    const float* __restrict__ w, const float* __restrict__ bias, float* __restrict__ xs)
{
    int tid = threadIdx.x;
    int l = blockIdx.x * 256 + tid;
    int c = blockIdx.y, b = blockIdx.z;
    const float* P = xh + ((size_t)b*DI + c)*LL;
    int h = l >> 6, ww = l & 63;
    float acc = bias[c];
#pragma unroll
    for (int kh = 0; kh < 3; kh++) {
        int hh = h + kh - 1;
        if ((unsigned)hh < 64u) {
#pragma unroll
            for (int kw = 0; kw < 3; kw++) {
                int wv = ww + kw - 1;
                if ((unsigned)wv < 64u) acc = fmaf(w[c*9 + kh*3 + kw], P[hh*64 + wv], acc);
            }
        }
    }
    float sg = 1.f / (1.f + __expf(-acc));
    xs[((size_t)b*DI + c)*LL + l] = acc * sg;
}

// -------- SimpleGates on low B/C + sum high+low -> dbc [B][44][L] -------------
__global__ __launch_bounds__(256) void gates_kernel(const float* __restrict__ dbcH,
    const float* __restrict__ dbcL,
    const float* __restrict__ sgb1, const float* __restrict__ sgb2,
    const float* __restrict__ sgc1, const float* __restrict__ sgc2,
    float* __restrict__ dbc)
{
    __shared__ float w1[2][192*16];
    __shared__ float w2[2][16*96];
    __shared__ float red[4][16][64];
    int tid = threadIdx.x;
    for (int i = tid; i < 192*16; i += 256) { w1[0][i] = sgb1[i]; w1[1][i] = sgc1[i]; }
    for (int i = tid; i < 16*96;  i += 256) { w2[0][i] = sgb2[i]; w2[1][i] = sgc2[i]; }
    int lq = tid & 63, p = tid >> 6;
    int l = blockIdx.x * 64 + lq;
    int b = blockIdx.y;
    size_t pb_ = (size_t)b*NCH*LL + l;
    __syncthreads();
#pragma unroll
    for (int i = 0; i < 3; i++) {
        int c = p*3 + i;
        dbc[pb_ + (size_t)c*LL] = dbcH[pb_ + (size_t)c*LL] + dbcL[pb_ + (size_t)c*LL];
    }
    for (int gate = 0; gate < 2; gate++) {
        int coff = RK + gate*NST;
        float xin[16], og[16];
#pragma unroll
        for (int n = 0; n < 16; n++) { xin[n] = dbcL[pb_ + (size_t)(coff+n)*LL]; og[n] = 0.f; }
        int h0 = p * 24;
        for (int h = h0; h < h0 + 24; h++) {
            float ya = 0.f, yb = 0.f;
#pragma unroll
            for (int n = 0; n < 16; n++) {
                ya = fmaf(w1[gate][h*16+n], xin[n], ya);
                yb = fmaf(w1[gate][(h+SGH)*16+n], xin[n], yb);
            }
            float gg = 0.5f * ya * (1.f + erff(ya * 0.70710678f)) * yb;
#pragma unroll
            for (int n = 0; n < 16; n++) og[n] = fmaf(w2[gate][n*SGH+h], gg, og[n]);
        }
#pragma unroll
        for (int n = 0; n < 16; n++) red[p][n][lq] = og[n];
        __syncthreads();
#pragma unroll
        for (int i = 0; i < 4; i++) {
            int n = p*4 + i;
            float v = red[0][n][lq] + red[1][n][lq] + red[2][n][lq] + red[3][n][lq];
            dbc[pb_ + (size_t)(coff+n)*LL] = dbcH[pb_ + (size_t)(coff+n)*LL] + v;
        }
        __syncthreads();
    }
}

// -------- residual dilated dwconv1d on dbc -> dts / Bs / Cs -------------------
__global__ __launch_bounds__(256) void conv_dbc_kernel(const float* __restrict__ dbc,
    const float* __restrict__ wdt, const float* __restrict__ wB, const float* __restrict__ wC,
    float* __restrict__ dts, float* __restrict__ Bs, float* __restrict__ Cs)
{
    int l = blockIdx.x * 256 + threadIdx.x;
    int c = blockIdx.y, b = blockIdx.z;
    const float* wsrc = (c < RK) ? (wdt + c*15)
                      : (c < RK+NST ? wB + (c-RK)*15 : wC + (c-RK-NST)*15);
    float w[15];
#pragma unroll
    for (int k = 0; k < 15; k++) w[k] = wsrc[k];
    const float* P = dbc + ((size_t)b*NCH + c)*LL;
    float a = P[l];
#pragma unroll
    for (int k = 0; k < 15; k++) {
        int lt = l + 2*k - 14;
        if ((unsigned)lt < (unsigned)LL) a = fmaf(w[k], P[lt], a);
    }
    if (c < RK)            dts[((size_t)b*RK  + c)*LL + l] = a;
    else if (c < RK+NST)   Bs [((size_t)b*NST + (c-RK))*LL + l] = a;
    else                   Cs [((size_t)b*NST + (c-RK-NST))*LL + l] = a;
}

// -------- delta projection + softplus:  [B][DI][L] ----------------------------
__global__ __launch_bounds__(256) void delta_kernel(const float* __restrict__ dts,
    const float* __restrict__ dtw, const float* __restrict__ dtb, float* __restrict__ delta)
{
    __shared__ float sdt[RK][128];
    __shared__ float sw[64][RK];
    int tid = threadIdx.x;
    int l0 = blockIdx.x * 128, d0 = blockIdx.y * 64, b = blockIdx.z;
    for (int i = tid; i < RK*128; i += 256) {
        int r = i >> 7, lq = i & 127;
        sdt[r][lq] = dts[((size_t)b*RK + r)*LL + l0 + lq];
    }
    for (int i = tid; i < 64*RK; i += 256) {
        int dq = i / RK, r = i - dq*RK;
        sw[dq][r] = dtw[(size_t)(d0+dq)*RK + r];
    }
    __syncthreads();
    int lq = tid & 63, g = tid >> 6;
    for (int dd = 0; dd < 16; dd++) {
        int dqq = g*16 + dd, d = d0 + dqq;
        float wr[RK];
#pragma unroll
        for (int r = 0; r < RK; r++) wr[r] = sw[dqq][r];
        float bias = dtb[d];
#pragma unroll
        for (int li = 0; li < 2; li++) {
            int lloc = lq + li*64;
            float s = bias;
#pragma unroll
            for (int r = 0; r < RK; r++) s = fmaf(wr[r], sdt[r][lloc], s);
            float sp = fmaxf(s, 0.f) + log1pf(__expf(-fabsf(s)));
            delta[((size_t)b*DI + d)*LL + l0 + lloc] = sp;
        }
    }
}

// -------- selective scan v2: state-split (8 states/block), shuffle scan -------
// block = 256 threads (4 waves), each thread scans a 16-step chunk.
// blockIdx.x = (b*DI+d)*2 + half. half0 handles states 0-7 (+D*u), half1 8-15.
// Cross-thread scan: wave shfl_up scan (no barriers) + one LDS wave handoff.
__global__ __launch_bounds__(256) void scan_kernel(
    const float* __restrict__ u_, const float* __restrict__ delta_,
    const float* __restrict__ Bs_, const float* __restrict__ Cs_,
    const float* __restrict__ Alogs, const float* __restrict__ Ds,
    float* __restrict__ y0_, float* __restrict__ y1_)
{
    __shared__ float wAs[4][8], wBs[4][8];
    int tid = threadIdx.x;
    int bid = blockIdx.x;
    int half = bid & 1, bd = bid >> 1;
    int b = bd / DI, d = bd % DI;
    int n0 = half * 8;
    size_t base = ((size_t)b*DI + d)*LL + tid*16;
    float dl[16], du[16], yac[16];
    LD16(du, u_ + base);
    LD16(dl, delta_ + base);
    float Dd = Ds[d];
#pragma unroll
    for (int s = 0; s < 16; s++) {
        yac[s] = half ? 0.f : du[s]*Dd;
        du[s] = dl[s]*du[s];
    }
    float Av[8];
#pragma unroll
    for (int j = 0; j < 8; j++) Av[j] = -__expf(Alogs[d*NST + n0 + j]);
    float ap[8], hv[8];
    // phase 1: local 16-step scan per state
#pragma unroll
    for (int j = 0; j < 8; j++) {
        float Bn[16];
        LD16(Bn, Bs_ + ((size_t)b*NST + n0 + j)*LL + tid*16);
        float a = 1.f, h = 0.f, An = Av[j];
#pragma unroll
        for (int s = 0; s < 16; s++) {
            float e = __expf(dl[s]*An);
            h = fmaf(e, h, du[s]*Bn[s]);
            a *= e;
        }
        ap[j] = a; hv[j] = h;
    }
    int lane = tid & 63, w = tid >> 6;
    // phase 2a: wave-level inclusive shuffle scan (register only)
    for (int off = 1; off < 64; off <<= 1) {
#pragma unroll
        for (int j = 0; j < 8; j++) {
            float pa = __shfl_up(ap[j], (unsigned)off, 64);
            float pb = __shfl_up(hv[j], (unsigned)off, 64);
            if (lane >= off) {
                hv[j] = fmaf(ap[j], pb, hv[j]);
                ap[j] *= pa;
            }
        }
    }
    // phase 2b: wave totals -> LDS
    if (lane == 63) {
#pragma unroll
        for (int j = 0; j < 8; j++) { wAs[w][j] = ap[j]; wBs[w][j] = hv[j]; }
    }
    __syncthreads();
    // phase 2c: compose prefix of preceding waves, apply, derive exclusive prefix
    float PB[8];
#pragma unroll
    for (int j = 0; j < 8; j++) PB[j] = 0.f;
    for (int ww = 0; ww < w; ww++) {
#pragma unroll
        for (int j = 0; j < 8; j++) PB[j] = fmaf(wAs[ww][j], PB[j], wBs[ww][j]);
    }
    float hin[8];
#pragma unroll
    for (int j = 0; j < 8; j++) {
        hv[j] = fmaf(ap[j], PB[j], hv[j]);      // global inclusive
        float t = __shfl_up(hv[j], 1u, 64);
        hin[j] = lane ? t : PB[j];              // global exclusive (state entering chunk)
    }
    // phase 3: recompute with incoming state, accumulate y = C . h
#pragma unroll
    for (int j = 0; j < 8; j++) {
        float Bn[16], Cn[16];
        LD16(Bn, Bs_ + ((size_t)b*NST + n0 + j)*LL + tid*16);
        LD16(Cn, Cs_ + ((size_t)b*NST + n0 + j)*LL + tid*16);
        float h = hin[j], An = Av[j];
#pragma unroll
        for (int s = 0; s < 16; s++) {
            float e = __expf(dl[s]*An);
            h = fmaf(e, h, du[s]*Bn[s]);
            yac[s] = fmaf(Cn[s], h, yac[s]);
        }
    }
    ST16((half ? y1_ : y0_) + base, yac);
}

// -------- out-norm LN(384) on y0+y1 + z-SiLU gating -> yg (in-place over y1) --
__global__ __launch_bounds__(256) void outnorm_gate_kernel(const float* __restrict__ y0,
    float* y1g, const float* __restrict__ z,
    const float* __restrict__ g, const float* __restrict__ bt)
{
    __shared__ float rs_[4][64], rq_[4][64];
    __shared__ float mu_s[64], rstd_s[64];
    int tid = threadIdx.x;
    int lq = tid & 63, p = tid >> 6;
    int l = blockIdx.x * 64 + lq;
    int b = blockIdx.y;
    const float* yp0 = y0 + (size_t)b*DI*LL + l;
    float* yp1 = y1g + (size_t)b*DI*LL + l;
    float s = 0.f, q = 0.f;
#pragma unroll 4
    for (int i = 0; i < 96; i++) {
        int d = p*96 + i;
        float v = yp0[(size_t)d*LL] + yp1[(size_t)d*LL];
        s += v; q = fmaf(v, v, q);
    }
    rs_[p][lq] = s; rq_[p][lq] = q;
    __syncthreads();
    if (p == 0) {
        float ss = rs_[0][lq]+rs_[1][lq]+rs_[2][lq]+rs_[3][lq];
        float qq = rq_[0][lq]+rq_[1][lq]+rq_[2][lq]+rq_[3][lq];
        float mu = ss * (1.f/DI);
        float var = qq * (1.f/DI) - mu*mu;
        mu_s[lq] = mu; rstd_s[lq] = rsqrtf(var + 1e-5f);
    }
    __syncthreads();
    float mu = mu_s[lq], rs = rstd_s[lq];
    const float* zp = z + (size_t)b*DI*LL + l;
#pragma unroll 4
    for (int i = 0; i < 96; i++) {
        int d = p*96 + i;
        float v = ((yp0[(size_t)d*LL] + yp1[(size_t)d*LL]) - mu)*rs*g[d] + bt[d];
        float zv = zp[(size_t)d*LL];
        float sg = 1.f / (1.f + __expf(-zv));
        yp1[(size_t)d*LL] = v * (zv * sg);
    }
}

extern "C" void kernel_launch(void* const* d_in, const int* in_sizes, int n_in,
                              void* d_out, int out_size, void* d_ws, size_t ws_size,
                              hipStream_t stream)
{
    (void)in_sizes; (void)n_in; (void)out_size; (void)ws_size;
    const float* x     = (const float*)d_in[0];
    const float* low   = (const float*)d_in[1];
    const float* ln_g  = (const float*)d_in[2];
    const float* ln_b  = (const float*)d_in[3];
    const float* w_in  = (const float*)d_in[4];
    const float* w_low = (const float*)d_in[5];
    const float* w_c2d = (const float*)d_in[6];
    const float* b_c2d = (const float*)d_in[7];
    const float* w_xp  = (const float*)d_in[8];
    const float* w_xpl = (const float*)d_in[9];
    const float* w_cdt = (const float*)d_in[10];
    const float* w_cB  = (const float*)d_in[11];
    const float* w_cC  = (const float*)d_in[12];
    const float* sgb1  = (const float*)d_in[13];
    const float* sgb2  = (const float*)d_in[14];
    const float* sgc1  = (const float*)d_in[15];
    const float* sgc2  = (const float*)d_in[16];
    const float* dtw   = (const float*)d_in[17];
    const float* dtb   = (const float*)d_in[18];
    const float* Alogs = (const float*)d_in[19];
    const float* Ds    = (const float*)d_in[20];
    const float* ong   = (const float*)d_in[21];
    const float* onb   = (const float*)d_in[22];
    const float* w_out = (const float*)d_in[23];
    float* ws  = (float*)d_ws;
    float* out = (float*)d_out;
    dim3 blk(256);

    transpose_pad_kernel<<<576, blk, 0, stream>>>(w_in,  ws + O_WT_IN,  768, 192, 768);
    transpose_pad_kernel<<<288, blk, 0, stream>>>(w_low, ws + O_WT_LOW, 384, 192, 384);
    transpose_pad_kernel<<<96,  blk, 0, stream>>>(w_xp,  ws + O_WT_XP,  44,  384, 64);
    transpose_pad_kernel<<<96,  blk, 0, stream>>>(w_xpl, ws + O_WT_XPL, 44,  384, 64);
    transpose_pad_kernel<<<288, blk, 0, stream>>>(w_out, ws + O_WT_OUT, 192, 384, 192);

    ln_tr_kernel<<<256, blk, 0, stream>>>(x,   ln_g, ln_b, ws + O_XN,   1);
    ln_tr_kernel<<<256, blk, 0, stream>>>(low, ln_g, ln_b, ws + O_LOWT, 0);

    gemm_ta<0><<<dim3(256,12), blk, 0, stream>>>(ws+O_XN,   ws+O_WT_IN,  nullptr, ws+O_XH,   ws+O_Z, 192, 768, 768);
    gemm_ta<1><<<dim3(256,6),  blk, 0, stream>>>(ws+O_LOWT, ws+O_WT_LOW, nullptr, ws+O_LOWP, nullptr, 192, 384, 384);

    conv2d_silu_kernel<<<dim3(16,384,4), blk, 0, stream>>>(ws+O_XH, w_c2d, b_c2d, ws+O_XS);

    gemm_xproj<<<dim3(256,1,2), blk, 0, stream>>>(ws+O_XS, ws+O_WT_XP, ws+O_DBCH,
                                                  ws+O_LOWP, ws+O_WT_XPL, ws+O_DBCL, 384, 64, 44);

    gates_kernel<<<dim3(64,4), blk, 0, stream>>>(ws+O_DBCH, ws+O_DBCL, sgb1, sgb2, sgc1, sgc2, ws+O_DBC);

    conv_dbc_kernel<<<dim3(16,44,4), blk, 0, stream>>>(ws+O_DBC, w_cdt, w_cB, w_cC,
                                                       ws+O_DTS, ws+O_BS, ws+O_CS);
    delta_kernel<<<dim3(32,6,4), blk, 0, stream>>>(ws+O_DTS, dtw, dtb, ws+O_DELTA);

    scan_kernel<<<3072, blk, 0, stream>>>(ws+O_XS, ws+O_DELTA, ws+O_BS, ws+O_CS, Alogs, Ds,
                                          ws+O_Y, ws+O_Y1);

    outnorm_gate_kernel<<<dim3(64,4), blk, 0, stream>>>(ws+O_Y, ws+O_Y1, ws+O_Z, ong, onb);

    gemm_ta<2><<<dim3(256,3), blk, 0, stream>>>(ws+O_YG, ws+O_WT_OUT, x, out, nullptr, 384, 192, 192);
}

// Round 4
// 398.150 us; speedup vs baseline: 2.0252x; 1.1938x over previous
//
#include <hip/hip_runtime.h>
#include <math.h>

#define LL 4096
#define NBATCH 4
#define CM 192
#define DI 384
#define NST 16
#define RK 12
#define NCH 44
#define SGH 96

// workspace offsets (floats)
#define O_WT_IN   0
#define O_WT_LOW  147456
#define O_WT_XP   221184
#define O_WT_XPL  245760
#define O_WT_OUT  270336
#define O_XN      344064
#define O_LOWT    3489792
#define O_XH      6635520
#define O_Z       12926976
#define O_LOWP    19218432
#define O_XS      25509888
#define O_DBCH    31801344
#define O_DBCL    32522240
#define O_DBC     33243136
#define O_BS      33964032
#define O_CS      34226176
#define O_DELTA   O_LOWP   // lowp dead after x_proj GEMMs
#define O_Y       O_XH     // xh dead after conv2d
#define O_Y1      O_XN     // xn+lowT dead after in_proj GEMMs (spans DI*LL*NB exactly)
#define O_YG      O_XN     // yg overwrites y1 in-place (same-thread read-then-write)
#define O_DTS     O_DBCH   // dbcH dead after gates_kernel

// ---- chunk-transposed ("perm") layout within each 4096-element row ----------
// element l = t*16 + i4*4 + j  stored at  i4*1024 + t*4 + j
// scan thread t: 4 float4 loads at {0,1024,2048,3072} + t*4 -> fully coalesced
__device__ __forceinline__ int permidx(int l) {
    return ((l >> 2) & 3) * 1024 + ((l >> 4) << 2) + (l & 3);
}

#define LD16P(dst, row, t4) { \
  float4 _a = *(const float4*)((row) + (t4)); \
  float4 _b = *(const float4*)((row) + 1024 + (t4)); \
  float4 _c = *(const float4*)((row) + 2048 + (t4)); \
  float4 _d = *(const float4*)((row) + 3072 + (t4)); \
  dst[0]=_a.x; dst[1]=_a.y; dst[2]=_a.z; dst[3]=_a.w; \
  dst[4]=_b.x; dst[5]=_b.y; dst[6]=_b.z; dst[7]=_b.w; \
  dst[8]=_c.x; dst[9]=_c.y; dst[10]=_c.z; dst[11]=_c.w; \
  dst[12]=_d.x; dst[13]=_d.y; dst[14]=_d.z; dst[15]=_d.w; }

// -------- weight transpose + pad:  in [N][K] -> out [K][N64] (zero padded) ----
__global__ void transpose_pad_kernel(const float* __restrict__ in, float* __restrict__ out,
                                     int N, int K, int N64)
{
    int idx = blockIdx.x * 256 + threadIdx.x;
    if (idx >= K * N64) return;
    int k = idx / N64, n = idx % N64;
    out[idx] = (n < N) ? in[n * K + k] : 0.f;
}

// -------- LayerNorm (optional) + transpose [T,192] -> [B][192][L] ------------
__global__ __launch_bounds__(256) void ln_tr_kernel(const float* __restrict__ X,
    const float* __restrict__ gw, const float* __restrict__ bw,
    float* __restrict__ out, int apply)
{
    __shared__ float xt[64][193];
    __shared__ float reds[64][4], redq[64][4];
    __shared__ float mu_s[64], rs_s[64];
    int tid = threadIdx.x;
    int t0 = blockIdx.x * 64;
    const float* Xb = X + (size_t)t0 * CM;
#pragma unroll
    for (int i = 0; i < 12; i++) {
        int f4 = tid + 256 * i;
        float4 v = *(const float4*)&Xb[f4 * 4];
        int row = f4 / 48, c = (f4 % 48) * 4;
        xt[row][c] = v.x; xt[row][c+1] = v.y; xt[row][c+2] = v.z; xt[row][c+3] = v.w;
    }
    __syncthreads();
    int tok = tid & 63, p = tid >> 6;
    if (apply) {
        float s = 0.f, q = 0.f;
#pragma unroll 8
        for (int i = 0; i < 48; i++) { float v = xt[tok][p*48+i]; s += v; q = fmaf(v, v, q); }
        reds[tok][p] = s; redq[tok][p] = q;
        __syncthreads();
        if (tid < 64) {
            float ss = reds[tid][0]+reds[tid][1]+reds[tid][2]+reds[tid][3];
            float qq = redq[tid][0]+redq[tid][1]+redq[tid][2]+redq[tid][3];
            float mu = ss * (1.f/CM);
            float var = qq * (1.f/CM) - mu*mu;
            mu_s[tid] = mu; rs_s[tid] = rsqrtf(var + 1e-5f);
        }
        __syncthreads();
    }
    int bb = t0 / LL, l0 = t0 % LL;
    float mu = apply ? mu_s[tok] : 0.f;
    float rs = apply ? rs_s[tok] : 1.f;
    for (int i = 0; i < 48; i++) {
        int c = p*48 + i;
        float v = xt[tok][c];
        if (apply) v = (v - mu) * rs * gw[c] + bw[c];
        out[((size_t)bb*CM + c)*LL + l0 + tok] = v;
    }
}

// -------- tiled GEMM: A channel-major [B][K][L], Wt [K][N64] ------------------
template<int MODE>
__global__ __launch_bounds__(256) void gemm_ta(
    const float* __restrict__ A, const float* __restrict__ Wt,
    const float* __restrict__ resid, float* __restrict__ out0,
    float* __restrict__ out1, int K, int N64, int Nreal)
{
    __shared__ __align__(16) float At[64][64];
    __shared__ __align__(16) float Wl[64][64];
    int tid = threadIdx.x;
    int t0 = blockIdx.x * 64;
    int b = t0 / LL, l0 = t0 % LL;
    int n0 = blockIdx.y * 64;
    const float* Ab = A + (size_t)b * K * LL;
    float acc[4][4] = {};
    int kr = tid >> 4;
    int m4 = (tid & 15) * 4;
    int r0 = m4;
    int c0 = kr * 4;
    for (int k0 = 0; k0 < K; k0 += 64) {
        __syncthreads();
#pragma unroll
        for (int i = 0; i < 4; i++) {
            int k = kr + i * 16;
            *(float4*)&At[k][m4] = *(const float4*)&Ab[(size_t)(k0+k)*LL + l0 + m4];
            *(float4*)&Wl[k][m4] = *(const float4*)&Wt[(size_t)(k0+k)*N64 + n0 + m4];
        }
        __syncthreads();
#pragma unroll
        for (int k = 0; k < 64; k++) {
            float4 a4 = *(const float4*)&At[k][r0];
            float4 w4 = *(const float4*)&Wl[k][c0];
            float av[4] = {a4.x, a4.y, a4.z, a4.w};
            float wv[4] = {w4.x, w4.y, w4.z, w4.w};
#pragma unroll
            for (int i = 0; i < 4; i++)
#pragma unroll
                for (int j = 0; j < 4; j++)
                    acc[i][j] = fmaf(av[i], wv[j], acc[i][j]);
        }
    }
#pragma unroll
    for (int i = 0; i < 4; i++) {
        int l = l0 + r0 + i;
        int t = t0 + r0 + i;
#pragma unroll
        for (int j = 0; j < 4; j++) {
            int n = n0 + c0 + j;
            float v = acc[i][j];
            if (MODE == 0) {
                if (n < DI) out0[((size_t)b*DI + n)*LL + l] = v;
                else        out1[((size_t)b*DI + (n-DI))*LL + l] = v;
            } else if (MODE == 1) {
                if (n < Nreal) out0[((size_t)b*Nreal + n)*LL + l] = v;
            } else {
                out0[(size_t)t*Nreal + n] = resid[(size_t)t*Nreal + n] + v;
            }
        }
    }
}

// -------- fused dual x_proj GEMM (z=0: xs in PERM layout; z=1: lowp normal) ---
__global__ __launch_bounds__(256) void gemm_xproj(
    const float* __restrict__ A0, const float* __restrict__ W0, float* __restrict__ o0,
    const float* __restrict__ A1, const float* __restrict__ W1, float* __restrict__ o1,
    int K, int N64, int Nreal)
{
    __shared__ __align__(16) float At[64][64];
    __shared__ __align__(16) float Wl[64][64];
    int permA = (blockIdx.z == 0);
    const float* A  = blockIdx.z ? A1 : A0;
    const float* Wt = blockIdx.z ? W1 : W0;
    float* out0     = blockIdx.z ? o1 : o0;
    int tid = threadIdx.x;
    int t0 = blockIdx.x * 64;
    int b = t0 / LL, l0 = t0 % LL;
    int n0 = blockIdx.y * 64;
    const float* Ab = A + (size_t)b * K * LL;
    float acc[4][4] = {};
    int kr = tid >> 4;
    int m4 = (tid & 15) * 4;
    int r0 = m4;
    int c0 = kr * 4;
    // A-tile float4 offset within row (perm layout keeps j 0..3 contiguous)
    int pA = permA ? (((m4 >> 2) & 3) * 1024 + (((l0 + m4) >> 4) << 2)) : (l0 + m4);
    for (int k0 = 0; k0 < K; k0 += 64) {
        __syncthreads();
#pragma unroll
        for (int i = 0; i < 4; i++) {
            int k = kr + i * 16;
            *(float4*)&At[k][m4] = *(const float4*)&Ab[(size_t)(k0+k)*LL + pA];
            *(float4*)&Wl[k][m4] = *(const float4*)&Wt[(size_t)(k0+k)*N64 + n0 + m4];
        }
        __syncthreads();
#pragma unroll
        for (int k = 0; k < 64; k++) {
            float4 a4 = *(const float4*)&At[k][r0];
            float4 w4 = *(const float4*)&Wl[k][c0];
            float av[4] = {a4.x, a4.y, a4.z, a4.w};
            float wv[4] = {w4.x, w4.y, w4.z, w4.w};
#pragma unroll
            for (int i = 0; i < 4; i++)
#pragma unroll
                for (int j = 0; j < 4; j++)
                    acc[i][j] = fmaf(av[i], wv[j], acc[i][j]);
        }
    }
#pragma unroll
    for (int i = 0; i < 4; i++) {
        int l = l0 + r0 + i;
#pragma unroll
        for (int j = 0; j < 4; j++) {
            int n = n0 + c0 + j;
            if (n < Nreal) out0[((size_t)b*Nreal + n)*LL + l] = acc[i][j];
        }
    }
}

// -------- depthwise 3x3 conv + bias + SiLU -> xs in PERM layout ---------------
__global__ __launch_bounds__(256) void conv2d_silu_kernel(const float* __restrict__ xh,
    const float* __restrict__ w, const float* __restrict__ bias, float* __restrict__ xs)
{
    int tid = threadIdx.x;
    int l = blockIdx.x * 256 + tid;
    int c = blockIdx.y, b = blockIdx.z;
    const float* P = xh + ((size_t)b*DI + c)*LL;
    int h = l >> 6, ww = l & 63;
    float acc = bias[c];
#pragma unroll
    for (int kh = 0; kh < 3; kh++) {
        int hh = h + kh - 1;
        if ((unsigned)hh < 64u) {
#pragma unroll
            for (int kw = 0; kw < 3; kw++) {
                int wv = ww + kw - 1;
                if ((unsigned)wv < 64u) acc = fmaf(w[c*9 + kh*3 + kw], P[hh*64 + wv], acc);
            }
        }
    }
    float sg = 1.f / (1.f + __expf(-acc));
    xs[((size_t)b*DI + c)*LL + permidx(l)] = acc * sg;
}

// -------- SimpleGates on low B/C + sum high+low -> dbc [B][44][L] -------------
__global__ __launch_bounds__(256) void gates_kernel(const float* __restrict__ dbcH,
    const float* __restrict__ dbcL,
    const float* __restrict__ sgb1, const float* __restrict__ sgb2,
    const float* __restrict__ sgc1, const float* __restrict__ sgc2,
    float* __restrict__ dbc)
{
    __shared__ float w1[2][192*16];
    __shared__ float w2[2][16*96];
    __shared__ float red[4][16][64];
    int tid = threadIdx.x;
    for (int i = tid; i < 192*16; i += 256) { w1[0][i] = sgb1[i]; w1[1][i] = sgc1[i]; }
    for (int i = tid; i < 16*96;  i += 256) { w2[0][i] = sgb2[i]; w2[1][i] = sgc2[i]; }
    int lq = tid & 63, p = tid >> 6;
    int l = blockIdx.x * 64 + lq;
    int b = blockIdx.y;
    size_t pb_ = (size_t)b*NCH*LL + l;
    __syncthreads();
#pragma unroll
    for (int i = 0; i < 3; i++) {
        int c = p*3 + i;
        dbc[pb_ + (size_t)c*LL] = dbcH[pb_ + (size_t)c*LL] + dbcL[pb_ + (size_t)c*LL];
    }
    for (int gate = 0; gate < 2; gate++) {
        int coff = RK + gate*NST;
        float xin[16], og[16];
#pragma unroll
        for (int n = 0; n < 16; n++) { xin[n] = dbcL[pb_ + (size_t)(coff+n)*LL]; og[n] = 0.f; }
        int h0 = p * 24;
        for (int h = h0; h < h0 + 24; h++) {
            float ya = 0.f, yb = 0.f;
#pragma unroll
            for (int n = 0; n < 16; n++) {
                ya = fmaf(w1[gate][h*16+n], xin[n], ya);
                yb = fmaf(w1[gate][(h+SGH)*16+n], xin[n], yb);
            }
            float gg = 0.5f * ya * (1.f + erff(ya * 0.70710678f)) * yb;
#pragma unroll
            for (int n = 0; n < 16; n++) og[n] = fmaf(w2[gate][n*SGH+h], gg, og[n]);
        }
#pragma unroll
        for (int n = 0; n < 16; n++) red[p][n][lq] = og[n];
        __syncthreads();
#pragma unroll
        for (int i = 0; i < 4; i++) {
            int n = p*4 + i;
            float v = red[0][n][lq] + red[1][n][lq] + red[2][n][lq] + red[3][n][lq];
            dbc[pb_ + (size_t)(coff+n)*LL] = dbcH[pb_ + (size_t)(coff+n)*LL] + v;
        }
        __syncthreads();
    }
}

// -------- residual dilated dwconv1d: dts normal; Bs/Cs in PERM layout ---------
__global__ __launch_bounds__(256) void conv_dbc_kernel(const float* __restrict__ dbc,
    const float* __restrict__ wdt, const float* __restrict__ wB, const float* __restrict__ wC,
    float* __restrict__ dts, float* __restrict__ Bs, float* __restrict__ Cs)
{
    int l = blockIdx.x * 256 + threadIdx.x;
    int c = blockIdx.y, b = blockIdx.z;
    const float* wsrc = (c < RK) ? (wdt + c*15)
                      : (c < RK+NST ? wB + (c-RK)*15 : wC + (c-RK-NST)*15);
    float w[15];
#pragma unroll
    for (int k = 0; k < 15; k++) w[k] = wsrc[k];
    const float* P = dbc + ((size_t)b*NCH + c)*LL;
    float a = P[l];
#pragma unroll
    for (int k = 0; k < 15; k++) {
        int lt = l + 2*k - 14;
        if ((unsigned)lt < (unsigned)LL) a = fmaf(w[k], P[lt], a);
    }
    if (c < RK)            dts[((size_t)b*RK  + c)*LL + l] = a;
    else if (c < RK+NST)   Bs [((size_t)b*NST + (c-RK))*LL + permidx(l)] = a;
    else                   Cs [((size_t)b*NST + (c-RK-NST))*LL + permidx(l)] = a;
}

// -------- delta projection + softplus -> delta in PERM layout -----------------
__global__ __launch_bounds__(256) void delta_kernel(const float* __restrict__ dts,
    const float* __restrict__ dtw, const float* __restrict__ dtb, float* __restrict__ delta)
{
    __shared__ float sdt[RK][128];
    __shared__ float sw[64][RK];
    int tid = threadIdx.x;
    int l0 = blockIdx.x * 128, d0 = blockIdx.y * 64, b = blockIdx.z;
    for (int i = tid; i < RK*128; i += 256) {
        int r = i >> 7, lq = i & 127;
        sdt[r][lq] = dts[((size_t)b*RK + r)*LL + l0 + lq];
    }
    for (int i = tid; i < 64*RK; i += 256) {
        int dq = i / RK, r = i - dq*RK;
        sw[dq][r] = dtw[(size_t)(d0+dq)*RK + r];
    }
    __syncthreads();
    int lq = tid & 63, g = tid >> 6;
    for (int dd = 0; dd < 16; dd++) {
        int dqq = g*16 + dd, d = d0 + dqq;
        float wr[RK];
#pragma unroll
        for (int r = 0; r < RK; r++) wr[r] = sw[dqq][r];
        float bias = dtb[d];
#pragma unroll
        for (int li = 0; li < 2; li++) {
            int lloc = lq + li*64;
            float s = bias;
#pragma unroll
            for (int r = 0; r < RK; r++) s = fmaf(wr[r], sdt[r][lloc], s);
            float sp = fmaxf(s, 0.f) + log1pf(__expf(-fabsf(s)));
            delta[((size_t)b*DI + d)*LL + permidx(l0 + lloc)] = sp;
        }
    }
}

// -------- selective scan v3: PERM-layout coalesced loads, LDS-transposed store
// block = 256 threads (4 waves); blockIdx.x = (b*DI+d)*2 + half (8 states each)
__global__ __launch_bounds__(256) void scan_kernel(
    const float* __restrict__ u_, const float* __restrict__ delta_,
    const float* __restrict__ Bs_, const float* __restrict__ Cs_,
    const float* __restrict__ Alogs, const float* __restrict__ Ds,
    float* __restrict__ y0_, float* __restrict__ y1_)
{
    __shared__ float wAs[4][8], wBs[4][8];
    __shared__ float yt[16][258];
    int tid = threadIdx.x;
    int t4 = tid * 4;
    int bid = blockIdx.x;
    int half = bid & 1, bd = bid >> 1;
    int b = bd / DI, d = bd % DI;
    int n0 = half * 8;
    size_t rowoff = ((size_t)b*DI + d)*LL;
    float dl[16], du[16], yac[16];
    LD16P(du, u_ + rowoff, t4);
    LD16P(dl, delta_ + rowoff, t4);
    float Dd = Ds[d];
#pragma unroll
    for (int s = 0; s < 16; s++) {
        yac[s] = half ? 0.f : du[s]*Dd;
        du[s] = dl[s]*du[s];
    }
    float Av[8];
#pragma unroll
    for (int j = 0; j < 8; j++) Av[j] = -__expf(Alogs[d*NST + n0 + j]);
    float ap[8], hv[8];
    // phase 1: local 16-step scan per state
#pragma unroll
    for (int j = 0; j < 8; j++) {
        float Bn[16];
        LD16P(Bn, Bs_ + ((size_t)b*NST + n0 + j)*LL, t4);
        float a = 1.f, h = 0.f, An = Av[j];
#pragma unroll
        for (int s = 0; s < 16; s++) {
            float e = __expf(dl[s]*An);
            h = fmaf(e, h, du[s]*Bn[s]);
            a *= e;
        }
        ap[j] = a; hv[j] = h;
    }
    int lane = tid & 63, w = tid >> 6;
    // phase 2a: wave-level inclusive shuffle scan (register only)
    for (int off = 1; off < 64; off <<= 1) {
#pragma unroll
        for (int j = 0; j < 8; j++) {
            float pa = __shfl_up(ap[j], (unsigned)off, 64);
            float pb = __shfl_up(hv[j], (unsigned)off, 64);
            if (lane >= off) {
                hv[j] = fmaf(ap[j], pb, hv[j]);
                ap[j] *= pa;
            }
        }
    }
    // phase 2b: wave totals -> LDS
    if (lane == 63) {
#pragma unroll
        for (int j = 0; j < 8; j++) { wAs[w][j] = ap[j]; wBs[w][j] = hv[j]; }
    }
    __syncthreads();
    // phase 2c: compose prefix of preceding waves, derive exclusive prefix
    float PB[8];
#pragma unroll
    for (int j = 0; j < 8; j++) PB[j] = 0.f;
    for (int ww = 0; ww < w; ww++) {
#pragma unroll
        for (int j = 0; j < 8; j++) PB[j] = fmaf(wAs[ww][j], PB[j], wBs[ww][j]);
    }
    float hin[8];
#pragma unroll
    for (int j = 0; j < 8; j++) {
        hv[j] = fmaf(ap[j], PB[j], hv[j]);      // global inclusive
        float t = __shfl_up(hv[j], 1u, 64);
        hin[j] = lane ? t : PB[j];              // global exclusive (state entering chunk)
    }
    // phase 3: recompute with incoming state, accumulate y = C . h
#pragma unroll
    for (int j = 0; j < 8; j++) {
        float Bn[16], Cn[16];
        LD16P(Bn, Bs_ + ((size_t)b*NST + n0 + j)*LL, t4);
        LD16P(Cn, Cs_ + ((size_t)b*NST + n0 + j)*LL, t4);
        float h = hin[j], An = Av[j];
#pragma unroll
        for (int s = 0; s < 16; s++) {
            float e = __expf(dl[s]*An);
            h = fmaf(e, h, du[s]*Bn[s]);
            yac[s] = fmaf(Cn[s], h, yac[s]);
        }
    }
    // store: LDS transpose -> coalesced normal-layout write
#pragma unroll
    for (int i = 0; i < 16; i++) yt[i][tid] = yac[i];
    __syncthreads();
    float* yout = (half ? y1_ : y0_) + rowoff;
#pragma unroll
    for (int r = 0; r < 16; r++)
        yout[r*256 + tid] = yt[tid & 15][r*16 + (tid >> 4)];
}

// -------- out-norm LN(384) on y0+y1 + z-SiLU gating -> yg (in-place over y1) --
__global__ __launch_bounds__(256) void outnorm_gate_kernel(const float* __restrict__ y0,
    float* y1g, const float* __restrict__ z,
    const float* __restrict__ g, const float* __restrict__ bt)
{
    __shared__ float rs_[4][64], rq_[4][64];
    __shared__ float mu_s[64], rstd_s[64];
    int tid = threadIdx.x;
    int lq = tid & 63, p = tid >> 6;
    int l = blockIdx.x * 64 + lq;
    int b = blockIdx.y;
    const float* yp0 = y0 + (size_t)b*DI*LL + l;
    float* yp1 = y1g + (size_t)b*DI*LL + l;
    float s = 0.f, q = 0.f;
#pragma unroll 4
    for (int i = 0; i < 96; i++) {
        int d = p*96 + i;
        float v = yp0[(size_t)d*LL] + yp1[(size_t)d*LL];
        s += v; q = fmaf(v, v, q);
    }
    rs_[p][lq] = s; rq_[p][lq] = q;
    __syncthreads();
    if (p == 0) {
        float ss = rs_[0][lq]+rs_[1][lq]+rs_[2][lq]+rs_[3][lq];
        float qq = rq_[0][lq]+rq_[1][lq]+rq_[2][lq]+rq_[3][lq];
        float mu = ss * (1.f/DI);
        float var = qq * (1.f/DI) - mu*mu;
        mu_s[lq] = mu; rstd_s[lq] = rsqrtf(var + 1e-5f);
    }
    __syncthreads();
    float mu = mu_s[lq], rs = rstd_s[lq];
    const float* zp = z + (size_t)b*DI*LL + l;
#pragma unroll 4
    for (int i = 0; i < 96; i++) {
        int d = p*96 + i;
        float v = ((yp0[(size_t)d*LL] + yp1[(size_t)d*LL]) - mu)*rs*g[d] + bt[d];
        float zv = zp[(size_t)d*LL];
        float sg = 1.f / (1.f + __expf(-zv));
        yp1[(size_t)d*LL] = v * (zv * sg);
    }
}

extern "C" void kernel_launch(void* const* d_in, const int* in_sizes, int n_in,
                              void* d_out, int out_size, void* d_ws, size_t ws_size,
                              hipStream_t stream)
{
    (void)in_sizes; (void)n_in; (void)out_size; (void)ws_size;
    const float* x     = (const float*)d_in[0];
    const float* low   = (const float*)d_in[1];
    const float* ln_g  = (const float*)d_in[2];
    const float* ln_b  = (const float*)d_in[3];
    const float* w_in  = (const float*)d_in[4];
    const float* w_low = (const float*)d_in[5];
    const float* w_c2d = (const float*)d_in[6];
    const float* b_c2d = (const float*)d_in[7];
    const float* w_xp  = (const float*)d_in[8];
    const float* w_xpl = (const float*)d_in[9];
    const float* w_cdt = (const float*)d_in[10];
    const float* w_cB  = (const float*)d_in[11];
    const float* w_cC  = (const float*)d_in[12];
    const float* sgb1  = (const float*)d_in[13];
    const float* sgb2  = (const float*)d_in[14];
    const float* sgc1  = (const float*)d_in[15];
    const float* sgc2  = (const float*)d_in[16];
    const float* dtw   = (const float*)d_in[17];
    const float* dtb   = (const float*)d_in[18];
    const float* Alogs = (const float*)d_in[19];
    const float* Ds    = (const float*)d_in[20];
    const float* ong   = (const float*)d_in[21];
    const float* onb   = (const float*)d_in[22];
    const float* w_out = (const float*)d_in[23];
    float* ws  = (float*)d_ws;
    float* out = (float*)d_out;
    dim3 blk(256);

    transpose_pad_kernel<<<576, blk, 0, stream>>>(w_in,  ws + O_WT_IN,  768, 192, 768);
    transpose_pad_kernel<<<288, blk, 0, stream>>>(w_low, ws + O_WT_LOW, 384, 192, 384);
    transpose_pad_kernel<<<96,  blk, 0, stream>>>(w_xp,  ws + O_WT_XP,  44,  384, 64);
    transpose_pad_kernel<<<96,  blk, 0, stream>>>(w_xpl, ws + O_WT_XPL, 44,  384, 64);
    transpose_pad_kernel<<<288, blk, 0, stream>>>(w_out, ws + O_WT_OUT, 192, 384, 192);

    ln_tr_kernel<<<256, blk, 0, stream>>>(x,   ln_g, ln_b, ws + O_XN,   1);
    ln_tr_kernel<<<256, blk, 0, stream>>>(low, ln_g, ln_b, ws + O_LOWT, 0);

    gemm_ta<0><<<dim3(256,12), blk, 0, stream>>>(ws+O_XN,   ws+O_WT_IN,  nullptr, ws+O_XH,   ws+O_Z, 192, 768, 768);
    gemm_ta<1><<<dim3(256,6),  blk, 0, stream>>>(ws+O_LOWT, ws+O_WT_LOW, nullptr, ws+O_LOWP, nullptr, 192, 384, 384);

    conv2d_silu_kernel<<<dim3(16,384,4), blk, 0, stream>>>(ws+O_XH, w_c2d, b_c2d, ws+O_XS);

    gemm_xproj<<<dim3(256,1,2), blk, 0, stream>>>(ws+O_XS, ws+O_WT_XP, ws+O_DBCH,
                                                  ws+O_LOWP, ws+O_WT_XPL, ws+O_DBCL, 384, 64, 44);

    gates_kernel<<<dim3(64,4), blk, 0, stream>>>(ws+O_DBCH, ws+O_DBCL, sgb1, sgb2, sgc1, sgc2, ws+O_DBC);

    conv_dbc_kernel<<<dim3(16,44,4), blk, 0, stream>>>(ws+O_DBC, w_cdt, w_cB, w_cC,
                                                       ws+O_DTS, ws+O_BS, ws+O_CS);
    delta_kernel<<<dim3(32,6,4), blk, 0, stream>>>(ws+O_DTS, dtw, dtb, ws+O_DELTA);

    scan_kernel<<<3072, blk, 0, stream>>>(ws+O_XS, ws+O_DELTA, ws+O_BS, ws+O_CS, Alogs, Ds,
                                          ws+O_Y, ws+O_Y1);

    outnorm_gate_kernel<<<dim3(64,4), blk, 0, stream>>>(ws+O_Y, ws+O_Y1, ws+O_Z, ong, onb);

    gemm_ta<2><<<dim3(256,3), blk, 0, stream>>>(ws+O_YG, ws+O_WT_OUT, x, out, nullptr, 384, 192, 192);
}

// Round 5
// 317.837 us; speedup vs baseline: 2.5369x; 1.2527x over previous
//
#include <hip/hip_runtime.h>
#include <math.h>

#define LL 4096
#define NBATCH 4
#define CM 192
#define DI 384
#define NST 16
#define RK 12
#define NCH 44
#define SGH 96

typedef unsigned short ushort_t;
typedef __attribute__((ext_vector_type(8))) short bf16x8;
typedef __attribute__((ext_vector_type(4))) float f32x4;
typedef __attribute__((ext_vector_type(8))) unsigned short ushort8;
typedef __attribute__((ext_vector_type(4))) unsigned short ushort4v;

// workspace offsets (float units)
#define O_WT_IN   0
#define O_WT_LOW  147456
#define O_WT_XP   221184
#define O_WT_XPL  245760
#define O_WT_OUT  270336
#define O_XN      344064
#define O_LOWT    3489792
#define O_XH      6635520
#define O_Z       12926976
#define O_LOWP    19218432
#define O_XS      25509888
#define O_DBCH    31801344
#define O_DBCL    32522240
#define O_DBC     33243136
#define O_BS      33964032
#define O_CS      34226176
#define O_DELTA   O_LOWP   // lowp dead after x_proj GEMMs
#define O_Y       O_XH     // xh dead after conv2d
#define O_Y1      O_XN     // xn/lowt bf16 planes dead after in/low GEMMs (spans both)
#define O_DTS     O_DBCH   // dbcH dead after gates_kernel
// bf16 aliases (byte-exact fits):
//  wInH/wInL   over O_WT_IN  (147456 u16 each)
//  wLowH/wLowL over O_WT_LOW (73728 each)
//  wOutH/wOutL over O_WT_OUT (73728 each)
//  xnh/xnl     over O_XN     (3145728 each)
//  lowh/lowl   over O_LOWT   (3145728 each)
//  ygh/ygl     over O_LOWP   (6291456 each; delta dead after scan)

__device__ __forceinline__ ushort_t f2bf(float v) {
    unsigned u = __float_as_uint(v);
    return (ushort_t)((u + 0x7FFFu + ((u >> 16) & 1u)) >> 16);
}
__device__ __forceinline__ float bf2f(ushort_t h) {
    return __uint_as_float(((unsigned)h) << 16);
}

// ---- chunk-transposed ("perm") layout within each 4096-element row ----------
__device__ __forceinline__ int permidx(int l) {
    return ((l >> 2) & 3) * 1024 + ((l >> 4) << 2) + (l & 3);
}

#define LD16P(dst, row, t4) { \
  float4 _a = *(const float4*)((row) + (t4)); \
  float4 _b = *(const float4*)((row) + 1024 + (t4)); \
  float4 _c = *(const float4*)((row) + 2048 + (t4)); \
  float4 _d = *(const float4*)((row) + 3072 + (t4)); \
  dst[0]=_a.x; dst[1]=_a.y; dst[2]=_a.z; dst[3]=_a.w; \
  dst[4]=_b.x; dst[5]=_b.y; dst[6]=_b.z; dst[7]=_b.w; \
  dst[8]=_c.x; dst[9]=_c.y; dst[10]=_c.z; dst[11]=_c.w; \
  dst[12]=_d.x; dst[13]=_d.y; dst[14]=_d.z; dst[15]=_d.w; }

// -------- weight transpose + pad (fp32, for xproj weights only) ---------------
__global__ void transpose_pad_kernel(const float* __restrict__ in, float* __restrict__ out,
                                     int N, int K, int N64)
{
    int idx = blockIdx.x * 256 + threadIdx.x;
    if (idx >= K * N64) return;
    int k = idx / N64, n = idx % N64;
    out[idx] = (n < N) ? in[n * K + k] : 0.f;
}

// -------- elementwise fp32 -> bf16 hi/lo split --------------------------------
__global__ void split_plain_kernel(const float* __restrict__ in,
                                   ushort_t* __restrict__ oh, ushort_t* __restrict__ ol, int n)
{
    int i = (blockIdx.x * 256 + threadIdx.x) * 4;
    if (i >= n) return;
    float4 v = *(const float4*)&in[i];
    ushort4v h, l;
    h.x = f2bf(v.x); l.x = f2bf(v.x - bf2f(h.x));
    h.y = f2bf(v.y); l.y = f2bf(v.y - bf2f(h.y));
    h.z = f2bf(v.z); l.z = f2bf(v.z - bf2f(h.z));
    h.w = f2bf(v.w); l.w = f2bf(v.w - bf2f(h.w));
    *(ushort4v*)&oh[i] = h;
    *(ushort4v*)&ol[i] = l;
}

// -------- LayerNorm(192) + bf16 hi/lo split, token-major out ------------------
__global__ __launch_bounds__(256) void ln_split_kernel(const float* __restrict__ X,
    const float* __restrict__ gw, const float* __restrict__ bw,
    ushort_t* __restrict__ oh, ushort_t* __restrict__ ol)
{
    __shared__ float xt[64][193];
    __shared__ float reds[64][4], redq[64][4];
    __shared__ float mu_s[64], rs_s[64];
    int tid = threadIdx.x;
    int t0 = blockIdx.x * 64;
    const float* Xb = X + (size_t)t0 * CM;
#pragma unroll
    for (int i = 0; i < 12; i++) {
        int f4 = tid + 256 * i;
        float4 v = *(const float4*)&Xb[f4 * 4];
        int row = f4 / 48, c = (f4 % 48) * 4;
        xt[row][c] = v.x; xt[row][c+1] = v.y; xt[row][c+2] = v.z; xt[row][c+3] = v.w;
    }
    __syncthreads();
    int tok = tid & 63, p = tid >> 6;
    float s = 0.f, q = 0.f;
#pragma unroll 8
    for (int i = 0; i < 48; i++) { float v = xt[tok][p*48+i]; s += v; q = fmaf(v, v, q); }
    reds[tok][p] = s; redq[tok][p] = q;
    __syncthreads();
    if (tid < 64) {
        float ss = reds[tid][0]+reds[tid][1]+reds[tid][2]+reds[tid][3];
        float qq = redq[tid][0]+redq[tid][1]+redq[tid][2]+redq[tid][3];
        float mu = ss * (1.f/CM);
        float var = qq * (1.f/CM) - mu*mu;
        mu_s[tid] = mu; rs_s[tid] = rsqrtf(var + 1e-5f);
    }
    __syncthreads();
    int tok2 = tid >> 2, c0 = (tid & 3) * 48;
    float mu = mu_s[tok2], rs = rs_s[tok2];
    size_t tb = (size_t)(t0 + tok2) * CM;
#pragma unroll 8
    for (int i = 0; i < 48; i++) {
        int c = c0 + i;
        float v = (xt[tok2][c] - mu) * rs * gw[c] + bw[c];
        ushort_t h = f2bf(v);
        oh[tb + c] = h;
        ol[tb + c] = f2bf(v - bf2f(h));
    }
}

// -------- split-bf16 MFMA GEMM ------------------------------------------------
// A: token-major bf16 [T][KDIM] (hi, lo planes); W: [N][KDIM] bf16 (hi, lo).
// Block: 256 thr (4 waves), tile 128 L x 64 N; wave computes 32 L x 64 N.
// LDS k-grouped layout [kgrp][row][8] -> conflict-free ds_read_b128 frags.
// SPLIT=3: acc += Ah*Wh + Ah*Wl + Al*Wh.  SPLIT=1: acc += Ah*Wh.
// MODE 0: in_proj -> xh (n<384) / z, channel-major via LDS transpose
// MODE 1: low_proj -> out0 channel-major
// MODE 2: out_proj -> out0[t][192] = resid[t][192] + acc (token-major)
template<int MODE, int SPLIT, int KDIM>
__global__ __launch_bounds__(256) void gemm_mfma(
    const ushort_t* __restrict__ Ahi, const ushort_t* __restrict__ Alo,
    const ushort_t* __restrict__ Whi, const ushort_t* __restrict__ Wlo,
    const float* __restrict__ resid,
    float* __restrict__ out0, float* __restrict__ out1)
{
    __shared__ __align__(16) char smem[33280];
    ushort_t* sAh = (ushort_t*)smem;        // [4][128][8]
    ushort_t* sAl = sAh + 4096;             // [4][128][8]
    ushort_t* sWh = sAh + 8192;             // [4][64][8]
    ushort_t* sWl = sAh + 10240;            // [4][64][8]
    int tid = threadIdx.x;
    int t0 = blockIdx.x * 128;
    int b = t0 >> 12, l0 = t0 & 4095;
    int n0 = blockIdx.y * 64;
    // staging assignments
    int arow = tid >> 1, kgA = (tid & 1) * 2;          // A: 2 thr/row
    int wrow = tid >> 2, kgW = tid & 3;                // W: 4 thr/row
    const ushort_t* gAh = Ahi + (size_t)(t0 + arow) * KDIM + kgA * 8;
    const ushort_t* gAl = Alo + (size_t)(t0 + arow) * KDIM + kgA * 8;
    const ushort_t* gWh = Whi + (size_t)(n0 + wrow) * KDIM + kgW * 8;
    const ushort_t* gWl = Wlo + (size_t)(n0 + wrow) * KDIM + kgW * 8;
    int lane = tid & 63, w = tid >> 6;
    int ln = lane & 15, kg = lane >> 4;
    int am0 = w * 32 + ln;
    f32x4 acc[2][4];
#pragma unroll
    for (int mf = 0; mf < 2; mf++)
#pragma unroll
        for (int nf = 0; nf < 4; nf++) acc[mf][nf] = (f32x4){0.f, 0.f, 0.f, 0.f};

    for (int k0 = 0; k0 < KDIM; k0 += 32) {
        __syncthreads();
        {
            ushort8 a0 = *(const ushort8*)(gAh + k0);
            ushort8 a1 = *(const ushort8*)(gAh + k0 + 8);
            *(ushort8*)(sAh + kgA*1024 + arow*8) = a0;
            *(ushort8*)(sAh + (kgA+1)*1024 + arow*8) = a1;
            ushort8 w0 = *(const ushort8*)(gWh + k0);
            *(ushort8*)(sWh + kgW*512 + wrow*8) = w0;
            if (SPLIT == 3) {
                ushort8 b0 = *(const ushort8*)(gAl + k0);
                ushort8 b1 = *(const ushort8*)(gAl + k0 + 8);
                *(ushort8*)(sAl + kgA*1024 + arow*8) = b0;
                *(ushort8*)(sAl + (kgA+1)*1024 + arow*8) = b1;
                ushort8 w1 = *(const ushort8*)(gWl + k0);
                *(ushort8*)(sWl + kgW*512 + wrow*8) = w1;
            }
        }
        __syncthreads();
        bf16x8 aH[2], bH[4];
#pragma unroll
        for (int mf = 0; mf < 2; mf++)
            aH[mf] = *(const bf16x8*)(sAh + kg*1024 + (am0 + mf*16)*8);
#pragma unroll
        for (int nf = 0; nf < 4; nf++)
            bH[nf] = *(const bf16x8*)(sWh + kg*512 + (nf*16 + ln)*8);
#pragma unroll
        for (int mf = 0; mf < 2; mf++)
#pragma unroll
            for (int nf = 0; nf < 4; nf++)
                acc[mf][nf] = __builtin_amdgcn_mfma_f32_16x16x32_bf16(aH[mf], bH[nf], acc[mf][nf], 0, 0, 0);
        if (SPLIT == 3) {
            bf16x8 aL[2], bL[4];
#pragma unroll
            for (int mf = 0; mf < 2; mf++)
                aL[mf] = *(const bf16x8*)(sAl + kg*1024 + (am0 + mf*16)*8);
#pragma unroll
            for (int nf = 0; nf < 4; nf++)
                bL[nf] = *(const bf16x8*)(sWl + kg*512 + (nf*16 + ln)*8);
#pragma unroll
            for (int mf = 0; mf < 2; mf++)
#pragma unroll
                for (int nf = 0; nf < 4; nf++) {
                    acc[mf][nf] = __builtin_amdgcn_mfma_f32_16x16x32_bf16(aH[mf], bL[nf], acc[mf][nf], 0, 0, 0);
                    acc[mf][nf] = __builtin_amdgcn_mfma_f32_16x16x32_bf16(aL[mf], bH[nf], acc[mf][nf], 0, 0, 0);
                }
        }
    }

    if (MODE == 2) {
#pragma unroll
        for (int mf = 0; mf < 2; mf++)
#pragma unroll
            for (int j = 0; j < 4; j++) {
                int t = t0 + w*32 + mf*16 + (lane>>4)*4 + j;
#pragma unroll
                for (int nf = 0; nf < 4; nf++) {
                    int n = n0 + nf*16 + ln;
                    out0[(size_t)t*CM + n] = resid[(size_t)t*CM + n] + acc[mf][nf][j];
                }
            }
    } else {
        __syncthreads();
        float* st = (float*)smem;   // [64][130]
#pragma unroll
        for (int mf = 0; mf < 2; mf++)
#pragma unroll
            for (int nf = 0; nf < 4; nf++)
#pragma unroll
                for (int j = 0; j < 4; j++) {
                    int ml = w*32 + mf*16 + (lane>>4)*4 + j;
                    int nl = nf*16 + ln;
                    st[nl*130 + ml] = acc[mf][nf][j];
                }
        __syncthreads();
        int nl = tid >> 2, mq = (tid & 3) * 32;
        int n = n0 + nl;
        float* dst;
        if (MODE == 0) {
            dst = (n < DI) ? (out0 + ((size_t)b*DI + n)*LL + l0 + mq)
                           : (out1 + ((size_t)b*DI + (n - DI))*LL + l0 + mq);
        } else {
            dst = out0 + ((size_t)b*DI + n)*LL + l0 + mq;
        }
#pragma unroll
        for (int i = 0; i < 8; i++)
            *(float4*)(dst + i*4) = *(const float4*)&st[nl*130 + mq + i*4];
    }
}

// -------- fused dual x_proj GEMM (z=0: xs in PERM layout; z=1: lowp normal) ---
__global__ __launch_bounds__(256) void gemm_xproj(
    const float* __restrict__ A0, const float* __restrict__ W0, float* __restrict__ o0,
    const float* __restrict__ A1, const float* __restrict__ W1, float* __restrict__ o1,
    int K, int N64, int Nreal)
{
    __shared__ __align__(16) float At[64][64];
    __shared__ __align__(16) float Wl[64][64];
    int permA = (blockIdx.z == 0);
    const float* A  = blockIdx.z ? A1 : A0;
    const float* Wt = blockIdx.z ? W1 : W0;
    float* out0     = blockIdx.z ? o1 : o0;
    int tid = threadIdx.x;
    int t0 = blockIdx.x * 64;
    int b = t0 / LL, l0 = t0 % LL;
    int n0 = blockIdx.y * 64;
    const float* Ab = A + (size_t)b * K * LL;
    float acc[4][4] = {};
    int kr = tid >> 4;
    int m4 = (tid & 15) * 4;
    int r0 = m4;
    int c0 = kr * 4;
    int pA = permA ? (((m4 >> 2) & 3) * 1024 + (((l0 + m4) >> 4) << 2)) : (l0 + m4);
    for (int k0 = 0; k0 < K; k0 += 64) {
        __syncthreads();
#pragma unroll
        for (int i = 0; i < 4; i++) {
            int k = kr + i * 16;
            *(float4*)&At[k][m4] = *(const float4*)&Ab[(size_t)(k0+k)*LL + pA];
            *(float4*)&Wl[k][m4] = *(const float4*)&Wt[(size_t)(k0+k)*N64 + n0 + m4];
        }
        __syncthreads();
#pragma unroll
        for (int k = 0; k < 64; k++) {
            float4 a4 = *(const float4*)&At[k][r0];
            float4 w4 = *(const float4*)&Wl[k][c0];
            float av[4] = {a4.x, a4.y, a4.z, a4.w};
            float wv[4] = {w4.x, w4.y, w4.z, w4.w};
#pragma unroll
            for (int i = 0; i < 4; i++)
#pragma unroll
                for (int j = 0; j < 4; j++)
                    acc[i][j] = fmaf(av[i], wv[j], acc[i][j]);
        }
    }
#pragma unroll
    for (int i = 0; i < 4; i++) {
        int l = l0 + r0 + i;
#pragma unroll
        for (int j = 0; j < 4; j++) {
            int n = n0 + c0 + j;
            if (n < Nreal) out0[((size_t)b*Nreal + n)*LL + l] = acc[i][j];
        }
    }
}

// -------- depthwise 3x3 conv + bias + SiLU -> xs in PERM layout ---------------
__global__ __launch_bounds__(256) void conv2d_silu_kernel(const float* __restrict__ xh,
    const float* __restrict__ w, const float* __restrict__ bias, float* __restrict__ xs)
{
    int tid = threadIdx.x;
    int l = blockIdx.x * 256 + tid;
    int c = blockIdx.y, b = blockIdx.z;
    const float* P = xh + ((size_t)b*DI + c)*LL;
    int h = l >> 6, ww = l & 63;
    float acc = bias[c];
#pragma unroll
    for (int kh = 0; kh < 3; kh++) {
        int hh = h + kh - 1;
        if ((unsigned)hh < 64u) {
#pragma unroll
            for (int kw = 0; kw < 3; kw++) {
                int wv = ww + kw - 1;
                if ((unsigned)wv < 64u) acc = fmaf(w[c*9 + kh*3 + kw], P[hh*64 + wv], acc);
            }
        }
    }
    float sg = 1.f / (1.f + __expf(-acc));
    xs[((size_t)b*DI + c)*LL + permidx(l)] = acc * sg;
}

// -------- SimpleGates on low B/C + sum high+low -> dbc [B][44][L] -------------
__global__ __launch_bounds__(256) void gates_kernel(const float* __restrict__ dbcH,
    const float* __restrict__ dbcL,
    const float* __restrict__ sgb1, const float* __restrict__ sgb2,
    const float* __restrict__ sgc1, const float* __restrict__ sgc2,
    float* __restrict__ dbc)
{
    __shared__ float w1[2][192*16];
    __shared__ float w2[2][16*96];
    __shared__ float red[4][16][64];
    int tid = threadIdx.x;
    for (int i = tid; i < 192*16; i += 256) { w1[0][i] = sgb1[i]; w1[1][i] = sgc1[i]; }
    for (int i = tid; i < 16*96;  i += 256) { w2[0][i] = sgb2[i]; w2[1][i] = sgc2[i]; }
    int lq = tid & 63, p = tid >> 6;
    int l = blockIdx.x * 64 + lq;
    int b = blockIdx.y;
    size_t pb_ = (size_t)b*NCH*LL + l;
    __syncthreads();
#pragma unroll
    for (int i = 0; i < 3; i++) {
        int c = p*3 + i;
        dbc[pb_ + (size_t)c*LL] = dbcH[pb_ + (size_t)c*LL] + dbcL[pb_ + (size_t)c*LL];
    }
    for (int gate = 0; gate < 2; gate++) {
        int coff = RK + gate*NST;
        float xin[16], og[16];
#pragma unroll
        for (int n = 0; n < 16; n++) { xin[n] = dbcL[pb_ + (size_t)(coff+n)*LL]; og[n] = 0.f; }
        int h0 = p * 24;
        for (int h = h0; h < h0 + 24; h++) {
            float ya = 0.f, yb = 0.f;
#pragma unroll
            for (int n = 0; n < 16; n++) {
                ya = fmaf(w1[gate][h*16+n], xin[n], ya);
                yb = fmaf(w1[gate][(h+SGH)*16+n], xin[n], yb);
            }
            float gg = 0.5f * ya * (1.f + erff(ya * 0.70710678f)) * yb;
#pragma unroll
            for (int n = 0; n < 16; n++) og[n] = fmaf(w2[gate][n*SGH+h], gg, og[n]);
        }
#pragma unroll
        for (int n = 0; n < 16; n++) red[p][n][lq] = og[n];
        __syncthreads();
#pragma unroll
        for (int i = 0; i < 4; i++) {
            int n = p*4 + i;
            float v = red[0][n][lq] + red[1][n][lq] + red[2][n][lq] + red[3][n][lq];
            dbc[pb_ + (size_t)(coff+n)*LL] = dbcH[pb_ + (size_t)(coff+n)*LL] + v;
        }
        __syncthreads();
    }
}

// -------- residual dilated dwconv1d: dts normal; Bs/Cs in PERM layout ---------
__global__ __launch_bounds__(256) void conv_dbc_kernel(const float* __restrict__ dbc,
    const float* __restrict__ wdt, const float* __restrict__ wB, const float* __restrict__ wC,
    float* __restrict__ dts, float* __restrict__ Bs, float* __restrict__ Cs)
{
    int l = blockIdx.x * 256 + threadIdx.x;
    int c = blockIdx.y, b = blockIdx.z;
    const float* wsrc = (c < RK) ? (wdt + c*15)
                      : (c < RK+NST ? wB + (c-RK)*15 : wC + (c-RK-NST)*15);
    float w[15];
#pragma unroll
    for (int k = 0; k < 15; k++) w[k] = wsrc[k];
    const float* P = dbc + ((size_t)b*NCH + c)*LL;
    float a = P[l];
#pragma unroll
    for (int k = 0; k < 15; k++) {
        int lt = l + 2*k - 14;
        if ((unsigned)lt < (unsigned)LL) a = fmaf(w[k], P[lt], a);
    }
    if (c < RK)            dts[((size_t)b*RK  + c)*LL + l] = a;
    else if (c < RK+NST)   Bs [((size_t)b*NST + (c-RK))*LL + permidx(l)] = a;
    else                   Cs [((size_t)b*NST + (c-RK-NST))*LL + permidx(l)] = a;
}

// -------- delta projection + softplus -> delta in PERM layout -----------------
__global__ __launch_bounds__(256) void delta_kernel(const float* __restrict__ dts,
    const float* __restrict__ dtw, const float* __restrict__ dtb, float* __restrict__ delta)
{
    __shared__ float sdt[RK][128];
    __shared__ float sw[64][RK];
    int tid = threadIdx.x;
    int l0 = blockIdx.x * 128, d0 = blockIdx.y * 64, b = blockIdx.z;
    for (int i = tid; i < RK*128; i += 256) {
        int r = i >> 7, lq = i & 127;
        sdt[r][lq] = dts[((size_t)b*RK + r)*LL + l0 + lq];
    }
    for (int i = tid; i < 64*RK; i += 256) {
        int dq = i / RK, r = i - dq*RK;
        sw[dq][r] = dtw[(size_t)(d0+dq)*RK + r];
    }
    __syncthreads();
    int lq = tid & 63, g = tid >> 6;
    for (int dd = 0; dd < 16; dd++) {
        int dqq = g*16 + dd, d = d0 + dqq;
        float wr[RK];
#pragma unroll
        for (int r = 0; r < RK; r++) wr[r] = sw[dqq][r];
        float bias = dtb[d];
#pragma unroll
        for (int li = 0; li < 2; li++) {
            int lloc = lq + li*64;
            float s = bias;
#pragma unroll
            for (int r = 0; r < RK; r++) s = fmaf(wr[r], sdt[r][lloc], s);
            float sp = fmaxf(s, 0.f) + log1pf(__expf(-fabsf(s)));
            delta[((size_t)b*DI + d)*LL + permidx(l0 + lloc)] = sp;
        }
    }
}

// -------- selective scan: PERM-layout coalesced loads, LDS-transposed store ---
__global__ __launch_bounds__(256) void scan_kernel(
    const float* __restrict__ u_, const float* __restrict__ delta_,
    const float* __restrict__ Bs_, const float* __restrict__ Cs_,
    const float* __restrict__ Alogs, const float* __restrict__ Ds,
    float* __restrict__ y0_, float* __restrict__ y1_)
{
    __shared__ float wAs[4][8], wBs[4][8];
    __shared__ float yt[16][258];
    int tid = threadIdx.x;
    int t4 = tid * 4;
    int bid = blockIdx.x;
    int half = bid & 1, bd = bid >> 1;
    int b = bd / DI, d = bd % DI;
    int n0 = half * 8;
    size_t rowoff = ((size_t)b*DI + d)*LL;
    float dl[16], du[16], yac[16];
    LD16P(du, u_ + rowoff, t4);
    LD16P(dl, delta_ + rowoff, t4);
    float Dd = Ds[d];
#pragma unroll
    for (int s = 0; s < 16; s++) {
        yac[s] = half ? 0.f : du[s]*Dd;
        du[s] = dl[s]*du[s];
    }
    float Av[8];
#pragma unroll
    for (int j = 0; j < 8; j++) Av[j] = -__expf(Alogs[d*NST + n0 + j]);
    float ap[8], hv[8];
#pragma unroll
    for (int j = 0; j < 8; j++) {
        float Bn[16];
        LD16P(Bn, Bs_ + ((size_t)b*NST + n0 + j)*LL, t4);
        float a = 1.f, h = 0.f, An = Av[j];
#pragma unroll
        for (int s = 0; s < 16; s++) {
            float e = __expf(dl[s]*An);
            h = fmaf(e, h, du[s]*Bn[s]);
            a *= e;
        }
        ap[j] = a; hv[j] = h;
    }
    int lane = tid & 63, w = tid >> 6;
    for (int off = 1; off < 64; off <<= 1) {
#pragma unroll
        for (int j = 0; j < 8; j++) {
            float pa = __shfl_up(ap[j], (unsigned)off, 64);
            float pb = __shfl_up(hv[j], (unsigned)off, 64);
            if (lane >= off) {
                hv[j] = fmaf(ap[j], pb, hv[j]);
                ap[j] *= pa;
            }
        }
    }
    if (lane == 63) {
#pragma unroll
        for (int j = 0; j < 8; j++) { wAs[w][j] = ap[j]; wBs[w][j] = hv[j]; }
    }
    __syncthreads();
    float PB[8];
#pragma unroll
    for (int j = 0; j < 8; j++) PB[j] = 0.f;
    for (int ww = 0; ww < w; ww++) {
#pragma unroll
        for (int j = 0; j < 8; j++) PB[j] = fmaf(wAs[ww][j], PB[j], wBs[ww][j]);
    }
    float hin[8];
#pragma unroll
    for (int j = 0; j < 8; j++) {
        hv[j] = fmaf(ap[j], PB[j], hv[j]);
        float t = __shfl_up(hv[j], 1u, 64);
        hin[j] = lane ? t : PB[j];
    }
#pragma unroll
    for (int j = 0; j < 8; j++) {
        float Bn[16], Cn[16];
        LD16P(Bn, Bs_ + ((size_t)b*NST + n0 + j)*LL, t4);
        LD16P(Cn, Cs_ + ((size_t)b*NST + n0 + j)*LL, t4);
        float h = hin[j], An = Av[j];
#pragma unroll
        for (int s = 0; s < 16; s++) {
            float e = __expf(dl[s]*An);
            h = fmaf(e, h, du[s]*Bn[s]);
            yac[s] = fmaf(Cn[s], h, yac[s]);
        }
    }
#pragma unroll
    for (int i = 0; i < 16; i++) yt[i][tid] = yac[i];
    __syncthreads();
    float* yout = (half ? y1_ : y0_) + rowoff;
#pragma unroll
    for (int r = 0; r < 16; r++)
        yout[r*256 + tid] = yt[tid & 15][r*16 + (tid >> 4)];
}

// -------- out-norm LN(384) on y0+y1 + z-SiLU gate -> token-major bf16 hi/lo ---
__global__ __launch_bounds__(256) void outnorm_gate_kernel(const float* __restrict__ y0,
    const float* __restrict__ y1, const float* __restrict__ z,
    const float* __restrict__ g, const float* __restrict__ bt,
    ushort_t* __restrict__ ygh, ushort_t* __restrict__ ygl)
{
    __shared__ unsigned yt[16][DI];   // packed hi<<16 | lo
    int tid = threadIdx.x;
    int tloc = tid >> 4, kk = tid & 15;
    int t = blockIdx.x * 16 + tloc;
    int b = t >> 12, l = t & 4095;
    size_t basec = (size_t)b * DI * LL + l;
    const float* yp0 = y0 + basec;
    const float* yp1 = y1 + basec;
    const float* zp = z + basec;
    float vv[24];
    float s = 0.f, q = 0.f;
#pragma unroll
    for (int i = 0; i < 24; i++) {
        int d = kk * 24 + i;
        float v = yp0[(size_t)d*LL] + yp1[(size_t)d*LL];
        vv[i] = v; s += v; q = fmaf(v, v, q);
    }
#pragma unroll
    for (int off = 8; off >= 1; off >>= 1) {
        s += __shfl_xor(s, off, 16);
        q += __shfl_xor(q, off, 16);
    }
    float mu = s * (1.f/DI);
    float var = q * (1.f/DI) - mu*mu;
    float rs = rsqrtf(var + 1e-5f);
#pragma unroll
    for (int i = 0; i < 24; i++) {
        int d = kk*24 + i;
        float v = (vv[i] - mu)*rs*g[d] + bt[d];
        float zv = zp[(size_t)d*LL];
        float yg = v * (zv / (1.f + __expf(-zv)));
        ushort_t h = f2bf(yg);
        ushort_t lo = f2bf(yg - bf2f(h));
        yt[tloc][d] = ((unsigned)h << 16) | (unsigned)lo;
    }
    __syncthreads();
    const unsigned* yf = (const unsigned*)yt;
    size_t obase = (size_t)blockIdx.x * 16 * DI;
    int j0 = tid * 24;
#pragma unroll
    for (int i = 0; i < 6; i++) {
        ushort4v hv, lv;
#pragma unroll
        for (int j = 0; j < 4; j++) {
            unsigned pv = yf[j0 + i*4 + j];
            hv[j] = (ushort_t)(pv >> 16);
            lv[j] = (ushort_t)(pv & 0xFFFFu);
        }
        *(ushort4v*)&ygh[obase + j0 + i*4] = hv;
        *(ushort4v*)&ygl[obase + j0 + i*4] = lv;
    }
}

extern "C" void kernel_launch(void* const* d_in, const int* in_sizes, int n_in,
                              void* d_out, int out_size, void* d_ws, size_t ws_size,
                              hipStream_t stream)
{
    (void)in_sizes; (void)n_in; (void)out_size; (void)ws_size;
    const float* x     = (const float*)d_in[0];
    const float* low   = (const float*)d_in[1];
    const float* ln_g  = (const float*)d_in[2];
    const float* ln_b  = (const float*)d_in[3];
    const float* w_in  = (const float*)d_in[4];
    const float* w_low = (const float*)d_in[5];
    const float* w_c2d = (const float*)d_in[6];
    const float* b_c2d = (const float*)d_in[7];
    const float* w_xp  = (const float*)d_in[8];
    const float* w_xpl = (const float*)d_in[9];
    const float* w_cdt = (const float*)d_in[10];
    const float* w_cB  = (const float*)d_in[11];
    const float* w_cC  = (const float*)d_in[12];
    const float* sgb1  = (const float*)d_in[13];
    const float* sgb2  = (const float*)d_in[14];
    const float* sgc1  = (const float*)d_in[15];
    const float* sgc2  = (const float*)d_in[16];
    const float* dtw   = (const float*)d_in[17];
    const float* dtb   = (const float*)d_in[18];
    const float* Alogs = (const float*)d_in[19];
    const float* Ds    = (const float*)d_in[20];
    const float* ong   = (const float*)d_in[21];
    const float* onb   = (const float*)d_in[22];
    const float* w_out = (const float*)d_in[23];
    float* ws  = (float*)d_ws;
    float* out = (float*)d_out;
    dim3 blk(256);

    // bf16 plane aliases
    ushort_t* wInH  = (ushort_t*)(ws + O_WT_IN);   ushort_t* wInL  = wInH + 147456;
    ushort_t* wLowH = (ushort_t*)(ws + O_WT_LOW);  ushort_t* wLowL = wLowH + 73728;
    ushort_t* wOutH = (ushort_t*)(ws + O_WT_OUT);  ushort_t* wOutL = wOutH + 73728;
    ushort_t* xnh   = (ushort_t*)(ws + O_XN);      ushort_t* xnl   = xnh + 3145728;
    ushort_t* lowh  = (ushort_t*)(ws + O_LOWT);    ushort_t* lowl  = lowh + 3145728;
    ushort_t* ygh   = (ushort_t*)(ws + O_LOWP);    ushort_t* ygl   = ygh + 6291456;

    split_plain_kernel<<<144, blk, 0, stream>>>(w_in,  wInH,  wInL,  147456);
    split_plain_kernel<<<72,  blk, 0, stream>>>(w_low, wLowH, wLowL, 73728);
    split_plain_kernel<<<72,  blk, 0, stream>>>(w_out, wOutH, wOutL, 73728);
    transpose_pad_kernel<<<96, blk, 0, stream>>>(w_xp,  ws + O_WT_XP,  44, 384, 64);
    transpose_pad_kernel<<<96, blk, 0, stream>>>(w_xpl, ws + O_WT_XPL, 44, 384, 64);

    ln_split_kernel<<<256, blk, 0, stream>>>(x, ln_g, ln_b, xnh, xnl);
    split_plain_kernel<<<3072, blk, 0, stream>>>(low, lowh, lowl, 3145728);

    gemm_mfma<0,3,192><<<dim3(128,12), blk, 0, stream>>>(xnh, xnl, wInH, wInL, nullptr,
                                                         ws+O_XH, ws+O_Z);
    gemm_mfma<1,3,192><<<dim3(128,6),  blk, 0, stream>>>(lowh, lowl, wLowH, wLowL, nullptr,
                                                         ws+O_LOWP, nullptr);

    conv2d_silu_kernel<<<dim3(16,384,4), blk, 0, stream>>>(ws+O_XH, w_c2d, b_c2d, ws+O_XS);

    gemm_xproj<<<dim3(256,1,2), blk, 0, stream>>>(ws+O_XS, ws+O_WT_XP, ws+O_DBCH,
                                                  ws+O_LOWP, ws+O_WT_XPL, ws+O_DBCL, 384, 64, 44);

    gates_kernel<<<dim3(64,4), blk, 0, stream>>>(ws+O_DBCH, ws+O_DBCL, sgb1, sgb2, sgc1, sgc2, ws+O_DBC);

    conv_dbc_kernel<<<dim3(16,44,4), blk, 0, stream>>>(ws+O_DBC, w_cdt, w_cB, w_cC,
                                                       ws+O_DTS, ws+O_BS, ws+O_CS);
    delta_kernel<<<dim3(32,6,4), blk, 0, stream>>>(ws+O_DTS, dtw, dtb, ws+O_DELTA);

    scan_kernel<<<3072, blk, 0, stream>>>(ws+O_XS, ws+O_DELTA, ws+O_BS, ws+O_CS, Alogs, Ds,
                                          ws+O_Y, ws+O_Y1);

    outnorm_gate_kernel<<<1024, blk, 0, stream>>>(ws+O_Y, ws+O_Y1, ws+O_Z, ong, onb, ygh, ygl);

    gemm_mfma<2,1,384><<<dim3(128,3), blk, 0, stream>>>(ygh, ygl, wOutH, wOutL, x, out, nullptr);
}

// Round 6
// 313.758 us; speedup vs baseline: 2.5699x; 1.0130x over previous
//
#include <hip/hip_runtime.h>
#include <math.h>

#define LL 4096
#define NBATCH 4
#define CM 192
#define DI 384
#define NST 16
#define RK 12
#define NCH 44
#define SGH 96

typedef unsigned short ushort_t;
typedef __attribute__((ext_vector_type(8))) short bf16x8;
typedef __attribute__((ext_vector_type(4))) float f32x4;
typedef __attribute__((ext_vector_type(8))) unsigned short ushort8;
typedef __attribute__((ext_vector_type(4))) unsigned short ushort4v;

// workspace offsets (float units)
#define O_WT_IN   0
#define O_WT_LOW  147456
#define O_WT_XP   221184
#define O_WT_XPL  245760
#define O_WT_OUT  270336
#define O_XN      344064
#define O_LOWT    3489792
#define O_XH      6635520
#define O_Z       12926976
#define O_LOWP    19218432
#define O_XS      25509888
#define O_DBCH    31801344
#define O_DBCL    32522240
#define O_DBC     33243136
#define O_BS      33964032
#define O_CS      34226176
#define O_DELTA   O_LOWP   // lowp dead after x_proj GEMMs
#define O_Y       O_XH     // xh dead after conv2d
#define O_Y1      O_XN     // xn/lowt bf16 planes dead after in/low GEMMs (spans both)
#define O_DTS     O_DBCH   // dbcH dead after gates_kernel

__device__ __forceinline__ ushort_t f2bf(float v) {
    unsigned u = __float_as_uint(v);
    return (ushort_t)((u + 0x7FFFu + ((u >> 16) & 1u)) >> 16);
}
__device__ __forceinline__ float bf2f(ushort_t h) {
    return __uint_as_float(((unsigned)h) << 16);
}

// ---- chunk-transposed ("perm") layout within each 4096-element row ----------
__device__ __forceinline__ int permidx(int l) {
    return ((l >> 2) & 3) * 1024 + ((l >> 4) << 2) + (l & 3);
}

#define LD16P(dst, row, t4) { \
  float4 _a = *(const float4*)((row) + (t4)); \
  float4 _b = *(const float4*)((row) + 1024 + (t4)); \
  float4 _c = *(const float4*)((row) + 2048 + (t4)); \
  float4 _d = *(const float4*)((row) + 3072 + (t4)); \
  dst[0]=_a.x; dst[1]=_a.y; dst[2]=_a.z; dst[3]=_a.w; \
  dst[4]=_b.x; dst[5]=_b.y; dst[6]=_b.z; dst[7]=_b.w; \
  dst[8]=_c.x; dst[9]=_c.y; dst[10]=_c.z; dst[11]=_c.w; \
  dst[12]=_d.x; dst[13]=_d.y; dst[14]=_d.z; dst[15]=_d.w; }

// -------- merged weight hi/lo split (w_in, w_low, w_out) ----------------------
__global__ void split3_kernel(const float* __restrict__ i0, ushort_t* h0, ushort_t* l0_,
                              const float* __restrict__ i1, ushort_t* h1, ushort_t* l1,
                              const float* __restrict__ i2, ushort_t* h2, ushort_t* l2)
{
    int bx = blockIdx.x;
    const float* in; ushort_t* oh; ushort_t* ol; int base;
    if (bx < 144)      { in = i0; oh = h0; ol = l0_; base = bx * 1024; }
    else if (bx < 216) { in = i1; oh = h1; ol = l1;  base = (bx-144) * 1024; }
    else               { in = i2; oh = h2; ol = l2;  base = (bx-216) * 1024; }
    int i = base + threadIdx.x * 4;
    float4 v = *(const float4*)&in[i];
    ushort4v h, l;
    h.x = f2bf(v.x); l.x = f2bf(v.x - bf2f(h.x));
    h.y = f2bf(v.y); l.y = f2bf(v.y - bf2f(h.y));
    h.z = f2bf(v.z); l.z = f2bf(v.z - bf2f(h.z));
    h.w = f2bf(v.w); l.w = f2bf(v.w - bf2f(h.w));
    *(ushort4v*)&oh[i] = h;
    *(ushort4v*)&ol[i] = l;
}

// -------- x_proj weights: [44][384] -> padded [64][384] bf16 hi/lo ------------
__global__ void split_padw_kernel(const float* __restrict__ in0, ushort_t* oh0, ushort_t* ol0,
                                  const float* __restrict__ in1, ushort_t* oh1, ushort_t* ol1)
{
    const float* in = blockIdx.y ? in1 : in0;
    ushort_t* oh = blockIdx.y ? oh1 : oh0;
    ushort_t* ol = blockIdx.y ? ol1 : ol0;
    int idx = (blockIdx.x * 256 + threadIdx.x) * 4;
    int n = idx / 384;
    float4 v = (n < NCH) ? *(const float4*)&in[idx] : make_float4(0.f,0.f,0.f,0.f);
    ushort4v h, l;
    h.x = f2bf(v.x); l.x = f2bf(v.x - bf2f(h.x));
    h.y = f2bf(v.y); l.y = f2bf(v.y - bf2f(h.y));
    h.z = f2bf(v.z); l.z = f2bf(v.z - bf2f(h.z));
    h.w = f2bf(v.w); l.w = f2bf(v.w - bf2f(h.w));
    *(ushort4v*)&oh[idx] = h;
    *(ushort4v*)&ol[idx] = l;
}

// -------- elementwise fp32 -> bf16 hi/lo split --------------------------------
__global__ void split_plain_kernel(const float* __restrict__ in,
                                   ushort_t* __restrict__ oh, ushort_t* __restrict__ ol, int n)
{
    int i = (blockIdx.x * 256 + threadIdx.x) * 4;
    if (i >= n) return;
    float4 v = *(const float4*)&in[i];
    ushort4v h, l;
    h.x = f2bf(v.x); l.x = f2bf(v.x - bf2f(h.x));
    h.y = f2bf(v.y); l.y = f2bf(v.y - bf2f(h.y));
    h.z = f2bf(v.z); l.z = f2bf(v.z - bf2f(h.z));
    h.w = f2bf(v.w); l.w = f2bf(v.w - bf2f(h.w));
    *(ushort4v*)&oh[i] = h;
    *(ushort4v*)&ol[i] = l;
}

// -------- LayerNorm(192) + bf16 hi/lo split, token-major out ------------------
__global__ __launch_bounds__(256) void ln_split_kernel(const float* __restrict__ X,
    const float* __restrict__ gw, const float* __restrict__ bw,
    ushort_t* __restrict__ oh, ushort_t* __restrict__ ol)
{
    __shared__ float xt[64][193];
    __shared__ float reds[64][4], redq[64][4];
    __shared__ float mu_s[64], rs_s[64];
    int tid = threadIdx.x;
    int t0 = blockIdx.x * 64;
    const float* Xb = X + (size_t)t0 * CM;
#pragma unroll
    for (int i = 0; i < 12; i++) {
        int f4 = tid + 256 * i;
        float4 v = *(const float4*)&Xb[f4 * 4];
        int row = f4 / 48, c = (f4 % 48) * 4;
        xt[row][c] = v.x; xt[row][c+1] = v.y; xt[row][c+2] = v.z; xt[row][c+3] = v.w;
    }
    __syncthreads();
    int tok = tid & 63, p = tid >> 6;
    float s = 0.f, q = 0.f;
#pragma unroll 8
    for (int i = 0; i < 48; i++) { float v = xt[tok][p*48+i]; s += v; q = fmaf(v, v, q); }
    reds[tok][p] = s; redq[tok][p] = q;
    __syncthreads();
    if (tid < 64) {
        float ss = reds[tid][0]+reds[tid][1]+reds[tid][2]+reds[tid][3];
        float qq = redq[tid][0]+redq[tid][1]+redq[tid][2]+redq[tid][3];
        float mu = ss * (1.f/CM);
        float var = qq * (1.f/CM) - mu*mu;
        mu_s[tid] = mu; rs_s[tid] = rsqrtf(var + 1e-5f);
    }
    __syncthreads();
    int tok2 = tid >> 2, c0 = (tid & 3) * 48;
    float mu = mu_s[tok2], rs = rs_s[tok2];
    size_t tb = (size_t)(t0 + tok2) * CM;
#pragma unroll 8
    for (int i = 0; i < 48; i++) {
        int c = c0 + i;
        float v = (xt[tok2][c] - mu) * rs * gw[c] + bw[c];
        ushort_t h = f2bf(v);
        oh[tb + c] = h;
        ol[tb + c] = f2bf(v - bf2f(h));
    }
}

// -------- split-bf16 MFMA GEMM, token-major bf16 A planes ---------------------
// MODE 0: in_proj -> xh/z channel-major.  MODE 1: low_proj -> out0 channel-major.
template<int MODE, int SPLIT, int KDIM>
__global__ __launch_bounds__(256) void gemm_mfma(
    const ushort_t* __restrict__ Ahi, const ushort_t* __restrict__ Alo,
    const ushort_t* __restrict__ Whi, const ushort_t* __restrict__ Wlo,
    float* __restrict__ out0, float* __restrict__ out1)
{
    __shared__ __align__(16) char smem[33280];
    ushort_t* sAh = (ushort_t*)smem;        // [4][128][8]
    ushort_t* sAl = sAh + 4096;
    ushort_t* sWh = sAh + 8192;             // [4][64][8]
    ushort_t* sWl = sAh + 10240;
    int tid = threadIdx.x;
    int t0 = blockIdx.x * 128;
    int b = t0 >> 12, l0 = t0 & 4095;
    int n0 = blockIdx.y * 64;
    int arow = tid >> 1, kgA = (tid & 1) * 2;
    int wrow = tid >> 2, kgW = tid & 3;
    const ushort_t* gAh = Ahi + (size_t)(t0 + arow) * KDIM + kgA * 8;
    const ushort_t* gAl = Alo + (size_t)(t0 + arow) * KDIM + kgA * 8;
    const ushort_t* gWh = Whi + (size_t)(n0 + wrow) * KDIM + kgW * 8;
    const ushort_t* gWl = Wlo + (size_t)(n0 + wrow) * KDIM + kgW * 8;
    int lane = tid & 63, w = tid >> 6;
    int ln = lane & 15, kg = lane >> 4;
    int am0 = w * 32 + ln;
    f32x4 acc[2][4];
#pragma unroll
    for (int mf = 0; mf < 2; mf++)
#pragma unroll
        for (int nf = 0; nf < 4; nf++) acc[mf][nf] = (f32x4){0.f, 0.f, 0.f, 0.f};

    for (int k0 = 0; k0 < KDIM; k0 += 32) {
        __syncthreads();
        {
            ushort8 a0 = *(const ushort8*)(gAh + k0);
            ushort8 a1 = *(const ushort8*)(gAh + k0 + 8);
            *(ushort8*)(sAh + kgA*1024 + arow*8) = a0;
            *(ushort8*)(sAh + (kgA+1)*1024 + arow*8) = a1;
            ushort8 w0 = *(const ushort8*)(gWh + k0);
            *(ushort8*)(sWh + kgW*512 + wrow*8) = w0;
            if (SPLIT == 3) {
                ushort8 b0 = *(const ushort8*)(gAl + k0);
                ushort8 b1 = *(const ushort8*)(gAl + k0 + 8);
                *(ushort8*)(sAl + kgA*1024 + arow*8) = b0;
                *(ushort8*)(sAl + (kgA+1)*1024 + arow*8) = b1;
                ushort8 w1 = *(const ushort8*)(gWl + k0);
                *(ushort8*)(sWl + kgW*512 + wrow*8) = w1;
            }
        }
        __syncthreads();
        bf16x8 aH[2], bH[4];
#pragma unroll
        for (int mf = 0; mf < 2; mf++)
            aH[mf] = *(const bf16x8*)(sAh + kg*1024 + (am0 + mf*16)*8);
#pragma unroll
        for (int nf = 0; nf < 4; nf++)
            bH[nf] = *(const bf16x8*)(sWh + kg*512 + (nf*16 + ln)*8);
#pragma unroll
        for (int mf = 0; mf < 2; mf++)
#pragma unroll
            for (int nf = 0; nf < 4; nf++)
                acc[mf][nf] = __builtin_amdgcn_mfma_f32_16x16x32_bf16(aH[mf], bH[nf], acc[mf][nf], 0, 0, 0);
        if (SPLIT == 3) {
            bf16x8 aL[2], bL[4];
#pragma unroll
            for (int mf = 0; mf < 2; mf++)
                aL[mf] = *(const bf16x8*)(sAl + kg*1024 + (am0 + mf*16)*8);
#pragma unroll
            for (int nf = 0; nf < 4; nf++)
                bL[nf] = *(const bf16x8*)(sWl + kg*512 + (nf*16 + ln)*8);
#pragma unroll
            for (int mf = 0; mf < 2; mf++)
#pragma unroll
                for (int nf = 0; nf < 4; nf++) {
                    acc[mf][nf] = __builtin_amdgcn_mfma_f32_16x16x32_bf16(aH[mf], bL[nf], acc[mf][nf], 0, 0, 0);
                    acc[mf][nf] = __builtin_amdgcn_mfma_f32_16x16x32_bf16(aL[mf], bH[nf], acc[mf][nf], 0, 0, 0);
                }
        }
    }
    __syncthreads();
    float* st = (float*)smem;   // [64][130]
#pragma unroll
    for (int mf = 0; mf < 2; mf++)
#pragma unroll
        for (int nf = 0; nf < 4; nf++)
#pragma unroll
            for (int j = 0; j < 4; j++) {
                int ml = w*32 + mf*16 + (lane>>4)*4 + j;
                int nl = nf*16 + ln;
                st[nl*130 + ml] = acc[mf][nf][j];
            }
    __syncthreads();
    int nl = tid >> 2, mq = (tid & 3) * 32;
    int n = n0 + nl;
    float* dst;
    if (MODE == 0) {
        dst = (n < DI) ? (out0 + ((size_t)b*DI + n)*LL + l0 + mq)
                       : (out1 + ((size_t)b*DI + (n - DI))*LL + l0 + mq);
    } else {
        dst = out0 + ((size_t)b*DI + n)*LL + l0 + mq;
    }
#pragma unroll
    for (int i = 0; i < 8; i++)
        *(float4*)(dst + i*4) = *(const float4*)&st[nl*130 + mq + i*4];
}

// -------- channel-major-A MFMA GEMM (fp32 A staged + on-the-fly bf16 split) ---
// A: [B][384][LL] fp32 (PERM0 applies to A0 only). W: bf16 hi/lo [Npad][384].
// MODE 1: out channel-major rows n<Nreal.  MODE 2: out token-major + resid.
template<int MODE, int SPLIT, int PERM0>
__global__ __launch_bounds__(256) void gemm_cmaj(
    const float* __restrict__ A0, const float* __restrict__ A1,
    const ushort_t* __restrict__ W0h, const ushort_t* __restrict__ W0l,
    const ushort_t* __restrict__ W1h, const ushort_t* __restrict__ W1l,
    const float* __restrict__ resid,
    float* __restrict__ o0, float* __restrict__ o1, int Nreal)
{
    __shared__ __align__(16) char smem[33280];
    float* sA = (float*)smem;                       // [32][132]
    ushort_t* sWh = (ushort_t*)(smem + 16896);      // [4][64][8]
    ushort_t* sWl = (ushort_t*)(smem + 20992);
    bool sel = (blockIdx.z == 1);
    const float* A = sel ? A1 : A0;
    const ushort_t* Wh = sel ? W1h : W0h;
    const ushort_t* Wl = sel ? W1l : W0l;
    float* out0 = sel ? o1 : o0;
    const bool perm = sel ? false : (PERM0 != 0);
    int tid = threadIdx.x;
    int t0 = blockIdx.x * 128;
    int b = t0 >> 12, l0 = t0 & 4095;
    int n0 = blockIdx.y * 64;
    const float* Ab = A + (size_t)b * 384 * LL;
    int srow = tid >> 3, sc8 = tid & 7;
    int wrow = tid >> 2, kgW = tid & 3;
    int lane = tid & 63, w = tid >> 6;
    int ln = lane & 15, kg = lane >> 4;
    int am0 = w * 32 + ln;
    f32x4 acc[2][4];
#pragma unroll
    for (int mf = 0; mf < 2; mf++)
#pragma unroll
        for (int nf = 0; nf < 4; nf++) acc[mf][nf] = (f32x4){0.f, 0.f, 0.f, 0.f};

    for (int k0 = 0; k0 < 384; k0 += 32) {
        __syncthreads();
#pragma unroll
        for (int i = 0; i < 4; i++) {
            int m = (sc8 + 8*i) * 4;
            int src = perm ? ((((m >> 2) & 3) * 1024) + (((l0 + m) >> 4) << 2))
                           : (l0 + m);
            float4 v = *(const float4*)&Ab[(size_t)(k0 + srow)*LL + src];
            *(float4*)&sA[srow*132 + m] = v;
        }
        {
            ushort8 wv = *(const ushort8*)(Wh + (size_t)(n0 + wrow)*384 + k0 + kgW*8);
            *(ushort8*)(sWh + kgW*512 + wrow*8) = wv;
            if (SPLIT == 3) {
                ushort8 wl = *(const ushort8*)(Wl + (size_t)(n0 + wrow)*384 + k0 + kgW*8);
                *(ushort8*)(sWl + kgW*512 + wrow*8) = wl;
            }
        }
        __syncthreads();
        bf16x8 aH[2], aL[2];
#pragma unroll
        for (int mf = 0; mf < 2; mf++) {
            int am = am0 + mf*16;
#pragma unroll
            for (int e = 0; e < 8; e++) {
                float v = sA[(kg*8 + e)*132 + am];
                ushort_t h = f2bf(v);
                aH[mf][e] = (short)h;
                if (SPLIT == 3) aL[mf][e] = (short)f2bf(v - bf2f(h));
            }
        }
        bf16x8 bH[4], bL[4];
#pragma unroll
        for (int nf = 0; nf < 4; nf++) {
            bH[nf] = *(const bf16x8*)(sWh + kg*512 + (nf*16 + ln)*8);
            if (SPLIT == 3) bL[nf] = *(const bf16x8*)(sWl + kg*512 + (nf*16 + ln)*8);
        }
#pragma unroll
        for (int mf = 0; mf < 2; mf++)
#pragma unroll
            for (int nf = 0; nf < 4; nf++) {
                acc[mf][nf] = __builtin_amdgcn_mfma_f32_16x16x32_bf16(aH[mf], bH[nf], acc[mf][nf], 0, 0, 0);
                if (SPLIT == 3) {
                    acc[mf][nf] = __builtin_amdgcn_mfma_f32_16x16x32_bf16(aH[mf], bL[nf], acc[mf][nf], 0, 0, 0);
                    acc[mf][nf] = __builtin_amdgcn_mfma_f32_16x16x32_bf16(aL[mf], bH[nf], acc[mf][nf], 0, 0, 0);
                }
            }
    }

    if (MODE == 2) {
#pragma unroll
        for (int mf = 0; mf < 2; mf++)
#pragma unroll
            for (int j = 0; j < 4; j++) {
                int t = t0 + w*32 + mf*16 + (lane>>4)*4 + j;
#pragma unroll
                for (int nf = 0; nf < 4; nf++) {
                    int n = n0 + nf*16 + ln;
                    out0[(size_t)t*CM + n] = resid[(size_t)t*CM + n] + acc[mf][nf][j];
                }
            }
    } else {
        __syncthreads();
        float* st = (float*)smem;   // [64][130]
#pragma unroll
        for (int mf = 0; mf < 2; mf++)
#pragma unroll
            for (int nf = 0; nf < 4; nf++)
#pragma unroll
                for (int j = 0; j < 4; j++) {
                    int ml = w*32 + mf*16 + (lane>>4)*4 + j;
                    int nl = nf*16 + ln;
                    st[nl*130 + ml] = acc[mf][nf][j];
                }
        __syncthreads();
        int nl = tid >> 2, mq = (tid & 3) * 32;
        int n = n0 + nl;
        if (n < Nreal) {
            float* dst = out0 + ((size_t)b*Nreal + n)*LL + l0 + mq;
#pragma unroll
            for (int i = 0; i < 8; i++)
                *(float4*)(dst + i*4) = *(const float4*)&st[nl*130 + mq + i*4];
        }
    }
}

// -------- depthwise 3x3 conv + bias + SiLU -> xs in PERM layout ---------------
__global__ __launch_bounds__(256) void conv2d_silu_kernel(const float* __restrict__ xh,
    const float* __restrict__ w, const float* __restrict__ bias, float* __restrict__ xs)
{
    int tid = threadIdx.x;
    int l = blockIdx.x * 256 + tid;
    int c = blockIdx.y, b = blockIdx.z;
    const float* P = xh + ((size_t)b*DI + c)*LL;
    int h = l >> 6, ww = l & 63;
    float acc = bias[c];
#pragma unroll
    for (int kh = 0; kh < 3; kh++) {
        int hh = h + kh - 1;
        if ((unsigned)hh < 64u) {
#pragma unroll
            for (int kw = 0; kw < 3; kw++) {
                int wv = ww + kw - 1;
                if ((unsigned)wv < 64u) acc = fmaf(w[c*9 + kh*3 + kw], P[hh*64 + wv], acc);
            }
        }
    }
    float sg = 1.f / (1.f + __expf(-acc));
    xs[((size_t)b*DI + c)*LL + permidx(l)] = acc * sg;
}

// -------- SimpleGates on low B/C + sum high+low -> dbc [B][44][L] -------------
__global__ __launch_bounds__(256) void gates_kernel(const float* __restrict__ dbcH,
    const float* __restrict__ dbcL,
    const float* __restrict__ sgb1, const float* __restrict__ sgb2,
    const float* __restrict__ sgc1, const float* __restrict__ sgc2,
    float* __restrict__ dbc)
{
    __shared__ float w1[2][192*16];
    __shared__ float w2[2][16*96];
    __shared__ float red[4][16][64];
    int tid = threadIdx.x;
    for (int i = tid; i < 192*16; i += 256) { w1[0][i] = sgb1[i]; w1[1][i] = sgc1[i]; }
    for (int i = tid; i < 16*96;  i += 256) { w2[0][i] = sgb2[i]; w2[1][i] = sgc2[i]; }
    int lq = tid & 63, p = tid >> 6;
    int l = blockIdx.x * 64 + lq;
    int b = blockIdx.y;
    size_t pb_ = (size_t)b*NCH*LL + l;
    __syncthreads();
#pragma unroll
    for (int i = 0; i < 3; i++) {
        int c = p*3 + i;
        dbc[pb_ + (size_t)c*LL] = dbcH[pb_ + (size_t)c*LL] + dbcL[pb_ + (size_t)c*LL];
    }
    for (int gate = 0; gate < 2; gate++) {
        int coff = RK + gate*NST;
        float xin[16], og[16];
#pragma unroll
        for (int n = 0; n < 16; n++) { xin[n] = dbcL[pb_ + (size_t)(coff+n)*LL]; og[n] = 0.f; }
        int h0 = p * 24;
        for (int h = h0; h < h0 + 24; h++) {
            float ya = 0.f, yb = 0.f;
#pragma unroll
            for (int n = 0; n < 16; n++) {
                ya = fmaf(w1[gate][h*16+n], xin[n], ya);
                yb = fmaf(w1[gate][(h+SGH)*16+n], xin[n], yb);
            }
            float gg = 0.5f * ya * (1.f + erff(ya * 0.70710678f)) * yb;
#pragma unroll
            for (int n = 0; n < 16; n++) og[n] = fmaf(w2[gate][n*SGH+h], gg, og[n]);
        }
#pragma unroll
        for (int n = 0; n < 16; n++) red[p][n][lq] = og[n];
        __syncthreads();
#pragma unroll
        for (int i = 0; i < 4; i++) {
            int n = p*4 + i;
            float v = red[0][n][lq] + red[1][n][lq] + red[2][n][lq] + red[3][n][lq];
            dbc[pb_ + (size_t)(coff+n)*LL] = dbcH[pb_ + (size_t)(coff+n)*LL] + v;
        }
        __syncthreads();
    }
}

// -------- residual dilated dwconv1d: dts normal; Bs/Cs in PERM layout ---------
__global__ __launch_bounds__(256) void conv_dbc_kernel(const float* __restrict__ dbc,
    const float* __restrict__ wdt, const float* __restrict__ wB, const float* __restrict__ wC,
    float* __restrict__ dts, float* __restrict__ Bs, float* __restrict__ Cs)
{
    int l = blockIdx.x * 256 + threadIdx.x;
    int c = blockIdx.y, b = blockIdx.z;
    const float* wsrc = (c < RK) ? (wdt + c*15)
                      : (c < RK+NST ? wB + (c-RK)*15 : wC + (c-RK-NST)*15);
    float w[15];
#pragma unroll
    for (int k = 0; k < 15; k++) w[k] = wsrc[k];
    const float* P = dbc + ((size_t)b*NCH + c)*LL;
    float a = P[l];
#pragma unroll
    for (int k = 0; k < 15; k++) {
        int lt = l + 2*k - 14;
        if ((unsigned)lt < (unsigned)LL) a = fmaf(w[k], P[lt], a);
    }
    if (c < RK)            dts[((size_t)b*RK  + c)*LL + l] = a;
    else if (c < RK+NST)   Bs [((size_t)b*NST + (c-RK))*LL + permidx(l)] = a;
    else                   Cs [((size_t)b*NST + (c-RK-NST))*LL + permidx(l)] = a;
}

// -------- delta projection + softplus -> delta in PERM layout -----------------
__global__ __launch_bounds__(256) void delta_kernel(const float* __restrict__ dts,
    const float* __restrict__ dtw, const float* __restrict__ dtb, float* __restrict__ delta)
{
    __shared__ float sdt[RK][128];
    __shared__ float sw[64][RK];
    int tid = threadIdx.x;
    int l0 = blockIdx.x * 128, d0 = blockIdx.y * 64, b = blockIdx.z;
    for (int i = tid; i < RK*128; i += 256) {
        int r = i >> 7, lq = i & 127;
        sdt[r][lq] = dts[((size_t)b*RK + r)*LL + l0 + lq];
    }
    for (int i = tid; i < 64*RK; i += 256) {
        int dq = i / RK, r = i - dq*RK;
        sw[dq][r] = dtw[(size_t)(d0+dq)*RK + r];
    }
    __syncthreads();
    int lq = tid & 63, g = tid >> 6;
    for (int dd = 0; dd < 16; dd++) {
        int dqq = g*16 + dd, d = d0 + dqq;
        float wr[RK];
#pragma unroll
        for (int r = 0; r < RK; r++) wr[r] = sw[dqq][r];
        float bias = dtb[d];
#pragma unroll
        for (int li = 0; li < 2; li++) {
            int lloc = lq + li*64;
            float s = bias;
#pragma unroll
            for (int r = 0; r < RK; r++) s = fmaf(wr[r], sdt[r][lloc], s);
            float sp = fmaxf(s, 0.f) + log1pf(__expf(-fabsf(s)));
            delta[((size_t)b*DI + d)*LL + permidx(l0 + lloc)] = sp;
        }
    }
}

// -------- selective scan v4: single-pass recurrence + deferred prefix fixup ---
// pass1 accumulates y from local h AND stores t[s]=C[s]*a_s; after block prefix
// gives hin, pass2 is 16 independent fmas (no exp recompute, no B/C reload).
__global__ __launch_bounds__(256) void scan_kernel(
    const float* __restrict__ u_, const float* __restrict__ delta_,
    const float* __restrict__ Bs_, const float* __restrict__ Cs_,
    const float* __restrict__ Alogs, const float* __restrict__ Ds,
    float* __restrict__ y0_, float* __restrict__ y1_)
{
    __shared__ float wAs[8][4], wBs[8][4];
    __shared__ float yt[16][258];
    int tid = threadIdx.x;
    int t4 = tid * 4;
    int bid = blockIdx.x;
    int half = bid & 1, bd = bid >> 1;
    int b = bd / DI, d = bd % DI;
    int n0 = half * 8;
    size_t rowoff = ((size_t)b*DI + d)*LL;
    float dl[16], du[16], yac[16];
    LD16P(du, u_ + rowoff, t4);
    LD16P(dl, delta_ + rowoff, t4);
    float Dd = Ds[d];
#pragma unroll
    for (int s = 0; s < 16; s++) {
        yac[s] = half ? 0.f : du[s]*Dd;
        du[s] = dl[s]*du[s];
    }
    int lane = tid & 63, w = tid >> 6;
    for (int j = 0; j < 8; j++) {
        float An = -__expf(Alogs[d*NST + n0 + j]);
        float Bn[16], Cn[16], t[16];
        LD16P(Bn, Bs_ + ((size_t)b*NST + n0 + j)*LL, t4);
        LD16P(Cn, Cs_ + ((size_t)b*NST + n0 + j)*LL, t4);
        float a = 1.f, h = 0.f;
#pragma unroll
        for (int s = 0; s < 16; s++) {
            float e = __expf(dl[s]*An);
            a *= e;
            h = fmaf(e, h, du[s]*Bn[s]);
            yac[s] = fmaf(Cn[s], h, yac[s]);
            t[s] = Cn[s]*a;
        }
        // cross-thread affine prefix on (a,h)
        float ap = a, hv = h;
        for (int off = 1; off < 64; off <<= 1) {
            float pa = __shfl_up(ap, (unsigned)off, 64);
            float pb = __shfl_up(hv, (unsigned)off, 64);
            if (lane >= off) { hv = fmaf(ap, pb, hv); ap *= pa; }
        }
        if (lane == 63) { wAs[j][w] = ap; wBs[j][w] = hv; }
        __syncthreads();
        float PB = 0.f;
        for (int ww = 0; ww < w; ww++) PB = fmaf(wAs[j][ww], PB, wBs[j][ww]);
        hv = fmaf(ap, PB, hv);
        float tt = __shfl_up(hv, 1u, 64);
        float hin = lane ? tt : PB;
#pragma unroll
        for (int s = 0; s < 16; s++) yac[s] = fmaf(t[s], hin, yac[s]);
    }
#pragma unroll
    for (int i = 0; i < 16; i++) yt[i][tid] = yac[i];
    __syncthreads();
    float* yout = (half ? y1_ : y0_) + rowoff;
#pragma unroll
    for (int r = 0; r < 16; r++)
        yout[r*256 + tid] = yt[tid & 15][r*16 + (tid >> 4)];
}

// -------- out-norm LN(384) on y0+y1 + z-SiLU gating (in-place over y1) --------
__global__ __launch_bounds__(256) void outnorm_gate_kernel(const float* __restrict__ y0,
    float* y1g, const float* __restrict__ z,
    const float* __restrict__ g, const float* __restrict__ bt)
{
    __shared__ float rs_[4][64], rq_[4][64];
    __shared__ float mu_s[64], rstd_s[64];
    int tid = threadIdx.x;
    int lq = tid & 63, p = tid >> 6;
    int l = blockIdx.x * 64 + lq;
    int b = blockIdx.y;
    const float* yp0 = y0 + (size_t)b*DI*LL + l;
    float* yp1 = y1g + (size_t)b*DI*LL + l;
    float s = 0.f, q = 0.f;
#pragma unroll 4
    for (int i = 0; i < 96; i++) {
        int d = p*96 + i;
        float v = yp0[(size_t)d*LL] + yp1[(size_t)d*LL];
        s += v; q = fmaf(v, v, q);
    }
    rs_[p][lq] = s; rq_[p][lq] = q;
    __syncthreads();
    if (p == 0) {
        float ss = rs_[0][lq]+rs_[1][lq]+rs_[2][lq]+rs_[3][lq];
        float qq = rq_[0][lq]+rq_[1][lq]+rq_[2][lq]+rq_[3][lq];
        float mu = ss * (1.f/DI);
        float var = qq * (1.f/DI) - mu*mu;
        mu_s[lq] = mu; rstd_s[lq] = rsqrtf(var + 1e-5f);
    }
    __syncthreads();
    float mu = mu_s[lq], rs = rstd_s[lq];
    const float* zp = z + (size_t)b*DI*LL + l;
#pragma unroll 4
    for (int i = 0; i < 96; i++) {
        int d = p*96 + i;
        float v = ((yp0[(size_t)d*LL] + yp1[(size_t)d*LL]) - mu)*rs*g[d] + bt[d];
        float zv = zp[(size_t)d*LL];
        float sg = 1.f / (1.f + __expf(-zv));
        yp1[(size_t)d*LL] = v * (zv * sg);
    }
}

extern "C" void kernel_launch(void* const* d_in, const int* in_sizes, int n_in,
                              void* d_out, int out_size, void* d_ws, size_t ws_size,
                              hipStream_t stream)
{
    (void)in_sizes; (void)n_in; (void)out_size; (void)ws_size;
    const float* x     = (const float*)d_in[0];
    const float* low   = (const float*)d_in[1];
    const float* ln_g  = (const float*)d_in[2];
    const float* ln_b  = (const float*)d_in[3];
    const float* w_in  = (const float*)d_in[4];
    const float* w_low = (const float*)d_in[5];
    const float* w_c2d = (const float*)d_in[6];
    const float* b_c2d = (const float*)d_in[7];
    const float* w_xp  = (const float*)d_in[8];
    const float* w_xpl = (const float*)d_in[9];
    const float* w_cdt = (const float*)d_in[10];
    const float* w_cB  = (const float*)d_in[11];
    const float* w_cC  = (const float*)d_in[12];
    const float* sgb1  = (const float*)d_in[13];
    const float* sgb2  = (const float*)d_in[14];
    const float* sgc1  = (const float*)d_in[15];
    const float* sgc2  = (const float*)d_in[16];
    const float* dtw   = (const float*)d_in[17];
    const float* dtb   = (const float*)d_in[18];
    const float* Alogs = (const float*)d_in[19];
    const float* Ds    = (const float*)d_in[20];
    const float* ong   = (const float*)d_in[21];
    const float* onb   = (const float*)d_in[22];
    const float* w_out = (const float*)d_in[23];
    float* ws  = (float*)d_ws;
    float* out = (float*)d_out;
    dim3 blk(256);

    // bf16 plane aliases
    ushort_t* wInH  = (ushort_t*)(ws + O_WT_IN);   ushort_t* wInL  = wInH + 147456;
    ushort_t* wLowH = (ushort_t*)(ws + O_WT_LOW);  ushort_t* wLowL = wLowH + 73728;
    ushort_t* wOutH = (ushort_t*)(ws + O_WT_OUT);  ushort_t* wOutL = wOutH + 73728;
    ushort_t* wXpH  = (ushort_t*)(ws + O_WT_XP);   ushort_t* wXpL  = wXpH + 24576;
    ushort_t* wXplH = (ushort_t*)(ws + O_WT_XPL);  ushort_t* wXplL = wXplH + 24576;
    ushort_t* xnh   = (ushort_t*)(ws + O_XN);      ushort_t* xnl   = xnh + 3145728;
    ushort_t* lowh  = (ushort_t*)(ws + O_LOWT);    ushort_t* lowl  = lowh + 3145728;

    split3_kernel<<<288, blk, 0, stream>>>(w_in, wInH, wInL, w_low, wLowH, wLowL,
                                           w_out, wOutH, wOutL);
    split_padw_kernel<<<dim3(24,2), blk, 0, stream>>>(w_xp, wXpH, wXpL, w_xpl, wXplH, wXplL);

    ln_split_kernel<<<256, blk, 0, stream>>>(x, ln_g, ln_b, xnh, xnl);
    split_plain_kernel<<<3072, blk, 0, stream>>>(low, lowh, lowl, 3145728);

    gemm_mfma<0,3,192><<<dim3(128,12), blk, 0, stream>>>(xnh, xnl, wInH, wInL,
                                                         ws+O_XH, ws+O_Z);
    gemm_mfma<1,3,192><<<dim3(128,6),  blk, 0, stream>>>(lowh, lowl, wLowH, wLowL,
                                                         ws+O_LOWP, nullptr);

    conv2d_silu_kernel<<<dim3(16,384,4), blk, 0, stream>>>(ws+O_XH, w_c2d, b_c2d, ws+O_XS);

    gemm_cmaj<1,3,1><<<dim3(128,1,2), blk, 0, stream>>>(ws+O_XS, ws+O_LOWP,
                                                        wXpH, wXpL, wXplH, wXplL,
                                                        nullptr, ws+O_DBCH, ws+O_DBCL, NCH);

    gates_kernel<<<dim3(64,4), blk, 0, stream>>>(ws+O_DBCH, ws+O_DBCL, sgb1, sgb2, sgc1, sgc2, ws+O_DBC);

    conv_dbc_kernel<<<dim3(16,44,4), blk, 0, stream>>>(ws+O_DBC, w_cdt, w_cB, w_cC,
                                                       ws+O_DTS, ws+O_BS, ws+O_CS);
    delta_kernel<<<dim3(32,6,4), blk, 0, stream>>>(ws+O_DTS, dtw, dtb, ws+O_DELTA);

    scan_kernel<<<3072, blk, 0, stream>>>(ws+O_XS, ws+O_DELTA, ws+O_BS, ws+O_CS, Alogs, Ds,
                                          ws+O_Y, ws+O_Y1);

    outnorm_gate_kernel<<<dim3(64,4), blk, 0, stream>>>(ws+O_Y, ws+O_Y1, ws+O_Z, ong, onb);

    gemm_cmaj<2,1,0><<<dim3(128,3,1), blk, 0, stream>>>(ws+O_Y1, nullptr,
                                                        wOutH, wOutL, nullptr, nullptr,
                                                        x, out, nullptr, CM);
}

// Round 7
// 309.634 us; speedup vs baseline: 2.6041x; 1.0133x over previous
//
#include <hip/hip_runtime.h>
#include <math.h>

#define LL 4096
#define NBATCH 4
#define CM 192
#define DI 384
#define NST 16
#define RK 12
#define NCH 44
#define SGH 96

typedef unsigned short ushort_t;
typedef __attribute__((ext_vector_type(8))) short bf16x8;
typedef __attribute__((ext_vector_type(4))) float f32x4;
typedef __attribute__((ext_vector_type(8))) unsigned short ushort8;
typedef __attribute__((ext_vector_type(4))) unsigned short ushort4v;

// workspace offsets (float units)
#define O_WT_IN   0
#define O_WT_LOW  147456
#define O_WT_XP   221184
#define O_WT_XPL  245760
#define O_WT_OUT  270336
#define O_XN      344064
#define O_LOWT    3489792
#define O_XH      6635520
#define O_Z       12926976
#define O_LOWP    19218432
#define O_XS      25509888
#define O_DBCH    31801344
#define O_DBCL    32522240
#define O_DBC     33243136
#define O_BS      33964032
#define O_CS      34226176
#define O_DELTA   O_LOWP   // lowp dead after x_proj GEMMs
#define O_Y       O_XH     // xh dead after conv2d
#define O_DTS     O_DBCH   // dbcH dead after gates_kernel

__device__ __forceinline__ ushort_t f2bf(float v) {
    unsigned u = __float_as_uint(v);
    return (ushort_t)((u + 0x7FFFu + ((u >> 16) & 1u)) >> 16);
}
__device__ __forceinline__ float bf2f(ushort_t h) {
    return __uint_as_float(((unsigned)h) << 16);
}

// ---- chunk-transposed ("perm") layout within each 4096-element row ----------
__device__ __forceinline__ int permidx(int l) {
    return ((l >> 2) & 3) * 1024 + ((l >> 4) << 2) + (l & 3);
}

#define LD16P(dst, row, t4) { \
  float4 _a = *(const float4*)((row) + (t4)); \
  float4 _b = *(const float4*)((row) + 1024 + (t4)); \
  float4 _c = *(const float4*)((row) + 2048 + (t4)); \
  float4 _d = *(const float4*)((row) + 3072 + (t4)); \
  dst[0]=_a.x; dst[1]=_a.y; dst[2]=_a.z; dst[3]=_a.w; \
  dst[4]=_b.x; dst[5]=_b.y; dst[6]=_b.z; dst[7]=_b.w; \
  dst[8]=_c.x; dst[9]=_c.y; dst[10]=_c.z; dst[11]=_c.w; \
  dst[12]=_d.x; dst[13]=_d.y; dst[14]=_d.z; dst[15]=_d.w; }

// -------- merged weight hi/lo split (w_in, w_low, w_out) ----------------------
__global__ void split3_kernel(const float* __restrict__ i0, ushort_t* h0, ushort_t* l0_,
                              const float* __restrict__ i1, ushort_t* h1, ushort_t* l1,
                              const float* __restrict__ i2, ushort_t* h2, ushort_t* l2)
{
    int bx = blockIdx.x;
    const float* in; ushort_t* oh; ushort_t* ol; int base;
    if (bx < 144)      { in = i0; oh = h0; ol = l0_; base = bx * 1024; }
    else if (bx < 216) { in = i1; oh = h1; ol = l1;  base = (bx-144) * 1024; }
    else               { in = i2; oh = h2; ol = l2;  base = (bx-216) * 1024; }
    int i = base + threadIdx.x * 4;
    float4 v = *(const float4*)&in[i];
    ushort4v h, l;
    h.x = f2bf(v.x); l.x = f2bf(v.x - bf2f(h.x));
    h.y = f2bf(v.y); l.y = f2bf(v.y - bf2f(h.y));
    h.z = f2bf(v.z); l.z = f2bf(v.z - bf2f(h.z));
    h.w = f2bf(v.w); l.w = f2bf(v.w - bf2f(h.w));
    *(ushort4v*)&oh[i] = h;
    *(ushort4v*)&ol[i] = l;
}

// -------- x_proj weights: [44][384] -> padded [64][384] bf16 hi/lo ------------
__global__ void split_padw_kernel(const float* __restrict__ in0, ushort_t* oh0, ushort_t* ol0,
                                  const float* __restrict__ in1, ushort_t* oh1, ushort_t* ol1)
{
    const float* in = blockIdx.y ? in1 : in0;
    ushort_t* oh = blockIdx.y ? oh1 : oh0;
    ushort_t* ol = blockIdx.y ? ol1 : ol0;
    int idx = (blockIdx.x * 256 + threadIdx.x) * 4;
    int n = idx / 384;
    float4 v = (n < NCH) ? *(const float4*)&in[idx] : make_float4(0.f,0.f,0.f,0.f);
    ushort4v h, l;
    h.x = f2bf(v.x); l.x = f2bf(v.x - bf2f(h.x));
    h.y = f2bf(v.y); l.y = f2bf(v.y - bf2f(h.y));
    h.z = f2bf(v.z); l.z = f2bf(v.z - bf2f(h.z));
    h.w = f2bf(v.w); l.w = f2bf(v.w - bf2f(h.w));
    *(ushort4v*)&oh[idx] = h;
    *(ushort4v*)&ol[idx] = l;
}

// -------- elementwise fp32 -> bf16 hi/lo split --------------------------------
__global__ void split_plain_kernel(const float* __restrict__ in,
                                   ushort_t* __restrict__ oh, ushort_t* __restrict__ ol, int n)
{
    int i = (blockIdx.x * 256 + threadIdx.x) * 4;
    if (i >= n) return;
    float4 v = *(const float4*)&in[i];
    ushort4v h, l;
    h.x = f2bf(v.x); l.x = f2bf(v.x - bf2f(h.x));
    h.y = f2bf(v.y); l.y = f2bf(v.y - bf2f(h.y));
    h.z = f2bf(v.z); l.z = f2bf(v.z - bf2f(h.z));
    h.w = f2bf(v.w); l.w = f2bf(v.w - bf2f(h.w));
    *(ushort4v*)&oh[i] = h;
    *(ushort4v*)&ol[i] = l;
}

// -------- LayerNorm(192) + bf16 hi/lo split, token-major out ------------------
__global__ __launch_bounds__(256) void ln_split_kernel(const float* __restrict__ X,
    const float* __restrict__ gw, const float* __restrict__ bw,
    ushort_t* __restrict__ oh, ushort_t* __restrict__ ol)
{
    __shared__ float xt[64][193];
    __shared__ float reds[64][4], redq[64][4];
    __shared__ float mu_s[64], rs_s[64];
    int tid = threadIdx.x;
    int t0 = blockIdx.x * 64;
    const float* Xb = X + (size_t)t0 * CM;
#pragma unroll
    for (int i = 0; i < 12; i++) {
        int f4 = tid + 256 * i;
        float4 v = *(const float4*)&Xb[f4 * 4];
        int row = f4 / 48, c = (f4 % 48) * 4;
        xt[row][c] = v.x; xt[row][c+1] = v.y; xt[row][c+2] = v.z; xt[row][c+3] = v.w;
    }
    __syncthreads();
    int tok = tid & 63, p = tid >> 6;
    float s = 0.f, q = 0.f;
#pragma unroll 8
    for (int i = 0; i < 48; i++) { float v = xt[tok][p*48+i]; s += v; q = fmaf(v, v, q); }
    reds[tok][p] = s; redq[tok][p] = q;
    __syncthreads();
    if (tid < 64) {
        float ss = reds[tid][0]+reds[tid][1]+reds[tid][2]+reds[tid][3];
        float qq = redq[tid][0]+redq[tid][1]+redq[tid][2]+redq[tid][3];
        float mu = ss * (1.f/CM);
        float var = qq * (1.f/CM) - mu*mu;
        mu_s[tid] = mu; rs_s[tid] = rsqrtf(var + 1e-5f);
    }
    __syncthreads();
    int tok2 = tid >> 2, c0 = (tid & 3) * 48;
    float mu = mu_s[tok2], rs = rs_s[tok2];
    size_t tb = (size_t)(t0 + tok2) * CM;
#pragma unroll 8
    for (int i = 0; i < 48; i++) {
        int c = c0 + i;
        float v = (xt[tok2][c] - mu) * rs * gw[c] + bw[c];
        ushort_t h = f2bf(v);
        oh[tb + c] = h;
        ol[tb + c] = f2bf(v - bf2f(h));
    }
}

// -------- split-bf16 MFMA GEMM, token-major bf16 A planes ---------------------
template<int MODE, int SPLIT, int KDIM>
__global__ __launch_bounds__(256) void gemm_mfma(
    const ushort_t* __restrict__ Ahi, const ushort_t* __restrict__ Alo,
    const ushort_t* __restrict__ Whi, const ushort_t* __restrict__ Wlo,
    float* __restrict__ out0, float* __restrict__ out1)
{
    __shared__ __align__(16) char smem[33280];
    ushort_t* sAh = (ushort_t*)smem;        // [4][128][8]
    ushort_t* sAl = sAh + 4096;
    ushort_t* sWh = sAh + 8192;             // [4][64][8]
    ushort_t* sWl = sAh + 10240;
    int tid = threadIdx.x;
    int t0 = blockIdx.x * 128;
    int b = t0 >> 12, l0 = t0 & 4095;
    int n0 = blockIdx.y * 64;
    int arow = tid >> 1, kgA = (tid & 1) * 2;
    int wrow = tid >> 2, kgW = tid & 3;
    const ushort_t* gAh = Ahi + (size_t)(t0 + arow) * KDIM + kgA * 8;
    const ushort_t* gAl = Alo + (size_t)(t0 + arow) * KDIM + kgA * 8;
    const ushort_t* gWh = Whi + (size_t)(n0 + wrow) * KDIM + kgW * 8;
    const ushort_t* gWl = Wlo + (size_t)(n0 + wrow) * KDIM + kgW * 8;
    int lane = tid & 63, w = tid >> 6;
    int ln = lane & 15, kg = lane >> 4;
    int am0 = w * 32 + ln;
    f32x4 acc[2][4];
#pragma unroll
    for (int mf = 0; mf < 2; mf++)
#pragma unroll
        for (int nf = 0; nf < 4; nf++) acc[mf][nf] = (f32x4){0.f, 0.f, 0.f, 0.f};

    for (int k0 = 0; k0 < KDIM; k0 += 32) {
        __syncthreads();
        {
            ushort8 a0 = *(const ushort8*)(gAh + k0);
            ushort8 a1 = *(const ushort8*)(gAh + k0 + 8);
            *(ushort8*)(sAh + kgA*1024 + arow*8) = a0;
            *(ushort8*)(sAh + (kgA+1)*1024 + arow*8) = a1;
            ushort8 w0 = *(const ushort8*)(gWh + k0);
            *(ushort8*)(sWh + kgW*512 + wrow*8) = w0;
            if (SPLIT == 3) {
                ushort8 b0 = *(const ushort8*)(gAl + k0);
                ushort8 b1 = *(const ushort8*)(gAl + k0 + 8);
                *(ushort8*)(sAl + kgA*1024 + arow*8) = b0;
                *(ushort8*)(sAl + (kgA+1)*1024 + arow*8) = b1;
                ushort8 w1 = *(const ushort8*)(gWl + k0);
                *(ushort8*)(sWl + kgW*512 + wrow*8) = w1;
            }
        }
        __syncthreads();
        bf16x8 aH[2], bH[4];
#pragma unroll
        for (int mf = 0; mf < 2; mf++)
            aH[mf] = *(const bf16x8*)(sAh + kg*1024 + (am0 + mf*16)*8);
#pragma unroll
        for (int nf = 0; nf < 4; nf++)
            bH[nf] = *(const bf16x8*)(sWh + kg*512 + (nf*16 + ln)*8);
#pragma unroll
        for (int mf = 0; mf < 2; mf++)
#pragma unroll
            for (int nf = 0; nf < 4; nf++)
                acc[mf][nf] = __builtin_amdgcn_mfma_f32_16x16x32_bf16(aH[mf], bH[nf], acc[mf][nf], 0, 0, 0);
        if (SPLIT == 3) {
            bf16x8 aL[2], bL[4];
#pragma unroll
            for (int mf = 0; mf < 2; mf++)
                aL[mf] = *(const bf16x8*)(sAl + kg*1024 + (am0 + mf*16)*8);
#pragma unroll
            for (int nf = 0; nf < 4; nf++)
                bL[nf] = *(const bf16x8*)(sWl + kg*512 + (nf*16 + ln)*8);
#pragma unroll
            for (int mf = 0; mf < 2; mf++)
#pragma unroll
                for (int nf = 0; nf < 4; nf++) {
                    acc[mf][nf] = __builtin_amdgcn_mfma_f32_16x16x32_bf16(aH[mf], bL[nf], acc[mf][nf], 0, 0, 0);
                    acc[mf][nf] = __builtin_amdgcn_mfma_f32_16x16x32_bf16(aL[mf], bH[nf], acc[mf][nf], 0, 0, 0);
                }
        }
    }
    __syncthreads();
    float* st = (float*)smem;   // [64][130]
#pragma unroll
    for (int mf = 0; mf < 2; mf++)
#pragma unroll
        for (int nf = 0; nf < 4; nf++)
#pragma unroll
            for (int j = 0; j < 4; j++) {
                int ml = w*32 + mf*16 + (lane>>4)*4 + j;
                int nl = nf*16 + ln;
                st[nl*130 + ml] = acc[mf][nf][j];
            }
    __syncthreads();
    int nl = tid >> 2, mq = (tid & 3) * 32;
    int n = n0 + nl;
    float* dst;
    if (MODE == 0) {
        dst = (n < DI) ? (out0 + ((size_t)b*DI + n)*LL + l0 + mq)
                       : (out1 + ((size_t)b*DI + (n - DI))*LL + l0 + mq);
    } else {
        dst = out0 + ((size_t)b*DI + n)*LL + l0 + mq;
    }
#pragma unroll
    for (int i = 0; i < 8; i++)
        *(float4*)(dst + i*4) = *(const float4*)&st[nl*130 + mq + i*4];
}

// -------- channel-major-A MFMA GEMM (fp32 A staged + on-the-fly bf16 split) ---
template<int MODE, int SPLIT, int PERM0>
__global__ __launch_bounds__(256) void gemm_cmaj(
    const float* __restrict__ A0, const float* __restrict__ A1,
    const ushort_t* __restrict__ W0h, const ushort_t* __restrict__ W0l,
    const ushort_t* __restrict__ W1h, const ushort_t* __restrict__ W1l,
    const float* __restrict__ resid,
    float* __restrict__ o0, float* __restrict__ o1, int Nreal)
{
    __shared__ __align__(16) char smem[33280];
    float* sA = (float*)smem;                       // [32][132]
    ushort_t* sWh = (ushort_t*)(smem + 16896);      // [4][64][8]
    ushort_t* sWl = (ushort_t*)(smem + 20992);
    bool sel = (blockIdx.z == 1);
    const float* A = sel ? A1 : A0;
    const ushort_t* Wh = sel ? W1h : W0h;
    const ushort_t* Wl = sel ? W1l : W0l;
    float* out0 = sel ? o1 : o0;
    const bool perm = sel ? false : (PERM0 != 0);
    int tid = threadIdx.x;
    int t0 = blockIdx.x * 128;
    int b = t0 >> 12, l0 = t0 & 4095;
    int n0 = blockIdx.y * 64;
    const float* Ab = A + (size_t)b * 384 * LL;
    int srow = tid >> 3, sc8 = tid & 7;
    int wrow = tid >> 2, kgW = tid & 3;
    int lane = tid & 63, w = tid >> 6;
    int ln = lane & 15, kg = lane >> 4;
    int am0 = w * 32 + ln;
    f32x4 acc[2][4];
#pragma unroll
    for (int mf = 0; mf < 2; mf++)
#pragma unroll
        for (int nf = 0; nf < 4; nf++) acc[mf][nf] = (f32x4){0.f, 0.f, 0.f, 0.f};

    for (int k0 = 0; k0 < 384; k0 += 32) {
        __syncthreads();
#pragma unroll
        for (int i = 0; i < 4; i++) {
            int m = (sc8 + 8*i) * 4;
            int src = perm ? ((((m >> 2) & 3) * 1024) + (((l0 + m) >> 4) << 2))
                           : (l0 + m);
            float4 v = *(const float4*)&Ab[(size_t)(k0 + srow)*LL + src];
            *(float4*)&sA[srow*132 + m] = v;
        }
        {
            ushort8 wv = *(const ushort8*)(Wh + (size_t)(n0 + wrow)*384 + k0 + kgW*8);
            *(ushort8*)(sWh + kgW*512 + wrow*8) = wv;
            if (SPLIT == 3) {
                ushort8 wl = *(const ushort8*)(Wl + (size_t)(n0 + wrow)*384 + k0 + kgW*8);
                *(ushort8*)(sWl + kgW*512 + wrow*8) = wl;
            }
        }
        __syncthreads();
        bf16x8 aH[2], aL[2];
#pragma unroll
        for (int mf = 0; mf < 2; mf++) {
            int am = am0 + mf*16;
#pragma unroll
            for (int e = 0; e < 8; e++) {
                float v = sA[(kg*8 + e)*132 + am];
                ushort_t h = f2bf(v);
                aH[mf][e] = (short)h;
                if (SPLIT == 3) aL[mf][e] = (short)f2bf(v - bf2f(h));
            }
        }
        bf16x8 bH[4], bL[4];
#pragma unroll
        for (int nf = 0; nf < 4; nf++) {
            bH[nf] = *(const bf16x8*)(sWh + kg*512 + (nf*16 + ln)*8);
            if (SPLIT == 3) bL[nf] = *(const bf16x8*)(sWl + kg*512 + (nf*16 + ln)*8);
        }
#pragma unroll
        for (int mf = 0; mf < 2; mf++)
#pragma unroll
            for (int nf = 0; nf < 4; nf++) {
                acc[mf][nf] = __builtin_amdgcn_mfma_f32_16x16x32_bf16(aH[mf], bH[nf], acc[mf][nf], 0, 0, 0);
                if (SPLIT == 3) {
                    acc[mf][nf] = __builtin_amdgcn_mfma_f32_16x16x32_bf16(aH[mf], bL[nf], acc[mf][nf], 0, 0, 0);
                    acc[mf][nf] = __builtin_amdgcn_mfma_f32_16x16x32_bf16(aL[mf], bH[nf], acc[mf][nf], 0, 0, 0);
                }
            }
    }

    if (MODE == 2) {
#pragma unroll
        for (int mf = 0; mf < 2; mf++)
#pragma unroll
            for (int j = 0; j < 4; j++) {
                int t = t0 + w*32 + mf*16 + (lane>>4)*4 + j;
#pragma unroll
                for (int nf = 0; nf < 4; nf++) {
                    int n = n0 + nf*16 + ln;
                    out0[(size_t)t*CM + n] = resid[(size_t)t*CM + n] + acc[mf][nf][j];
                }
            }
    } else {
        __syncthreads();
        float* st = (float*)smem;   // [64][130]
#pragma unroll
        for (int mf = 0; mf < 2; mf++)
#pragma unroll
            for (int nf = 0; nf < 4; nf++)
#pragma unroll
                for (int j = 0; j < 4; j++) {
                    int ml = w*32 + mf*16 + (lane>>4)*4 + j;
                    int nl = nf*16 + ln;
                    st[nl*130 + ml] = acc[mf][nf][j];
                }
        __syncthreads();
        int nl = tid >> 2, mq = (tid & 3) * 32;
        int n = n0 + nl;
        if (n < Nreal) {
            float* dst = out0 + ((size_t)b*Nreal + n)*LL + l0 + mq;
#pragma unroll
            for (int i = 0; i < 8; i++)
                *(float4*)(dst + i*4) = *(const float4*)&st[nl*130 + mq + i*4];
        }
    }
}

// -------- depthwise 3x3 conv + bias + SiLU -> xs in PERM layout ---------------
__global__ __launch_bounds__(256) void conv2d_silu_kernel(const float* __restrict__ xh,
    const float* __restrict__ w, const float* __restrict__ bias, float* __restrict__ xs)
{
    int tid = threadIdx.x;
    int l = blockIdx.x * 256 + tid;
    int c = blockIdx.y, b = blockIdx.z;
    const float* P = xh + ((size_t)b*DI + c)*LL;
    int h = l >> 6, ww = l & 63;
    float acc = bias[c];
#pragma unroll
    for (int kh = 0; kh < 3; kh++) {
        int hh = h + kh - 1;
        if ((unsigned)hh < 64u) {
#pragma unroll
            for (int kw = 0; kw < 3; kw++) {
                int wv = ww + kw - 1;
                if ((unsigned)wv < 64u) acc = fmaf(w[c*9 + kh*3 + kw], P[hh*64 + wv], acc);
            }
        }
    }
    float sg = 1.f / (1.f + __expf(-acc));
    xs[((size_t)b*DI + c)*LL + permidx(l)] = acc * sg;
}

// -------- SimpleGates on low B/C + sum high+low -> dbc [B][44][L] -------------
__global__ __launch_bounds__(256) void gates_kernel(const float* __restrict__ dbcH,
    const float* __restrict__ dbcL,
    const float* __restrict__ sgb1, const float* __restrict__ sgb2,
    const float* __restrict__ sgc1, const float* __restrict__ sgc2,
    float* __restrict__ dbc)
{
    __shared__ float w1[2][192*16];
    __shared__ float w2[2][16*96];
    __shared__ float red[4][16][64];
    int tid = threadIdx.x;
    for (int i = tid; i < 192*16; i += 256) { w1[0][i] = sgb1[i]; w1[1][i] = sgc1[i]; }
    for (int i = tid; i < 16*96;  i += 256) { w2[0][i] = sgb2[i]; w2[1][i] = sgc2[i]; }
    int lq = tid & 63, p = tid >> 6;
    int l = blockIdx.x * 64 + lq;
    int b = blockIdx.y;
    size_t pb_ = (size_t)b*NCH*LL + l;
    __syncthreads();
#pragma unroll
    for (int i = 0; i < 3; i++) {
        int c = p*3 + i;
        dbc[pb_ + (size_t)c*LL] = dbcH[pb_ + (size_t)c*LL] + dbcL[pb_ + (size_t)c*LL];
    }
    for (int gate = 0; gate < 2; gate++) {
        int coff = RK + gate*NST;
        float xin[16], og[16];
#pragma unroll
        for (int n = 0; n < 16; n++) { xin[n] = dbcL[pb_ + (size_t)(coff+n)*LL]; og[n] = 0.f; }
        int h0 = p * 24;
        for (int h = h0; h < h0 + 24; h++) {
            float ya = 0.f, yb = 0.f;
#pragma unroll
            for (int n = 0; n < 16; n++) {
                ya = fmaf(w1[gate][h*16+n], xin[n], ya);
                yb = fmaf(w1[gate][(h+SGH)*16+n], xin[n], yb);
            }
            float gg = 0.5f * ya * (1.f + erff(ya * 0.70710678f)) * yb;
#pragma unroll
            for (int n = 0; n < 16; n++) og[n] = fmaf(w2[gate][n*SGH+h], gg, og[n]);
        }
#pragma unroll
        for (int n = 0; n < 16; n++) red[p][n][lq] = og[n];
        __syncthreads();
#pragma unroll
        for (int i = 0; i < 4; i++) {
            int n = p*4 + i;
            float v = red[0][n][lq] + red[1][n][lq] + red[2][n][lq] + red[3][n][lq];
            dbc[pb_ + (size_t)(coff+n)*LL] = dbcH[pb_ + (size_t)(coff+n)*LL] + v;
        }
        __syncthreads();
    }
}

// -------- residual dilated dwconv1d: dts normal; Bs/Cs in PERM layout ---------
__global__ __launch_bounds__(256) void conv_dbc_kernel(const float* __restrict__ dbc,
    const float* __restrict__ wdt, const float* __restrict__ wB, const float* __restrict__ wC,
    float* __restrict__ dts, float* __restrict__ Bs, float* __restrict__ Cs)
{
    int l = blockIdx.x * 256 + threadIdx.x;
    int c = blockIdx.y, b = blockIdx.z;
    const float* wsrc = (c < RK) ? (wdt + c*15)
                      : (c < RK+NST ? wB + (c-RK)*15 : wC + (c-RK-NST)*15);
    float w[15];
#pragma unroll
    for (int k = 0; k < 15; k++) w[k] = wsrc[k];
    const float* P = dbc + ((size_t)b*NCH + c)*LL;
    float a = P[l];
#pragma unroll
    for (int k = 0; k < 15; k++) {
        int lt = l + 2*k - 14;
        if ((unsigned)lt < (unsigned)LL) a = fmaf(w[k], P[lt], a);
    }
    if (c < RK)            dts[((size_t)b*RK  + c)*LL + l] = a;
    else if (c < RK+NST)   Bs [((size_t)b*NST + (c-RK))*LL + permidx(l)] = a;
    else                   Cs [((size_t)b*NST + (c-RK-NST))*LL + permidx(l)] = a;
}

// -------- delta projection + softplus -> delta in PERM layout -----------------
__global__ __launch_bounds__(256) void delta_kernel(const float* __restrict__ dts,
    const float* __restrict__ dtw, const float* __restrict__ dtb, float* __restrict__ delta)
{
    __shared__ float sdt[RK][128];
    __shared__ float sw[64][RK];
    int tid = threadIdx.x;
    int l0 = blockIdx.x * 128, d0 = blockIdx.y * 64, b = blockIdx.z;
    for (int i = tid; i < RK*128; i += 256) {
        int r = i >> 7, lq = i & 127;
        sdt[r][lq] = dts[((size_t)b*RK + r)*LL + l0 + lq];
    }
    for (int i = tid; i < 64*RK; i += 256) {
        int dq = i / RK, r = i - dq*RK;
        sw[dq][r] = dtw[(size_t)(d0+dq)*RK + r];
    }
    __syncthreads();
    int lq = tid & 63, g = tid >> 6;
    for (int dd = 0; dd < 16; dd++) {
        int dqq = g*16 + dd, d = d0 + dqq;
        float wr[RK];
#pragma unroll
        for (int r = 0; r < RK; r++) wr[r] = sw[dqq][r];
        float bias = dtb[d];
#pragma unroll
        for (int li = 0; li < 2; li++) {
            int lloc = lq + li*64;
            float s = bias;
#pragma unroll
            for (int r = 0; r < RK; r++) s = fmaf(wr[r], sdt[r][lloc], s);
            float sp = fmaxf(s, 0.f) + log1pf(__expf(-fabsf(s)));
            delta[((size_t)b*DI + d)*LL + permidx(l0 + lloc)] = sp;
        }
    }
}

// -------- selective scan v5: merged 16-state block, power-fast-path exp -------
// A_n == -(n+1) (verified at runtime per block) => exp(dl*A_n) = e1^(n+1),
// e1 = exp(-dl): ONE exp per step total, running power E[s] *= e1[s] per state.
// Generic per-state-exp fallback preserves correctness for arbitrary A_logs.
__global__ __launch_bounds__(256) void scan_kernel(
    const float* __restrict__ u_, const float* __restrict__ delta_,
    const float* __restrict__ Bs_, const float* __restrict__ Cs_,
    const float* __restrict__ Alogs, const float* __restrict__ Ds,
    float* __restrict__ y_)
{
    __shared__ float wAs[16][4], wBs[16][4];
    __shared__ float yt[16][258];
    int tid = threadIdx.x;
    int t4 = tid * 4;
    int bd = blockIdx.x;
    int b = bd / DI, d = bd % DI;
    size_t rowoff = ((size_t)b*DI + d)*LL;
    float dl[16], du[16], yac[16], E[16];
    LD16P(du, u_ + rowoff, t4);
    LD16P(dl, delta_ + rowoff, t4);
    float Dd = Ds[d];
#pragma unroll
    for (int s = 0; s < 16; s++) { yac[s] = du[s]*Dd; du[s] = dl[s]*du[s]; E[s] = 1.f; }
    // fast-path check: A_n == -(n+1) for all n (uniform per block)
    bool fast = true;
#pragma unroll 1
    for (int n = 0; n < NST; n++) {
        float An = -__expf(Alogs[d*NST + n]);
        fast = fast && (fabsf(An + (float)(n+1)) < 1e-3f * (float)(n+1));
    }
    if (fast) {
#pragma unroll
        for (int s = 0; s < 16; s++) dl[s] = __expf(-dl[s]);   // dl := e1
    }
    int lane = tid & 63, w = tid >> 6;
#pragma unroll 1
    for (int j = 0; j < NST; j++) {
        float Bn[16], Cn[16];
        LD16P(Bn, Bs_ + ((size_t)b*NST + j)*LL, t4);
        LD16P(Cn, Cs_ + ((size_t)b*NST + j)*LL, t4);
        float a = 1.f, h = 0.f;
        if (fast) {
#pragma unroll
            for (int s = 0; s < 16; s++) {
                E[s] *= dl[s];
                a *= E[s];
                h = fmaf(E[s], h, du[s]*Bn[s]);
                yac[s] = fmaf(Cn[s], h, yac[s]);
                Cn[s] *= a;
            }
        } else {
            float An = -__expf(Alogs[d*NST + j]);
#pragma unroll
            for (int s = 0; s < 16; s++) {
                float e = __expf(dl[s]*An);
                a *= e;
                h = fmaf(e, h, du[s]*Bn[s]);
                yac[s] = fmaf(Cn[s], h, yac[s]);
                Cn[s] *= a;
            }
        }
        // cross-thread affine prefix on (a,h)
        float ap = a, hv = h;
        for (int off = 1; off < 64; off <<= 1) {
            float pa = __shfl_up(ap, (unsigned)off, 64);
            float pb = __shfl_up(hv, (unsigned)off, 64);
            if (lane >= off) { hv = fmaf(ap, pb, hv); ap *= pa; }
        }
        if (lane == 63) { wAs[j][w] = ap; wBs[j][w] = hv; }
        __syncthreads();
        float PB = 0.f;
        for (int ww = 0; ww < w; ww++) PB = fmaf(wAs[j][ww], PB, wBs[j][ww]);
        hv = fmaf(ap, PB, hv);
        float tt = __shfl_up(hv, 1u, 64);
        float hin = lane ? tt : PB;
#pragma unroll
        for (int s = 0; s < 16; s++) yac[s] = fmaf(Cn[s], hin, yac[s]);
    }
#pragma unroll
    for (int i = 0; i < 16; i++) yt[i][tid] = yac[i];
    __syncthreads();
    float* yout = y_ + rowoff;
#pragma unroll
    for (int r = 0; r < 16; r++)
        yout[r*256 + tid] = yt[tid & 15][r*16 + (tid >> 4)];
}

// -------- out-norm LN(384) on y + z-SiLU gating (in-place over y) -------------
__global__ __launch_bounds__(256) void outnorm_gate_kernel(float* yio,
    const float* __restrict__ z,
    const float* __restrict__ g, const float* __restrict__ bt)
{
    __shared__ float rs_[4][64], rq_[4][64];
    __shared__ float mu_s[64], rstd_s[64];
    int tid = threadIdx.x;
    int lq = tid & 63, p = tid >> 6;
    int l = blockIdx.x * 64 + lq;
    int b = blockIdx.y;
    float* yp = yio + (size_t)b*DI*LL + l;
    float s = 0.f, q = 0.f;
#pragma unroll 4
    for (int i = 0; i < 96; i++) {
        int d = p*96 + i;
        float v = yp[(size_t)d*LL];
        s += v; q = fmaf(v, v, q);
    }
    rs_[p][lq] = s; rq_[p][lq] = q;
    __syncthreads();
    if (p == 0) {
        float ss = rs_[0][lq]+rs_[1][lq]+rs_[2][lq]+rs_[3][lq];
        float qq = rq_[0][lq]+rq_[1][lq]+rq_[2][lq]+rq_[3][lq];
        float mu = ss * (1.f/DI);
        float var = qq * (1.f/DI) - mu*mu;
        mu_s[lq] = mu; rstd_s[lq] = rsqrtf(var + 1e-5f);
    }
    __syncthreads();
    float mu = mu_s[lq], rs = rstd_s[lq];
    const float* zp = z + (size_t)b*DI*LL + l;
#pragma unroll 4
    for (int i = 0; i < 96; i++) {
        int d = p*96 + i;
        float v = (yp[(size_t)d*LL] - mu)*rs*g[d] + bt[d];
        float zv = zp[(size_t)d*LL];
        float sg = 1.f / (1.f + __expf(-zv));
        yp[(size_t)d*LL] = v * (zv * sg);
    }
}

extern "C" void kernel_launch(void* const* d_in, const int* in_sizes, int n_in,
                              void* d_out, int out_size, void* d_ws, size_t ws_size,
                              hipStream_t stream)
{
    (void)in_sizes; (void)n_in; (void)out_size; (void)ws_size;
    const float* x     = (const float*)d_in[0];
    const float* low   = (const float*)d_in[1];
    const float* ln_g  = (const float*)d_in[2];
    const float* ln_b  = (const float*)d_in[3];
    const float* w_in  = (const float*)d_in[4];
    const float* w_low = (const float*)d_in[5];
    const float* w_c2d = (const float*)d_in[6];
    const float* b_c2d = (const float*)d_in[7];
    const float* w_xp  = (const float*)d_in[8];
    const float* w_xpl = (const float*)d_in[9];
    const float* w_cdt = (const float*)d_in[10];
    const float* w_cB  = (const float*)d_in[11];
    const float* w_cC  = (const float*)d_in[12];
    const float* sgb1  = (const float*)d_in[13];
    const float* sgb2  = (const float*)d_in[14];
    const float* sgc1  = (const float*)d_in[15];
    const float* sgc2  = (const float*)d_in[16];
    const float* dtw   = (const float*)d_in[17];
    const float* dtb   = (const float*)d_in[18];
    const float* Alogs = (const float*)d_in[19];
    const float* Ds    = (const float*)d_in[20];
    const float* ong   = (const float*)d_in[21];
    const float* onb   = (const float*)d_in[22];
    const float* w_out = (const float*)d_in[23];
    float* ws  = (float*)d_ws;
    float* out = (float*)d_out;
    dim3 blk(256);

    // bf16 plane aliases
    ushort_t* wInH  = (ushort_t*)(ws + O_WT_IN);   ushort_t* wInL  = wInH + 147456;
    ushort_t* wLowH = (ushort_t*)(ws + O_WT_LOW);  ushort_t* wLowL = wLowH + 73728;
    ushort_t* wOutH = (ushort_t*)(ws + O_WT_OUT);  ushort_t* wOutL = wOutH + 73728;
    ushort_t* wXpH  = (ushort_t*)(ws + O_WT_XP);   ushort_t* wXpL  = wXpH + 24576;
    ushort_t* wXplH = (ushort_t*)(ws + O_WT_XPL);  ushort_t* wXplL = wXplH + 24576;
    ushort_t* xnh   = (ushort_t*)(ws + O_XN);      ushort_t* xnl   = xnh + 3145728;
    ushort_t* lowh  = (ushort_t*)(ws + O_LOWT);    ushort_t* lowl  = lowh + 3145728;

    split3_kernel<<<288, blk, 0, stream>>>(w_in, wInH, wInL, w_low, wLowH, wLowL,
                                           w_out, wOutH, wOutL);
    split_padw_kernel<<<dim3(24,2), blk, 0, stream>>>(w_xp, wXpH, wXpL, w_xpl, wXplH, wXplL);

    ln_split_kernel<<<256, blk, 0, stream>>>(x, ln_g, ln_b, xnh, xnl);
    split_plain_kernel<<<3072, blk, 0, stream>>>(low, lowh, lowl, 3145728);

    gemm_mfma<0,3,192><<<dim3(128,12), blk, 0, stream>>>(xnh, xnl, wInH, wInL,
                                                         ws+O_XH, ws+O_Z);
    gemm_mfma<1,3,192><<<dim3(128,6),  blk, 0, stream>>>(lowh, lowl, wLowH, wLowL,
                                                         ws+O_LOWP, nullptr);

    conv2d_silu_kernel<<<dim3(16,384,4), blk, 0, stream>>>(ws+O_XH, w_c2d, b_c2d, ws+O_XS);

    gemm_cmaj<1,3,1><<<dim3(128,1,2), blk, 0, stream>>>(ws+O_XS, ws+O_LOWP,
                                                        wXpH, wXpL, wXplH, wXplL,
                                                        nullptr, ws+O_DBCH, ws+O_DBCL, NCH);

    gates_kernel<<<dim3(64,4), blk, 0, stream>>>(ws+O_DBCH, ws+O_DBCL, sgb1, sgb2, sgc1, sgc2, ws+O_DBC);

    conv_dbc_kernel<<<dim3(16,44,4), blk, 0, stream>>>(ws+O_DBC, w_cdt, w_cB, w_cC,
                                                       ws+O_DTS, ws+O_BS, ws+O_CS);
    delta_kernel<<<dim3(32,6,4), blk, 0, stream>>>(ws+O_DTS, dtw, dtb, ws+O_DELTA);

    scan_kernel<<<1536, blk, 0, stream>>>(ws+O_XS, ws+O_DELTA, ws+O_BS, ws+O_CS, Alogs, Ds,
                                          ws+O_Y);

    outnorm_gate_kernel<<<dim3(64,4), blk, 0, stream>>>(ws+O_Y, ws+O_Z, ong, onb);

    gemm_cmaj<2,1,0><<<dim3(128,3,1), blk, 0, stream>>>(ws+O_Y, nullptr,
                                                        wOutH, wOutL, nullptr, nullptr,
                                                        x, out, nullptr, CM);
}

// Round 8
// 307.365 us; speedup vs baseline: 2.6234x; 1.0074x over previous
//
#include <hip/hip_runtime.h>
#include <math.h>

#define LL 4096
#define NBATCH 4
#define CM 192
#define DI 384
#define NST 16
#define RK 12
#define NCH 44
#define SGH 96

typedef unsigned short ushort_t;
typedef __attribute__((ext_vector_type(8))) short bf16x8;
typedef __attribute__((ext_vector_type(4))) float f32x4;
typedef __attribute__((ext_vector_type(8))) unsigned short ushort8;
typedef __attribute__((ext_vector_type(4))) unsigned short ushort4v;

// workspace offsets (float units)
#define O_WT_IN   0
#define O_WT_LOW  147456
#define O_WT_XP   221184
#define O_WT_XPL  245760
#define O_WT_OUT  270336
#define O_XN      344064
#define O_LOWT    3489792
#define O_XH      6635520
#define O_Z       12926976
#define O_LOWP    19218432
#define O_XS      25509888
#define O_DBCH    31801344
#define O_DBCL    32522240
#define O_DBC     33243136
#define O_BS      33964032
#define O_CS      34226176
#define O_DELTA   O_LOWP   // lowp dead after x_proj GEMMs
#define O_Y       O_XH     // xh dead after conv2d
#define O_DTS     O_DBCH   // dbcH dead after gates_kernel

__device__ __forceinline__ ushort_t f2bf(float v) {
    unsigned u = __float_as_uint(v);
    return (ushort_t)((u + 0x7FFFu + ((u >> 16) & 1u)) >> 16);
}
__device__ __forceinline__ float bf2f(ushort_t h) {
    return __uint_as_float(((unsigned)h) << 16);
}

// ---- chunk-transposed ("perm") layout within each 4096-element row ----------
__device__ __forceinline__ int permidx(int l) {
    return ((l >> 2) & 3) * 1024 + ((l >> 4) << 2) + (l & 3);
}

#define LD16P(dst, row, t4) { \
  float4 _a = *(const float4*)((row) + (t4)); \
  float4 _b = *(const float4*)((row) + 1024 + (t4)); \
  float4 _c = *(const float4*)((row) + 2048 + (t4)); \
  float4 _d = *(const float4*)((row) + 3072 + (t4)); \
  dst[0]=_a.x; dst[1]=_a.y; dst[2]=_a.z; dst[3]=_a.w; \
  dst[4]=_b.x; dst[5]=_b.y; dst[6]=_b.z; dst[7]=_b.w; \
  dst[8]=_c.x; dst[9]=_c.y; dst[10]=_c.z; dst[11]=_c.w; \
  dst[12]=_d.x; dst[13]=_d.y; dst[14]=_d.z; dst[15]=_d.w; }

// -------- merged weight prep: hi/lo splits + padded x_proj weights ------------
__global__ void wprep_kernel(const float* __restrict__ i0, ushort_t* h0, ushort_t* l0_,
                             const float* __restrict__ i1, ushort_t* h1, ushort_t* l1,
                             const float* __restrict__ i2, ushort_t* h2, ushort_t* l2,
                             const float* __restrict__ p0, ushort_t* ph0, ushort_t* pl0,
                             const float* __restrict__ p1, ushort_t* ph1, ushort_t* pl1)
{
    int bx = blockIdx.x;
    if (bx < 288) {
        const float* in; ushort_t* oh; ushort_t* ol; int base;
        if (bx < 144)      { in = i0; oh = h0; ol = l0_; base = bx * 1024; }
        else if (bx < 216) { in = i1; oh = h1; ol = l1;  base = (bx-144) * 1024; }
        else               { in = i2; oh = h2; ol = l2;  base = (bx-216) * 1024; }
        int i = base + threadIdx.x * 4;
        float4 v = *(const float4*)&in[i];
        ushort4v h, l;
        h.x = f2bf(v.x); l.x = f2bf(v.x - bf2f(h.x));
        h.y = f2bf(v.y); l.y = f2bf(v.y - bf2f(h.y));
        h.z = f2bf(v.z); l.z = f2bf(v.z - bf2f(h.z));
        h.w = f2bf(v.w); l.w = f2bf(v.w - bf2f(h.w));
        *(ushort4v*)&oh[i] = h;
        *(ushort4v*)&ol[i] = l;
    } else {
        int bb = bx - 288;
        int sel = bb / 24, bxx = bb % 24;
        const float* in = sel ? p1 : p0;
        ushort_t* oh = sel ? ph1 : ph0;
        ushort_t* ol = sel ? pl1 : pl0;
        int idx = (bxx * 256 + threadIdx.x) * 4;
        int n = idx / 384;
        float4 v = (n < NCH) ? *(const float4*)&in[idx] : make_float4(0.f,0.f,0.f,0.f);
        ushort4v h, l;
        h.x = f2bf(v.x); l.x = f2bf(v.x - bf2f(h.x));
        h.y = f2bf(v.y); l.y = f2bf(v.y - bf2f(h.y));
        h.z = f2bf(v.z); l.z = f2bf(v.z - bf2f(h.z));
        h.w = f2bf(v.w); l.w = f2bf(v.w - bf2f(h.w));
        *(ushort4v*)&oh[idx] = h;
        *(ushort4v*)&ol[idx] = l;
    }
}

// -------- merged activation prep: LN(192)+split (x) and plain split (low) -----
__global__ __launch_bounds__(256) void actprep_kernel(const float* __restrict__ X,
    const float* __restrict__ gw, const float* __restrict__ bw,
    ushort_t* __restrict__ oh, ushort_t* __restrict__ ol,
    const float* __restrict__ LOW, ushort_t* __restrict__ lh, ushort_t* __restrict__ llo)
{
    __shared__ float xt[64][193];
    __shared__ float reds[64][4], redq[64][4];
    __shared__ float mu_s[64], rs_s[64];
    int tid = threadIdx.x;
    if (blockIdx.x >= 256) {
        int i = ((blockIdx.x - 256) * 256 + tid) * 4;
        float4 v = *(const float4*)&LOW[i];
        ushort4v h, l;
        h.x = f2bf(v.x); l.x = f2bf(v.x - bf2f(h.x));
        h.y = f2bf(v.y); l.y = f2bf(v.y - bf2f(h.y));
        h.z = f2bf(v.z); l.z = f2bf(v.z - bf2f(h.z));
        h.w = f2bf(v.w); l.w = f2bf(v.w - bf2f(h.w));
        *(ushort4v*)&lh[i] = h;
        *(ushort4v*)&llo[i] = l;
        return;
    }
    int t0 = blockIdx.x * 64;
    const float* Xb = X + (size_t)t0 * CM;
#pragma unroll
    for (int i = 0; i < 12; i++) {
        int f4 = tid + 256 * i;
        float4 v = *(const float4*)&Xb[f4 * 4];
        int row = f4 / 48, c = (f4 % 48) * 4;
        xt[row][c] = v.x; xt[row][c+1] = v.y; xt[row][c+2] = v.z; xt[row][c+3] = v.w;
    }
    __syncthreads();
    int tok = tid & 63, p = tid >> 6;
    float s = 0.f, q = 0.f;
#pragma unroll 8
    for (int i = 0; i < 48; i++) { float v = xt[tok][p*48+i]; s += v; q = fmaf(v, v, q); }
    reds[tok][p] = s; redq[tok][p] = q;
    __syncthreads();
    if (tid < 64) {
        float ss = reds[tid][0]+reds[tid][1]+reds[tid][2]+reds[tid][3];
        float qq = redq[tid][0]+redq[tid][1]+redq[tid][2]+redq[tid][3];
        float mu = ss * (1.f/CM);
        float var = qq * (1.f/CM) - mu*mu;
        mu_s[tid] = mu; rs_s[tid] = rsqrtf(var + 1e-5f);
    }
    __syncthreads();
    int tok2 = tid >> 2, c0 = (tid & 3) * 48;
    float mu = mu_s[tok2], rs = rs_s[tok2];
    size_t tb = (size_t)(t0 + tok2) * CM;
#pragma unroll 8
    for (int i = 0; i < 48; i++) {
        int c = c0 + i;
        float v = (xt[tok2][c] - mu) * rs * gw[c] + bw[c];
        ushort_t h = f2bf(v);
        oh[tb + c] = h;
        ol[tb + c] = f2bf(v - bf2f(h));
    }
}

// -------- split-bf16 MFMA GEMM, token-major bf16 A planes ---------------------
template<int MODE, int SPLIT, int KDIM>
__global__ __launch_bounds__(256) void gemm_mfma(
    const ushort_t* __restrict__ Ahi, const ushort_t* __restrict__ Alo,
    const ushort_t* __restrict__ Whi, const ushort_t* __restrict__ Wlo,
    float* __restrict__ out0, float* __restrict__ out1)
{
    __shared__ __align__(16) char smem[33280];
    ushort_t* sAh = (ushort_t*)smem;        // [4][128][8]
    ushort_t* sAl = sAh + 4096;
    ushort_t* sWh = sAh + 8192;             // [4][64][8]
    ushort_t* sWl = sAh + 10240;
    int tid = threadIdx.x;
    int t0 = blockIdx.x * 128;
    int b = t0 >> 12, l0 = t0 & 4095;
    int n0 = blockIdx.y * 64;
    int arow = tid >> 1, kgA = (tid & 1) * 2;
    int wrow = tid >> 2, kgW = tid & 3;
    const ushort_t* gAh = Ahi + (size_t)(t0 + arow) * KDIM + kgA * 8;
    const ushort_t* gAl = Alo + (size_t)(t0 + arow) * KDIM + kgA * 8;
    const ushort_t* gWh = Whi + (size_t)(n0 + wrow) * KDIM + kgW * 8;
    const ushort_t* gWl = Wlo + (size_t)(n0 + wrow) * KDIM + kgW * 8;
    int lane = tid & 63, w = tid >> 6;
    int ln = lane & 15, kg = lane >> 4;
    int am0 = w * 32 + ln;
    f32x4 acc[2][4];
#pragma unroll
    for (int mf = 0; mf < 2; mf++)
#pragma unroll
        for (int nf = 0; nf < 4; nf++) acc[mf][nf] = (f32x4){0.f, 0.f, 0.f, 0.f};

    for (int k0 = 0; k0 < KDIM; k0 += 32) {
        __syncthreads();
        {
            ushort8 a0 = *(const ushort8*)(gAh + k0);
            ushort8 a1 = *(const ushort8*)(gAh + k0 + 8);
            *(ushort8*)(sAh + kgA*1024 + arow*8) = a0;
            *(ushort8*)(sAh + (kgA+1)*1024 + arow*8) = a1;
            ushort8 w0 = *(const ushort8*)(gWh + k0);
            *(ushort8*)(sWh + kgW*512 + wrow*8) = w0;
            if (SPLIT == 3) {
                ushort8 b0 = *(const ushort8*)(gAl + k0);
                ushort8 b1 = *(const ushort8*)(gAl + k0 + 8);
                *(ushort8*)(sAl + kgA*1024 + arow*8) = b0;
                *(ushort8*)(sAl + (kgA+1)*1024 + arow*8) = b1;
                ushort8 w1 = *(const ushort8*)(gWl + k0);
                *(ushort8*)(sWl + kgW*512 + wrow*8) = w1;
            }
        }
        __syncthreads();
        bf16x8 aH[2], bH[4];
#pragma unroll
        for (int mf = 0; mf < 2; mf++)
            aH[mf] = *(const bf16x8*)(sAh + kg*1024 + (am0 + mf*16)*8);
#pragma unroll
        for (int nf = 0; nf < 4; nf++)
            bH[nf] = *(const bf16x8*)(sWh + kg*512 + (nf*16 + ln)*8);
#pragma unroll
        for (int mf = 0; mf < 2; mf++)
#pragma unroll
            for (int nf = 0; nf < 4; nf++)
                acc[mf][nf] = __builtin_amdgcn_mfma_f32_16x16x32_bf16(aH[mf], bH[nf], acc[mf][nf], 0, 0, 0);
        if (SPLIT == 3) {
            bf16x8 aL[2], bL[4];
#pragma unroll
            for (int mf = 0; mf < 2; mf++)
                aL[mf] = *(const bf16x8*)(sAl + kg*1024 + (am0 + mf*16)*8);
#pragma unroll
            for (int nf = 0; nf < 4; nf++)
                bL[nf] = *(const bf16x8*)(sWl + kg*512 + (nf*16 + ln)*8);
#pragma unroll
            for (int mf = 0; mf < 2; mf++)
#pragma unroll
                for (int nf = 0; nf < 4; nf++) {
                    acc[mf][nf] = __builtin_amdgcn_mfma_f32_16x16x32_bf16(aH[mf], bL[nf], acc[mf][nf], 0, 0, 0);
                    acc[mf][nf] = __builtin_amdgcn_mfma_f32_16x16x32_bf16(aL[mf], bH[nf], acc[mf][nf], 0, 0, 0);
                }
        }
    }
    __syncthreads();
    float* st = (float*)smem;   // [64][130]
#pragma unroll
    for (int mf = 0; mf < 2; mf++)
#pragma unroll
        for (int nf = 0; nf < 4; nf++)
#pragma unroll
            for (int j = 0; j < 4; j++) {
                int ml = w*32 + mf*16 + (lane>>4)*4 + j;
                int nl = nf*16 + ln;
                st[nl*130 + ml] = acc[mf][nf][j];
            }
    __syncthreads();
    int nl = tid >> 2, mq = (tid & 3) * 32;
    int n = n0 + nl;
    float* dst;
    if (MODE == 0) {
        dst = (n < DI) ? (out0 + ((size_t)b*DI + n)*LL + l0 + mq)
                       : (out1 + ((size_t)b*DI + (n - DI))*LL + l0 + mq);
    } else {
        dst = out0 + ((size_t)b*DI + n)*LL + l0 + mq;
    }
#pragma unroll
    for (int i = 0; i < 8; i++)
        *(float4*)(dst + i*4) = *(const float4*)&st[nl*130 + mq + i*4];
}

// -------- channel-major-A MFMA GEMM (fp32 A staged + on-the-fly bf16 split) ---
template<int MODE, int SPLIT, int PERM0>
__global__ __launch_bounds__(256) void gemm_cmaj(
    const float* __restrict__ A0, const float* __restrict__ A1,
    const ushort_t* __restrict__ W0h, const ushort_t* __restrict__ W0l,
    const ushort_t* __restrict__ W1h, const ushort_t* __restrict__ W1l,
    const float* __restrict__ resid,
    float* __restrict__ o0, float* __restrict__ o1, int Nreal)
{
    __shared__ __align__(16) char smem[33280];
    float* sA = (float*)smem;                       // [32][132]
    ushort_t* sWh = (ushort_t*)(smem + 16896);      // [4][64][8]
    ushort_t* sWl = (ushort_t*)(smem + 20992);
    bool sel = (blockIdx.z == 1);
    const float* A = sel ? A1 : A0;
    const ushort_t* Wh = sel ? W1h : W0h;
    const ushort_t* Wl = sel ? W1l : W0l;
    float* out0 = sel ? o1 : o0;
    const bool perm = sel ? false : (PERM0 != 0);
    int tid = threadIdx.x;
    int t0 = blockIdx.x * 128;
    int b = t0 >> 12, l0 = t0 & 4095;
    int n0 = blockIdx.y * 64;
    const float* Ab = A + (size_t)b * 384 * LL;
    int srow = tid >> 3, sc8 = tid & 7;
    int wrow = tid >> 2, kgW = tid & 3;
    int lane = tid & 63, w = tid >> 6;
    int ln = lane & 15, kg = lane >> 4;
    int am0 = w * 32 + ln;
    f32x4 acc[2][4];
#pragma unroll
    for (int mf = 0; mf < 2; mf++)
#pragma unroll
        for (int nf = 0; nf < 4; nf++) acc[mf][nf] = (f32x4){0.f, 0.f, 0.f, 0.f};

    for (int k0 = 0; k0 < 384; k0 += 32) {
        __syncthreads();
#pragma unroll
        for (int i = 0; i < 4; i++) {
            int m = (sc8 + 8*i) * 4;
            int src = perm ? ((((m >> 2) & 3) * 1024) + (((l0 + m) >> 4) << 2))
                           : (l0 + m);
            float4 v = *(const float4*)&Ab[(size_t)(k0 + srow)*LL + src];
            *(float4*)&sA[srow*132 + m] = v;
        }
        {
            ushort8 wv = *(const ushort8*)(Wh + (size_t)(n0 + wrow)*384 + k0 + kgW*8);
            *(ushort8*)(sWh + kgW*512 + wrow*8) = wv;
            if (SPLIT == 3) {
                ushort8 wl = *(const ushort8*)(Wl + (size_t)(n0 + wrow)*384 + k0 + kgW*8);
                *(ushort8*)(sWl + kgW*512 + wrow*8) = wl;
            }
        }
        __syncthreads();
        bf16x8 aH[2], aL[2];
#pragma unroll
        for (int mf = 0; mf < 2; mf++) {
            int am = am0 + mf*16;
#pragma unroll
            for (int e = 0; e < 8; e++) {
                float v = sA[(kg*8 + e)*132 + am];
                ushort_t h = f2bf(v);
                aH[mf][e] = (short)h;
                if (SPLIT == 3) aL[mf][e] = (short)f2bf(v - bf2f(h));
            }
        }
        bf16x8 bH[4], bL[4];
#pragma unroll
        for (int nf = 0; nf < 4; nf++) {
            bH[nf] = *(const bf16x8*)(sWh + kg*512 + (nf*16 + ln)*8);
            if (SPLIT == 3) bL[nf] = *(const bf16x8*)(sWl + kg*512 + (nf*16 + ln)*8);
        }
#pragma unroll
        for (int mf = 0; mf < 2; mf++)
#pragma unroll
            for (int nf = 0; nf < 4; nf++) {
                acc[mf][nf] = __builtin_amdgcn_mfma_f32_16x16x32_bf16(aH[mf], bH[nf], acc[mf][nf], 0, 0, 0);
                if (SPLIT == 3) {
                    acc[mf][nf] = __builtin_amdgcn_mfma_f32_16x16x32_bf16(aH[mf], bL[nf], acc[mf][nf], 0, 0, 0);
                    acc[mf][nf] = __builtin_amdgcn_mfma_f32_16x16x32_bf16(aL[mf], bH[nf], acc[mf][nf], 0, 0, 0);
                }
            }
    }

    if (MODE == 2) {
#pragma unroll
        for (int mf = 0; mf < 2; mf++)
#pragma unroll
            for (int j = 0; j < 4; j++) {
                int t = t0 + w*32 + mf*16 + (lane>>4)*4 + j;
#pragma unroll
                for (int nf = 0; nf < 4; nf++) {
                    int n = n0 + nf*16 + ln;
                    out0[(size_t)t*CM + n] = resid[(size_t)t*CM + n] + acc[mf][nf][j];
                }
            }
    } else {
        __syncthreads();
        float* st = (float*)smem;   // [64][130]
#pragma unroll
        for (int mf = 0; mf < 2; mf++)
#pragma unroll
            for (int nf = 0; nf < 4; nf++)
#pragma unroll
                for (int j = 0; j < 4; j++) {
                    int ml = w*32 + mf*16 + (lane>>4)*4 + j;
                    int nl = nf*16 + ln;
                    st[nl*130 + ml] = acc[mf][nf][j];
                }
        __syncthreads();
        int nl = tid >> 2, mq = (tid & 3) * 32;
        int n = n0 + nl;
        if (n < Nreal) {
            float* dst = out0 + ((size_t)b*Nreal + n)*LL + l0 + mq;
#pragma unroll
            for (int i = 0; i < 8; i++)
                *(float4*)(dst + i*4) = *(const float4*)&st[nl*130 + mq + i*4];
        }
    }
}

// -------- depthwise 3x3 conv + bias + SiLU -> xs in PERM layout ---------------
__global__ __launch_bounds__(256) void conv2d_silu_kernel(const float* __restrict__ xh,
    const float* __restrict__ w, const float* __restrict__ bias, float* __restrict__ xs)
{
    int tid = threadIdx.x;
    int l = blockIdx.x * 256 + tid;
    int c = blockIdx.y, b = blockIdx.z;
    const float* P = xh + ((size_t)b*DI + c)*LL;
    int h = l >> 6, ww = l & 63;
    float acc = bias[c];
#pragma unroll
    for (int kh = 0; kh < 3; kh++) {
        int hh = h + kh - 1;
        if ((unsigned)hh < 64u) {
#pragma unroll
            for (int kw = 0; kw < 3; kw++) {
                int wv = ww + kw - 1;
                if ((unsigned)wv < 64u) acc = fmaf(w[c*9 + kh*3 + kw], P[hh*64 + wv], acc);
            }
        }
    }
    float sg = 1.f / (1.f + __expf(-acc));
    xs[((size_t)b*DI + c)*LL + permidx(l)] = acc * sg;
}

// -------- SimpleGates on low B/C + sum high+low -> dbc [B][44][L] -------------
__global__ __launch_bounds__(256) void gates_kernel(const float* __restrict__ dbcH,
    const float* __restrict__ dbcL,
    const float* __restrict__ sgb1, const float* __restrict__ sgb2,
    const float* __restrict__ sgc1, const float* __restrict__ sgc2,
    float* __restrict__ dbc)
{
    __shared__ float w1[2][192*16];
    __shared__ float w2[2][16*96];
    __shared__ float red[4][16][64];
    int tid = threadIdx.x;
    for (int i = tid; i < 192*16; i += 256) { w1[0][i] = sgb1[i]; w1[1][i] = sgc1[i]; }
    for (int i = tid; i < 16*96;  i += 256) { w2[0][i] = sgb2[i]; w2[1][i] = sgc2[i]; }
    int lq = tid & 63, p = tid >> 6;
    int l = blockIdx.x * 64 + lq;
    int b = blockIdx.y;
    size_t pb_ = (size_t)b*NCH*LL + l;
    __syncthreads();
#pragma unroll
    for (int i = 0; i < 3; i++) {
        int c = p*3 + i;
        dbc[pb_ + (size_t)c*LL] = dbcH[pb_ + (size_t)c*LL] + dbcL[pb_ + (size_t)c*LL];
    }
    for (int gate = 0; gate < 2; gate++) {
        int coff = RK + gate*NST;
        float xin[16], og[16];
#pragma unroll
        for (int n = 0; n < 16; n++) { xin[n] = dbcL[pb_ + (size_t)(coff+n)*LL]; og[n] = 0.f; }
        int h0 = p * 24;
        for (int h = h0; h < h0 + 24; h++) {
            float ya = 0.f, yb = 0.f;
#pragma unroll
            for (int n = 0; n < 16; n++) {
                ya = fmaf(w1[gate][h*16+n], xin[n], ya);
                yb = fmaf(w1[gate][(h+SGH)*16+n], xin[n], yb);
            }
            float gg = 0.5f * ya * (1.f + erff(ya * 0.70710678f)) * yb;
#pragma unroll
            for (int n = 0; n < 16; n++) og[n] = fmaf(w2[gate][n*SGH+h], gg, og[n]);
        }
#pragma unroll
        for (int n = 0; n < 16; n++) red[p][n][lq] = og[n];
        __syncthreads();
#pragma unroll
        for (int i = 0; i < 4; i++) {
            int n = p*4 + i;
            float v = red[0][n][lq] + red[1][n][lq] + red[2][n][lq] + red[3][n][lq];
            dbc[pb_ + (size_t)(coff+n)*LL] = dbcH[pb_ + (size_t)(coff+n)*LL] + v;
        }
        __syncthreads();
    }
}

// -------- residual dilated dwconv1d: dts normal; Bs/Cs in PERM layout ---------
__global__ __launch_bounds__(256) void conv_dbc_kernel(const float* __restrict__ dbc,
    const float* __restrict__ wdt, const float* __restrict__ wB, const float* __restrict__ wC,
    float* __restrict__ dts, float* __restrict__ Bs, float* __restrict__ Cs)
{
    int l = blockIdx.x * 256 + threadIdx.x;
    int c = blockIdx.y, b = blockIdx.z;
    const float* wsrc = (c < RK) ? (wdt + c*15)
                      : (c < RK+NST ? wB + (c-RK)*15 : wC + (c-RK-NST)*15);
    float w[15];
#pragma unroll
    for (int k = 0; k < 15; k++) w[k] = wsrc[k];
    const float* P = dbc + ((size_t)b*NCH + c)*LL;
    float a = P[l];
#pragma unroll
    for (int k = 0; k < 15; k++) {
        int lt = l + 2*k - 14;
        if ((unsigned)lt < (unsigned)LL) a = fmaf(w[k], P[lt], a);
    }
    if (c < RK)            dts[((size_t)b*RK  + c)*LL + l] = a;
    else if (c < RK+NST)   Bs [((size_t)b*NST + (c-RK))*LL + permidx(l)] = a;
    else                   Cs [((size_t)b*NST + (c-RK-NST))*LL + permidx(l)] = a;
}

// -------- delta projection + softplus -> delta in PERM layout -----------------
__global__ __launch_bounds__(256) void delta_kernel(const float* __restrict__ dts,
    const float* __restrict__ dtw, const float* __restrict__ dtb, float* __restrict__ delta)
{
    __shared__ float sdt[RK][128];
    __shared__ float sw[64][RK];
    int tid = threadIdx.x;
    int l0 = blockIdx.x * 128, d0 = blockIdx.y * 64, b = blockIdx.z;
    for (int i = tid; i < RK*128; i += 256) {
        int r = i >> 7, lq = i & 127;
        sdt[r][lq] = dts[((size_t)b*RK + r)*LL + l0 + lq];
    }
    for (int i = tid; i < 64*RK; i += 256) {
        int dq = i / RK, r = i - dq*RK;
        sw[dq][r] = dtw[(size_t)(d0+dq)*RK + r];
    }
    __syncthreads();
    int lq = tid & 63, g = tid >> 6;
    for (int dd = 0; dd < 16; dd++) {
        int dqq = g*16 + dd, d = d0 + dqq;
        float wr[RK];
#pragma unroll
        for (int r = 0; r < RK; r++) wr[r] = sw[dqq][r];
        float bias = dtb[d];
#pragma unroll
        for (int li = 0; li < 2; li++) {
            int lloc = lq + li*64;
            float s = bias;
#pragma unroll
            for (int r = 0; r < RK; r++) s = fmaf(wr[r], sdt[r][lloc], s);
            float sp = fmaxf(s, 0.f) + log1pf(__expf(-fabsf(s)));
            delta[((size_t)b*DI + d)*LL + permidx(l0 + lloc)] = sp;
        }
    }
}

// -------- selective scan v6: single-barrier fast path via closed-form powers --
// fast (A_n == -(n+1)): decay_j[s] = e1[s]^(j+1), a_cum_j[s] = Pc[s]^(j+1)
// (Pc = cumprod e1). Phase A: all local scans + register shuffle scans.
// ONE barrier. Phase B: per-state fixup with running power Q[s] *= Pc[s].
__global__ __launch_bounds__(256) void scan_kernel(
    const float* __restrict__ u_, const float* __restrict__ delta_,
    const float* __restrict__ Bs_, const float* __restrict__ Cs_,
    const float* __restrict__ Alogs, const float* __restrict__ Ds,
    float* __restrict__ y_)
{
    __shared__ float wAs[16][4], wBs[16][4];
    __shared__ float yt[16][258];
    int tid = threadIdx.x;
    int t4 = tid * 4;
    int bd = blockIdx.x;
    int b = bd / DI, d = bd % DI;
    size_t rowoff = ((size_t)b*DI + d)*LL;
    float dl[16], du[16], yac[16];
    LD16P(du, u_ + rowoff, t4);
    LD16P(dl, delta_ + rowoff, t4);
    float Dd = Ds[d];
#pragma unroll
    for (int s = 0; s < 16; s++) { yac[s] = du[s]*Dd; du[s] = dl[s]*du[s]; }
    bool fast = true;
#pragma unroll 1
    for (int n = 0; n < NST; n++) {
        float An = -__expf(Alogs[d*NST + n]);
        fast = fast && (fabsf(An + (float)(n+1)) < 1e-3f * (float)(n+1));
    }
    int lane = tid & 63, w = tid >> 6;
    if (fast) {
        float Pc[16], E[16], ap[16], hv[16];
#pragma unroll
        for (int s = 0; s < 16; s++) dl[s] = __expf(-dl[s]);   // dl := e1
        float run = 1.f;
#pragma unroll
        for (int s = 0; s < 16; s++) { run *= dl[s]; Pc[s] = run; E[s] = 1.f; }
        float Apow = 1.f;
        // Phase A: local scans + wave shuffle scans (no barrier)
#pragma unroll 1
        for (int j = 0; j < NST; j++) {
            float Bn[16], Cn[16];
            LD16P(Bn, Bs_ + ((size_t)b*NST + j)*LL, t4);
            LD16P(Cn, Cs_ + ((size_t)b*NST + j)*LL, t4);
            float h = 0.f;
#pragma unroll
            for (int s = 0; s < 16; s++) {
                E[s] *= dl[s];
                h = fmaf(E[s], h, du[s]*Bn[s]);
                yac[s] = fmaf(Cn[s], h, yac[s]);
            }
            Apow *= Pc[15];
            float a = Apow;
            for (int off = 1; off < 64; off <<= 1) {
                float pa = __shfl_up(a, (unsigned)off, 64);
                float pb = __shfl_up(h, (unsigned)off, 64);
                if (lane >= off) { h = fmaf(a, pb, h); a *= pa; }
            }
            ap[j] = a; hv[j] = h;
            if (lane == 63) { wAs[j][w] = a; wBs[j][w] = h; }
        }
        __syncthreads();
        // Phase B: fixup (C reloads are L2 hits; whole C tensor is 1 MB)
        float Q[16];
#pragma unroll
        for (int s = 0; s < 16; s++) Q[s] = Pc[s];
#pragma unroll 1
        for (int j = 0; j < NST; j++) {
            float PB = 0.f;
            for (int ww = 0; ww < w; ww++) PB = fmaf(wAs[j][ww], PB, wBs[j][ww]);
            float hvv = fmaf(ap[j], PB, hv[j]);
            float tt = __shfl_up(hvv, 1u, 64);
            float hin = lane ? tt : PB;
            float Cn[16];
            LD16P(Cn, Cs_ + ((size_t)b*NST + j)*LL, t4);
#pragma unroll
            for (int s = 0; s < 16; s++) {
                yac[s] = fmaf(Cn[s]*Q[s], hin, yac[s]);
                Q[s] *= Pc[s];
            }
        }
    } else {
        // generic fallback: per-state exp + per-state barrier (correct for any A)
        float E[16];
#pragma unroll
        for (int s = 0; s < 16; s++) E[s] = 1.f;
#pragma unroll 1
        for (int j = 0; j < NST; j++) {
            float Bn[16], Cn[16];
            LD16P(Bn, Bs_ + ((size_t)b*NST + j)*LL, t4);
            LD16P(Cn, Cs_ + ((size_t)b*NST + j)*LL, t4);
            float An = -__expf(Alogs[d*NST + j]);
            float a = 1.f, h = 0.f;
#pragma unroll
            for (int s = 0; s < 16; s++) {
                float e = __expf(dl[s]*An);
                a *= e;
                h = fmaf(e, h, du[s]*Bn[s]);
                yac[s] = fmaf(Cn[s], h, yac[s]);
                Cn[s] *= a;
            }
            float ap = a, hv = h;
            for (int off = 1; off < 64; off <<= 1) {
                float pa = __shfl_up(ap, (unsigned)off, 64);
                float pb = __shfl_up(hv, (unsigned)off, 64);
                if (lane >= off) { hv = fmaf(ap, pb, hv); ap *= pa; }
            }
            if (lane == 63) { wAs[j][w] = ap; wBs[j][w] = hv; }
            __syncthreads();
            float PB = 0.f;
            for (int ww = 0; ww < w; ww++) PB = fmaf(wAs[j][ww], PB, wBs[j][ww]);
            hv = fmaf(ap, PB, hv);
            float tt = __shfl_up(hv, 1u, 64);
            float hin = lane ? tt : PB;
#pragma unroll
            for (int s = 0; s < 16; s++) yac[s] = fmaf(Cn[s], hin, yac[s]);
        }
    }
#pragma unroll
    for (int i = 0; i < 16; i++) yt[i][tid] = yac[i];
    __syncthreads();
    float* yout = y_ + rowoff;
#pragma unroll
    for (int r = 0; r < 16; r++)
        yout[r*256 + tid] = yt[tid & 15][r*16 + (tid >> 4)];
}

// -------- out-norm LN(384) on y + z-SiLU gating (in-place over y) -------------
__global__ __launch_bounds__(256) void outnorm_gate_kernel(float* yio,
    const float* __restrict__ z,
    const float* __restrict__ g, const float* __restrict__ bt)
{
    __shared__ float rs_[4][64], rq_[4][64];
    __shared__ float mu_s[64], rstd_s[64];
    int tid = threadIdx.x;
    int lq = tid & 63, p = tid >> 6;
    int l = blockIdx.x * 64 + lq;
    int b = blockIdx.y;
    float* yp = yio + (size_t)b*DI*LL + l;
    float s = 0.f, q = 0.f;
#pragma unroll 4
    for (int i = 0; i < 96; i++) {
        int d = p*96 + i;
        float v = yp[(size_t)d*LL];
        s += v; q = fmaf(v, v, q);
    }
    rs_[p][lq] = s; rq_[p][lq] = q;
    __syncthreads();
    if (p == 0) {
        float ss = rs_[0][lq]+rs_[1][lq]+rs_[2][lq]+rs_[3][lq];
        float qq = rq_[0][lq]+rq_[1][lq]+rq_[2][lq]+rq_[3][lq];
        float mu = ss * (1.f/DI);
        float var = qq * (1.f/DI) - mu*mu;
        mu_s[lq] = mu; rstd_s[lq] = rsqrtf(var + 1e-5f);
    }
    __syncthreads();
    float mu = mu_s[lq], rs = rstd_s[lq];
    const float* zp = z + (size_t)b*DI*LL + l;
#pragma unroll 4
    for (int i = 0; i < 96; i++) {
        int d = p*96 + i;
        float v = (yp[(size_t)d*LL] - mu)*rs*g[d] + bt[d];
        float zv = zp[(size_t)d*LL];
        float sg = 1.f / (1.f + __expf(-zv));
        yp[(size_t)d*LL] = v * (zv * sg);
    }
}

extern "C" void kernel_launch(void* const* d_in, const int* in_sizes, int n_in,
                              void* d_out, int out_size, void* d_ws, size_t ws_size,
                              hipStream_t stream)
{
    (void)in_sizes; (void)n_in; (void)out_size; (void)ws_size;
    const float* x     = (const float*)d_in[0];
    const float* low   = (const float*)d_in[1];
    const float* ln_g  = (const float*)d_in[2];
    const float* ln_b  = (const float*)d_in[3];
    const float* w_in  = (const float*)d_in[4];
    const float* w_low = (const float*)d_in[5];
    const float* w_c2d = (const float*)d_in[6];
    const float* b_c2d = (const float*)d_in[7];
    const float* w_xp  = (const float*)d_in[8];
    const float* w_xpl = (const float*)d_in[9];
    const float* w_cdt = (const float*)d_in[10];
    const float* w_cB  = (const float*)d_in[11];
    const float* w_cC  = (const float*)d_in[12];
    const float* sgb1  = (const float*)d_in[13];
    const float* sgb2  = (const float*)d_in[14];
    const float* sgc1  = (const float*)d_in[15];
    const float* sgc2  = (const float*)d_in[16];
    const float* dtw   = (const float*)d_in[17];
    const float* dtb   = (const float*)d_in[18];
    const float* Alogs = (const float*)d_in[19];
    const float* Ds    = (const float*)d_in[20];
    const float* ong   = (const float*)d_in[21];
    const float* onb   = (const float*)d_in[22];
    const float* w_out = (const float*)d_in[23];
    float* ws  = (float*)d_ws;
    float* out = (float*)d_out;
    dim3 blk(256);

    // bf16 plane aliases
    ushort_t* wInH  = (ushort_t*)(ws + O_WT_IN);   ushort_t* wInL  = wInH + 147456;
    ushort_t* wLowH = (ushort_t*)(ws + O_WT_LOW);  ushort_t* wLowL = wLowH + 73728;
    ushort_t* wOutH = (ushort_t*)(ws + O_WT_OUT);  ushort_t* wOutL = wOutH + 73728;
    ushort_t* wXpH  = (ushort_t*)(ws + O_WT_XP);   ushort_t* wXpL  = wXpH + 24576;
    ushort_t* wXplH = (ushort_t*)(ws + O_WT_XPL);  ushort_t* wXplL = wXplH + 24576;
    ushort_t* xnh   = (ushort_t*)(ws + O_XN);      ushort_t* xnl   = xnh + 3145728;
    ushort_t* lowh  = (ushort_t*)(ws + O_LOWT);    ushort_t* lowl  = lowh + 3145728;

    wprep_kernel<<<336, blk, 0, stream>>>(w_in, wInH, wInL, w_low, wLowH, wLowL,
                                          w_out, wOutH, wOutL,
                                          w_xp, wXpH, wXpL, w_xpl, wXplH, wXplL);

    actprep_kernel<<<3328, blk, 0, stream>>>(x, ln_g, ln_b, xnh, xnl, low, lowh, lowl);

    gemm_mfma<0,3,192><<<dim3(128,12), blk, 0, stream>>>(xnh, xnl, wInH, wInL,
                                                         ws+O_XH, ws+O_Z);
    gemm_mfma<1,3,192><<<dim3(128,6),  blk, 0, stream>>>(lowh, lowl, wLowH, wLowL,
                                                         ws+O_LOWP, nullptr);

    conv2d_silu_kernel<<<dim3(16,384,4), blk, 0, stream>>>(ws+O_XH, w_c2d, b_c2d, ws+O_XS);

    gemm_cmaj<1,3,1><<<dim3(128,1,2), blk, 0, stream>>>(ws+O_XS, ws+O_LOWP,
                                                        wXpH, wXpL, wXplH, wXplL,
                                                        nullptr, ws+O_DBCH, ws+O_DBCL, NCH);

    gates_kernel<<<dim3(64,4), blk, 0, stream>>>(ws+O_DBCH, ws+O_DBCL, sgb1, sgb2, sgc1, sgc2, ws+O_DBC);

    conv_dbc_kernel<<<dim3(16,44,4), blk, 0, stream>>>(ws+O_DBC, w_cdt, w_cB, w_cC,
                                                       ws+O_DTS, ws+O_BS, ws+O_CS);
    delta_kernel<<<dim3(32,6,4), blk, 0, stream>>>(ws+O_DTS, dtw, dtb, ws+O_DELTA);

    scan_kernel<<<1536, blk, 0, stream>>>(ws+O_XS, ws+O_DELTA, ws+O_BS, ws+O_CS, Alogs, Ds,
                                          ws+O_Y);

    outnorm_gate_kernel<<<dim3(64,4), blk, 0, stream>>>(ws+O_Y, ws+O_Z, ong, onb);

    gemm_cmaj<2,1,0><<<dim3(128,3,1), blk, 0, stream>>>(ws+O_Y, nullptr,
                                                        wOutH, wOutL, nullptr, nullptr,
                                                        x, out, nullptr, CM);
}